// Round 6
// baseline (589.197 us; speedup 1.0000x reference)
//
#include <hip/hip_runtime.h>
#include <math.h>

#define D_MODEL   1024
#define N_HEADS   16
#define H_DIM     64
#define SEQ       2048
#define BATCH     2
#define ROWS      (BATCH * SEQ)        // 4096
#define THREE_D   (3 * D_MODEL)       // 3072

// q pre-scale: 1/sqrt(64) * log2(e)  -> softmax in exp2 domain
#define QK_SCALE  (0.125f * 1.44269504088896340736f)

typedef __attribute__((ext_vector_type(8))) short short8v;   // 8 bf16
typedef __attribute__((ext_vector_type(4))) float f32x4;
typedef __attribute__((ext_vector_type(4))) unsigned int uint4v;
typedef __attribute__((ext_vector_type(2))) unsigned int uint2v;

union Frag { uint4v u; short8v s; };

__device__ __forceinline__ void async_copy16(const float* g, float* l)
{
    __builtin_amdgcn_global_load_lds(
        (const __attribute__((address_space(1))) void*)g,
        (__attribute__((address_space(3))) void*)l,
        16, 0, 0);
}

// LDS octet swizzle key: spreads banks for BOTH row-strided (stride-4) write
// groups and 16-row fragment read groups.  Used at every K/V/P LDS site.
__device__ __forceinline__ int swz8(int row, int oct)
{
    return oct ^ ((row ^ (row >> 2)) & 7);
}

// split fp32 -> 3 bf16 planes (truncation)
#define SPL(x, j)                                                          \
    {                                                                      \
        const float x_ = (x);                                              \
        const unsigned u1_ = __float_as_uint(x_);                          \
        const float r1_ = x_ - __uint_as_float(u1_ & 0xFFFF0000u);         \
        const unsigned u2_ = __float_as_uint(r1_);                         \
        const float r2_ = r1_ - __uint_as_float(u2_ & 0xFFFF0000u);        \
        h1[j] = (short)(u1_ >> 16);                                        \
        h2[j] = (short)(u2_ >> 16);                                        \
        h3[j] = (short)(__float_as_uint(r2_) >> 16);                       \
    }

// split fp32 -> 2 bf16 planes
#define SPL2(x, j)                                                         \
    {                                                                      \
        const float x_ = (x);                                              \
        const unsigned u1_ = __float_as_uint(x_);                          \
        const float r1_ = x_ - __uint_as_float(u1_ & 0xFFFF0000u);         \
        h1[j] = (short)(u1_ >> 16);                                        \
        h2[j] = (short)(__float_as_uint(r1_) >> 16);                       \
    }

// split 8 floats into 3 packed bf16x8 planes
__device__ __forceinline__ void split3x8(const float* v, uint4v& U1, uint4v& U2, uint4v& U3)
{
    unsigned b1[8], b2[8], b3[8];
#pragma unroll
    for (int j = 0; j < 8; ++j) {
        const unsigned u = __float_as_uint(v[j]);
        b1[j] = u;
        const float r  = v[j] - __uint_as_float(u & 0xFFFF0000u);
        const unsigned ur = __float_as_uint(r);
        b2[j] = ur;
        const float r2 = r - __uint_as_float(ur & 0xFFFF0000u);
        b3[j] = __float_as_uint(r2);
    }
    U1 = (uint4v){ (b1[0]>>16)|(b1[1]&0xFFFF0000u), (b1[2]>>16)|(b1[3]&0xFFFF0000u),
                   (b1[4]>>16)|(b1[5]&0xFFFF0000u), (b1[6]>>16)|(b1[7]&0xFFFF0000u) };
    U2 = (uint4v){ (b2[0]>>16)|(b2[1]&0xFFFF0000u), (b2[2]>>16)|(b2[3]&0xFFFF0000u),
                   (b2[4]>>16)|(b2[5]&0xFFFF0000u), (b2[6]>>16)|(b2[7]&0xFFFF0000u) };
    U3 = (uint4v){ (b3[0]>>16)|(b3[1]&0xFFFF0000u), (b3[2]>>16)|(b3[3]&0xFFFF0000u),
                   (b3[4]>>16)|(b3[5]&0xFFFF0000u), (b3[6]>>16)|(b3[7]&0xFFFF0000u) };
}

// split 8 floats into 2 packed bf16x8 planes
__device__ __forceinline__ void split2x8(const float* v, uint4v& U1, uint4v& U2)
{
    unsigned b1[8], b2[8];
#pragma unroll
    for (int j = 0; j < 8; ++j) {
        const unsigned u = __float_as_uint(v[j]);
        b1[j] = u;
        const float r = v[j] - __uint_as_float(u & 0xFFFF0000u);
        b2[j] = __float_as_uint(r);
    }
    U1 = (uint4v){ (b1[0]>>16)|(b1[1]&0xFFFF0000u), (b1[2]>>16)|(b1[3]&0xFFFF0000u),
                   (b1[4]>>16)|(b1[5]&0xFFFF0000u), (b1[6]>>16)|(b1[7]&0xFFFF0000u) };
    U2 = (uint4v){ (b2[0]>>16)|(b2[1]&0xFFFF0000u), (b2[2]>>16)|(b2[3]&0xFFFF0000u),
                   (b2[4]>>16)|(b2[5]&0xFFFF0000u), (b2[6]>>16)|(b2[7]&0xFFFF0000u) };
}

// ---------------------------------------------------------------------------
// GEMM:  C[M,N] = A[M,K] * B[N,K]^T + bias[N]   via bf16-split MFMA.
// A split x3, B split x2, 5 products.  (unchanged from R4 — verified)
// ---------------------------------------------------------------------------
__global__ __launch_bounds__(256, 2)
void gemm_bt_mfma(const float* __restrict__ A, int lda,
                  const float* __restrict__ B, int ldb,
                  const float* __restrict__ bias,
                  float* __restrict__ C, int ldc, int K,
                  int nbx, size_t segA, size_t segB, int segBias, size_t segC)
{
    __shared__ __align__(16) float As[2][128 * 32];
    __shared__ __align__(16) float Bs[2][128 * 32];

    const int seg = blockIdx.x / nbx;
    const int bxs = blockIdx.x - seg * nbx;
    const int bm  = blockIdx.y * 128;
    const int bn  = bxs * 128;
    A    += (size_t)seg * segA;
    B    += (size_t)seg * segB;
    bias += seg * segBias;
    C    += (size_t)seg * segC;

    const int t    = threadIdx.x;
    const int wid  = t >> 6;
    const int lane = t & 63;
    const int wr   = wid >> 1;
    const int wc   = wid & 1;
    const int cl   = lane & 15;
    const int kq   = lane >> 4;
    const int lrow = lane >> 3;
    const int gs   = lane & 7;

    auto stage = [&](int buf, int k0) {
        const int gl = gs ^ lrow;
#pragma unroll
        for (int q = 0; q < 4; ++q) {
            const int r0  = (wid * 4 + q) * 8;
            const int row = r0 + lrow;
            async_copy16(A + (size_t)(bm + row) * lda + k0 + (gl << 2),
                         &As[buf][r0 * 32]);
            async_copy16(B + (size_t)(bn + row) * ldb + k0 + (gl << 2),
                         &Bs[buf][r0 * 32]);
        }
    };

    f32x4 acc[4][4];
#pragma unroll
    for (int m = 0; m < 4; ++m)
#pragma unroll
        for (int n = 0; n < 4; ++n) acc[m][n] = (f32x4)(0.f);

    const int NT = K >> 5;
    stage(0, 0);

    for (int it = 0; it < NT; ++it) {
        __syncthreads();
        if (it + 1 < NT)
            stage((it + 1) & 1, (it + 1) << 5);

        const float* as = As[it & 1];
        const float* bs = Bs[it & 1];

        short8v A1[4], A2[4], A3[4], B1[4], B2[4];
#pragma unroll
        for (int m = 0; m < 4; ++m) {
            const int r  = wr * 64 + m * 16 + cl;
            const int s1 = (2 * kq) ^ (r & 7);
            const float4 lo = *reinterpret_cast<const float4*>(as + r * 32 + (s1 << 2));
            const float4 hi = *reinterpret_cast<const float4*>(as + r * 32 + ((s1 ^ 1) << 2));
            short8v h1, h2, h3;
            SPL(lo.x, 0) SPL(lo.y, 1) SPL(lo.z, 2) SPL(lo.w, 3)
            SPL(hi.x, 4) SPL(hi.y, 5) SPL(hi.z, 6) SPL(hi.w, 7)
            A1[m] = h1; A2[m] = h2; A3[m] = h3;
        }
#pragma unroll
        for (int n = 0; n < 4; ++n) {
            const int r  = wc * 64 + n * 16 + cl;
            const int s1 = (2 * kq) ^ (r & 7);
            const float4 lo = *reinterpret_cast<const float4*>(bs + r * 32 + (s1 << 2));
            const float4 hi = *reinterpret_cast<const float4*>(bs + r * 32 + ((s1 ^ 1) << 2));
            short8v h1, h2;
            SPL2(lo.x, 0) SPL2(lo.y, 1) SPL2(lo.z, 2) SPL2(lo.w, 3)
            SPL2(hi.x, 4) SPL2(hi.y, 5) SPL2(hi.z, 6) SPL2(hi.w, 7)
            B1[n] = h1; B2[n] = h2;
        }

#pragma unroll
        for (int m = 0; m < 4; ++m)
#pragma unroll
            for (int n = 0; n < 4; ++n) {
                f32x4 c = acc[m][n];
                c = __builtin_amdgcn_mfma_f32_16x16x32_bf16(A1[m], B1[n], c, 0, 0, 0);
                c = __builtin_amdgcn_mfma_f32_16x16x32_bf16(A2[m], B1[n], c, 0, 0, 0);
                c = __builtin_amdgcn_mfma_f32_16x16x32_bf16(A1[m], B2[n], c, 0, 0, 0);
                c = __builtin_amdgcn_mfma_f32_16x16x32_bf16(A2[m], B2[n], c, 0, 0, 0);
                c = __builtin_amdgcn_mfma_f32_16x16x32_bf16(A3[m], B1[n], c, 0, 0, 0);
                acc[m][n] = c;
            }
    }

    const int rw = lane >> 4;
#pragma unroll
    for (int n = 0; n < 4; ++n) {
        const int col = bn + wc * 64 + n * 16 + cl;
        const float bv = bias[col];
#pragma unroll
        for (int m = 0; m < 4; ++m) {
            const size_t rbase = (size_t)(bm + wr * 64 + m * 16 + rw * 4);
#pragma unroll
            for (int i = 0; i < 4; ++i)
                C[(rbase + i) * ldc + col] = acc[m][n][i] + bv;
        }
    }
}

// ---------------------------------------------------------------------------
// RoPE
// ---------------------------------------------------------------------------
__global__ void rope_table(float* __restrict__ tab)
{
    const int idx = blockIdx.x * 256 + threadIdx.x;
    const int s = idx >> 5;
    const int i = idx & 31;
    const double inv = pow(10000.0, -(double)(2 * i) / 64.0);
    const double f = (double)s * inv;
    tab[idx * 2 + 0] = (float)cos(f);
    tab[idx * 2 + 1] = (float)sin(f);
}

__global__ void rope_apply(float* __restrict__ comb, const float* __restrict__ tab)
{
    const int idx = blockIdx.x * 256 + threadIdx.x;
    const int i     = idx & 31;
    const int h     = (idx >> 5) & 15;
    const int row   = (idx >> 9) & (ROWS - 1);
    const int which = idx >> 21;
    const int s     = row & (SEQ - 1);

    const float c  = tab[(s * 32 + i) * 2 + 0];
    const float sn = tab[(s * 32 + i) * 2 + 1];

    float* base = comb + (size_t)row * THREE_D + which * D_MODEL + h * H_DIM;
    const float t1 = base[i];
    const float t2 = base[i + 32];
    base[i]      = t1 * c - t2 * sn;
    base[i + 32] = t2 * c + t1 * sn;
}

// ---------------------------------------------------------------------------
// Flash attention, bf16-split MFMA, kv-split 2x, T14 async staging.
// grid = (SEQ/128, BATCH*N_HEADS, 2).  256 threads = 4 waves x 32 q-rows.
// Schedule per tile: [bar: writes visible] -> issue t+1 global loads (regs)
// -> QK/softmax/PV (hides load latency) -> [bar: reads done] -> split+write
// t+1.  All LDS sites share the swz8() octet key (conflict-free by enum).
// ---------------------------------------------------------------------------
__global__ __launch_bounds__(256)
void attn_mfma(const float* __restrict__ Qg, const float* __restrict__ Kg,
               const float* __restrict__ Vg,
               float* __restrict__ Pacc, float* __restrict__ Pml)
{
    __shared__ __align__(16) short Ks1[64 * 64];
    __shared__ __align__(16) short Ks2[64 * 64];
    __shared__ __align__(16) short Vt1[64 * 64];
    __shared__ __align__(16) short Vt2[64 * 64];
    __shared__ __align__(16) short Ps[4 * 2 * 16 * 64];   // [wave][plane][q16][k64]

    const int bh   = blockIdx.y;
    const int b    = bh >> 4;
    const int h    = bh & 15;
    const int q0   = blockIdx.x * 128;
    const int half = blockIdx.z;
    const size_t rowBase = (size_t)b * SEQ;
    const int hOff = h * H_DIM;

    const int t    = threadIdx.x;
    const int w    = t >> 6;
    const int lane = t & 63;
    const int cl   = lane & 15;
    const int g    = lane >> 4;

    // staging lane roles
    const int krow = t >> 2;            // K: row k
    const int dob  = (t & 3) * 2;       // K: logical octet base
    const int vkq  = t >> 4;            // V: k = 4*vkq + r
    const int vdq  = t & 15;            // V: d = 4*vdq + rr

    // ---- Q fragments (B-operand), 3 planes, pre-scaled
    Frag qf[2][2][3];   // [qs][c][plane]
#pragma unroll
    for (int qs = 0; qs < 2; ++qs)
#pragma unroll
        for (int c = 0; c < 2; ++c) {
            const float* qp = Qg + (rowBase + q0 + w * 32 + qs * 16 + cl) * D_MODEL
                              + hOff + c * 32 + g * 8;
            const float4 f0 = *reinterpret_cast<const float4*>(qp);
            const float4 f1 = *reinterpret_cast<const float4*>(qp + 4);
            float v[8] = { f0.x * QK_SCALE, f0.y * QK_SCALE, f0.z * QK_SCALE, f0.w * QK_SCALE,
                           f1.x * QK_SCALE, f1.y * QK_SCALE, f1.z * QK_SCALE, f1.w * QK_SCALE };
            split3x8(v, qf[qs][c][0].u, qf[qs][c][1].u, qf[qs][c][2].u);
        }

    f32x4 acc[2][4];
#pragma unroll
    for (int qs = 0; qs < 2; ++qs)
#pragma unroll
        for (int s = 0; s < 4; ++s) acc[qs][s] = (f32x4)(0.f);
    float m[2] = { -1e30f, -1e30f };
    float l[2] = { 0.f, 0.f };

    // staged tile registers (float4 x4 K + x4 V = 32 VGPRs)
    float4 kr0, kr1, kr2, kr3, vr0, vr1, vr2, vr3;

    auto load_tile = [&](int k0) {
        const float* kp = Kg + (rowBase + k0 + krow) * D_MODEL + hOff + dob * 8;
        kr0 = reinterpret_cast<const float4*>(kp)[0];
        kr1 = reinterpret_cast<const float4*>(kp)[1];
        kr2 = reinterpret_cast<const float4*>(kp)[2];
        kr3 = reinterpret_cast<const float4*>(kp)[3];
        const float* vp = Vg + (rowBase + k0 + vkq * 4) * D_MODEL + hOff + vdq * 4;
        vr0 = *reinterpret_cast<const float4*>(vp);
        vr1 = *reinterpret_cast<const float4*>(vp + D_MODEL);
        vr2 = *reinterpret_cast<const float4*>(vp + 2 * D_MODEL);
        vr3 = *reinterpret_cast<const float4*>(vp + 3 * D_MODEL);
    };

    auto write_tile = [&]() {
        // ---- K: 2 planes, swizzled octets
        {
            float v[16];
            *reinterpret_cast<float4*>(&v[0])  = kr0;
            *reinterpret_cast<float4*>(&v[4])  = kr1;
            *reinterpret_cast<float4*>(&v[8])  = kr2;
            *reinterpret_cast<float4*>(&v[12]) = kr3;
            uint4v a1, a2, b1, b2;
            split2x8(v,     a1, a2);
            split2x8(v + 8, b1, b2);
            short* kb1 = Ks1 + krow * 64;
            short* kb2 = Ks2 + krow * 64;
            *reinterpret_cast<uint4v*>(kb1 + swz8(krow, dob    ) * 8) = a1;
            *reinterpret_cast<uint4v*>(kb1 + swz8(krow, dob + 1) * 8) = b1;
            *reinterpret_cast<uint4v*>(kb2 + swz8(krow, dob    ) * 8) = a2;
            *reinterpret_cast<uint4v*>(kb2 + swz8(krow, dob + 1) * 8) = b2;
        }
        // ---- V^T: 2 planes, 4x4 register transpose, swizzled octets
        {
            float va[4][4];
            *reinterpret_cast<float4*>(va[0]) = vr0;
            *reinterpret_cast<float4*>(va[1]) = vr1;
            *reinterpret_cast<float4*>(va[2]) = vr2;
            *reinterpret_cast<float4*>(va[3]) = vr3;
            const int lo = vkq >> 1;
            const int hf = (vkq & 1) * 4;
#pragma unroll
            for (int rr = 0; rr < 4; ++rr) {
                const int row = 4 * vdq + rr;
                unsigned ub[4], rb[4];
#pragma unroll
                for (int r = 0; r < 4; ++r) {
                    const float x = va[r][rr];
                    const unsigned u = __float_as_uint(x);
                    ub[r] = u;
                    rb[r] = __float_as_uint(x - __uint_as_float(u & 0xFFFF0000u));
                }
                uint2v w1, w2;
                w1.x = (ub[0] >> 16) | (ub[1] & 0xFFFF0000u);
                w1.y = (ub[2] >> 16) | (ub[3] & 0xFFFF0000u);
                w2.x = (rb[0] >> 16) | (rb[1] & 0xFFFF0000u);
                w2.y = (rb[2] >> 16) | (rb[3] & 0xFFFF0000u);
                const int o = row * 64 + swz8(row, lo) * 8 + hf;
                *reinterpret_cast<uint2v*>(&Vt1[o]) = w1;
                *reinterpret_cast<uint2v*>(&Vt2[o]) = w2;
            }
        }
    };

    const int kbase = half * (SEQ / 2);
    const int NT = (SEQ / 2) / 64;       // 16 tiles

    load_tile(kbase);
    write_tile();

    for (int it = 0; it < NT; ++it) {
        __syncthreads();   // tile `it` writes visible
        if (it + 1 < NT)
            load_tile(kbase + (it + 1) * 64);   // hidden under compute below

        // ---- QK^T (swapped): sacc[qs][ks], k = 16ks+4g+i, q = cl
        f32x4 sacc[2][4];
#pragma unroll
        for (int qs = 0; qs < 2; ++qs)
#pragma unroll
            for (int ks = 0; ks < 4; ++ks) sacc[qs][ks] = (f32x4)(0.f);

        __builtin_amdgcn_s_setprio(1);
#pragma unroll
        for (int ks = 0; ks < 4; ++ks)
#pragma unroll
            for (int c = 0; c < 2; ++c) {
                const int row = ks * 16 + cl;
                const int po  = row * 64 + swz8(row, 4 * c + g) * 8;
                Frag ka1, ka2;
                ka1.s = *reinterpret_cast<const short8v*>(&Ks1[po]);
                ka2.s = *reinterpret_cast<const short8v*>(&Ks2[po]);
#pragma unroll
                for (int qs = 0; qs < 2; ++qs) {
                    f32x4 s = sacc[qs][ks];
                    s = __builtin_amdgcn_mfma_f32_16x16x32_bf16(ka1.s, qf[qs][c][0].s, s, 0, 0, 0);
                    s = __builtin_amdgcn_mfma_f32_16x16x32_bf16(ka2.s, qf[qs][c][0].s, s, 0, 0, 0);
                    s = __builtin_amdgcn_mfma_f32_16x16x32_bf16(ka1.s, qf[qs][c][1].s, s, 0, 0, 0);
                    s = __builtin_amdgcn_mfma_f32_16x16x32_bf16(ka2.s, qf[qs][c][1].s, s, 0, 0, 0);
                    s = __builtin_amdgcn_mfma_f32_16x16x32_bf16(ka1.s, qf[qs][c][2].s, s, 0, 0, 0);
                    sacc[qs][ks] = s;
                }
            }
        __builtin_amdgcn_s_setprio(0);

        // ---- per-qs: softmax -> P (per-wave LDS, 2 planes) -> PV
        short* pb1 = Ps + ((w * 2 + 0) * 16 + cl) * 64;
        short* pb2 = Ps + ((w * 2 + 1) * 16 + cl) * 64;

#pragma unroll
        for (int qs = 0; qs < 2; ++qs) {
            float tm = -1e30f;
#pragma unroll
            for (int ks = 0; ks < 4; ++ks)
#pragma unroll
                for (int i = 0; i < 4; ++i) tm = fmaxf(tm, sacc[qs][ks][i]);
            tm = fmaxf(tm, __shfl_xor(tm, 16));
            tm = fmaxf(tm, __shfl_xor(tm, 32));

            const float mn = fmaxf(m[qs], tm);
            const float sc = __builtin_amdgcn_exp2f(m[qs] - mn);
            m[qs] = mn;

            float rs = 0.f;
            uint2v P1[4], P2[4];
#pragma unroll
            for (int ks = 0; ks < 4; ++ks) {
                float p[4];
                unsigned ub[4], rb[4];
#pragma unroll
                for (int i = 0; i < 4; ++i) {
                    p[i] = __builtin_amdgcn_exp2f(sacc[qs][ks][i] - mn);
                    rs += p[i];
                    const unsigned u = __float_as_uint(p[i]);
                    ub[i] = u;
                    rb[i] = __float_as_uint(p[i] - __uint_as_float(u & 0xFFFF0000u));
                }
                P1[ks] = (uint2v){ (ub[0] >> 16) | (ub[1] & 0xFFFF0000u),
                                   (ub[2] >> 16) | (ub[3] & 0xFFFF0000u) };
                P2[ks] = (uint2v){ (rb[0] >> 16) | (rb[1] & 0xFFFF0000u),
                                   (rb[2] >> 16) | (rb[3] & 0xFFFF0000u) };
            }
            rs += __shfl_xor(rs, 16);
            rs += __shfl_xor(rs, 32);
            l[qs] = l[qs] * sc + rs;

            // rescale acc rows (q = 4g+i; sc lives at lane cl = q)
            float scv[4];
#pragma unroll
            for (int i = 0; i < 4; ++i) scv[i] = __shfl(sc, 4 * g + i);
#pragma unroll
            for (int s = 0; s < 4; ++s)
#pragma unroll
                for (int i = 0; i < 4; ++i) acc[qs][s][i] *= scv[i];

            // write P to per-wave LDS (row q = cl, k = 16ks+4g+i)
#pragma unroll
            for (int ks = 0; ks < 4; ++ks) {
                const int off = swz8(cl, 2 * ks + (g >> 1)) * 8 + (g & 1) * 4;
                *reinterpret_cast<uint2v*>(pb1 + off) = P1[ks];
                *reinterpret_cast<uint2v*>(pb2 + off) = P2[ks];
            }

            // PV: A = P (A-frag: row q = cl), B = V^T
            __builtin_amdgcn_s_setprio(1);
#pragma unroll
            for (int c = 0; c < 2; ++c) {
                const int po = swz8(cl, 4 * c + g) * 8;
                Frag pa1, pa2;
                pa1.s = *reinterpret_cast<const short8v*>(pb1 + po);
                pa2.s = *reinterpret_cast<const short8v*>(pb2 + po);
#pragma unroll
                for (int s = 0; s < 4; ++s) {
                    const int row = s * 16 + cl;
                    const int vo  = row * 64 + swz8(row, 4 * c + g) * 8;
                    Frag vb1, vb2;
                    vb1.s = *reinterpret_cast<const short8v*>(&Vt1[vo]);
                    vb2.s = *reinterpret_cast<const short8v*>(&Vt2[vo]);
                    f32x4 a = acc[qs][s];
                    a = __builtin_amdgcn_mfma_f32_16x16x32_bf16(pa1.s, vb1.s, a, 0, 0, 0);
                    a = __builtin_amdgcn_mfma_f32_16x16x32_bf16(pa2.s, vb1.s, a, 0, 0, 0);
                    a = __builtin_amdgcn_mfma_f32_16x16x32_bf16(pa1.s, vb2.s, a, 0, 0, 0);
                    acc[qs][s] = a;
                }
            }
            __builtin_amdgcn_s_setprio(0);
        }

        __syncthreads();   // all reads of tile `it` done
        if (it + 1 < NT)
            write_tile();  // stage tile it+1 (regs loaded long ago)
    }

    // ---- store partials (raw acc + m,l); combine kernel normalizes
    const int pblk = (half * 32 + bh) * 16 + blockIdx.x;
    float* ab = Pacc + (size_t)pblk * (128 * 64);
#pragma unroll
    for (int qs = 0; qs < 2; ++qs) {
#pragma unroll
        for (int s = 0; s < 4; ++s)
#pragma unroll
            for (int i = 0; i < 4; ++i)
                ab[(w * 32 + qs * 16 + 4 * g + i) * 64 + s * 16 + cl] = acc[qs][s][i];
        if (g == 0) {
            float2 ml; ml.x = m[qs]; ml.y = l[qs];
            reinterpret_cast<float2*>(Pml)[pblk * 128 + w * 32 + qs * 16 + cl] = ml;
        }
    }
}

// ---------------------------------------------------------------------------
// Combine the two kv-half partials and normalize -> ctx.
// ---------------------------------------------------------------------------
__global__ __launch_bounds__(256)
void attn_combine(const float* __restrict__ Pacc, const float* __restrict__ Pml,
                  float* __restrict__ ctx)
{
    const int tid = blockIdx.x * 256 + threadIdx.x;    // 0 .. ROWS*D_MODEL/4-1
    const int col = (tid & 255) * 4;                   // 0..1020
    const int row = tid >> 8;                          // 0..4095
    const int b = row >> 11, s = row & 2047;
    const int h = col >> 6,  d = col & 63;
    const int p0 = (b * 16 + h) * 16 + (s >> 7);
    const int q  = s & 127;

    const float2 mlA = reinterpret_cast<const float2*>(Pml)[p0 * 128 + q];
    const float2 mlB = reinterpret_cast<const float2*>(Pml)[(p0 + 512) * 128 + q];
    const float4 a = *reinterpret_cast<const float4*>(
        Pacc + ((size_t)p0 * 128 + q) * 64 + d);
    const float4 c = *reinterpret_cast<const float4*>(
        Pacc + ((size_t)(p0 + 512) * 128 + q) * 64 + d);

    const float mf = fmaxf(mlA.x, mlB.x);
    const float wa = __builtin_amdgcn_exp2f(mlA.x - mf);
    const float wb = __builtin_amdgcn_exp2f(mlB.x - mf);
    const float inv = 1.f / (wa * mlA.y + wb * mlB.y);

    float4 o;
    o.x = (wa * a.x + wb * c.x) * inv;
    o.y = (wa * a.y + wb * c.y) * inv;
    o.z = (wa * a.z + wb * c.z) * inv;
    o.w = (wa * a.w + wb * c.w) * inv;
    *reinterpret_cast<float4*>(&ctx[(size_t)row * D_MODEL + col]) = o;
}

// ---------------------------------------------------------------------------
extern "C" void kernel_launch(void* const* d_in, const int* in_sizes, int n_in,
                              void* d_out, int out_size, void* d_ws, size_t ws_size,
                              hipStream_t stream)
{
    const float* x    = (const float*)d_in[0];
    const float* Win  = (const float*)d_in[1];   // (3072, 1024)
    const float* bin  = (const float*)d_in[2];   // (3072,)
    const float* Wout = (const float*)d_in[3];   // (1024, 1024)
    const float* bout = (const float*)d_in[4];   // (1024,)
    float* out = (float*)d_out;

    float* combined = (float*)d_ws;                                  // ROWS x 3072
    float* qkv  = combined + (size_t)ROWS * THREE_D;                 // 3 x ROWS x 1024
    float* qbuf = qkv;
    float* kbuf = qkv + (size_t)ROWS * D_MODEL;
    float* vbuf = kbuf + (size_t)ROWS * D_MODEL;
    float* tab  = vbuf + (size_t)ROWS * D_MODEL;                     // SEQ*32*2
    float* Pml  = tab + (size_t)SEQ * 64;                            // 1024*128*2
    float* ctx  = combined;                                          // ROWS x 1024
    float* Pacc = combined + (size_t)ROWS * D_MODEL;                 // 1024*128*64

    const dim3 blk(256);

    rope_table<<<dim3(SEQ * 32 / 256), blk, 0, stream>>>(tab);

    // GEMM1: combined = x @ Win^T + bin
    gemm_bt_mfma<<<dim3(24, 32), blk, 0, stream>>>(
        x, D_MODEL, Win, D_MODEL, bin, combined, THREE_D, D_MODEL,
        24, (size_t)0, (size_t)0, 0, (size_t)0);

    // RoPE in place on q/k thirds of combined
    rope_apply<<<dim3((2 * ROWS * N_HEADS * 32) / 256), blk, 0, stream>>>(combined, tab);

    // fused q/k/v second projection
    gemm_bt_mfma<<<dim3(24, 32), blk, 0, stream>>>(
        combined, THREE_D, Win, D_MODEL, bin, qkv, D_MODEL, D_MODEL,
        8, (size_t)D_MODEL, (size_t)D_MODEL * D_MODEL, D_MODEL,
        (size_t)ROWS * D_MODEL);

    // attention partials (kv-split 2x) then combine -> ctx
    attn_mfma<<<dim3(SEQ / 128, BATCH * N_HEADS, 2), blk, 0, stream>>>(
        qbuf, kbuf, vbuf, Pacc, Pml);
    attn_combine<<<dim3(ROWS * D_MODEL / 4 / 256), blk, 0, stream>>>(Pacc, Pml, ctx);

    // GEMM3: out = ctx @ Wout^T + bout
    gemm_bt_mfma<<<dim3(8, 32), blk, 0, stream>>>(
        ctx, D_MODEL, Wout, D_MODEL, bout, out, D_MODEL, D_MODEL,
        8, (size_t)0, (size_t)0, 0, (size_t)0);
}

// Round 7
// 531.603 us; speedup vs baseline: 1.1083x; 1.1083x over previous
//
#include <hip/hip_runtime.h>
#include <math.h>

#define D_MODEL   1024
#define N_HEADS   16
#define H_DIM     64
#define SEQ       2048
#define BATCH     2
#define ROWS      (BATCH * SEQ)        // 4096
#define THREE_D   (3 * D_MODEL)       // 3072

// q pre-scale: 1/sqrt(64) * log2(e)  -> softmax in exp2 domain
#define QK_SCALE  (0.125f * 1.44269504088896340736f)

typedef __attribute__((ext_vector_type(8))) short short8v;   // 8 bf16
typedef __attribute__((ext_vector_type(4))) float f32x4;
typedef __attribute__((ext_vector_type(4))) unsigned int uint4v;
typedef __attribute__((ext_vector_type(2))) unsigned int uint2v;

union Frag { uint4v u; short8v s; };

__device__ __forceinline__ void async_copy16(const float* g, float* l)
{
    __builtin_amdgcn_global_load_lds(
        (const __attribute__((address_space(1))) void*)g,
        (__attribute__((address_space(3))) void*)l,
        16, 0, 0);
}

// LDS octet swizzle key: spreads banks for BOTH row-strided (stride-4) write
// groups and 16-row fragment read groups.  Used at every K/V/P LDS site.
__device__ __forceinline__ int swz8(int row, int oct)
{
    return oct ^ ((row ^ (row >> 2)) & 7);
}

// split fp32 -> 3 bf16 planes (truncation)
#define SPL(x, j)                                                          \
    {                                                                      \
        const float x_ = (x);                                              \
        const unsigned u1_ = __float_as_uint(x_);                          \
        const float r1_ = x_ - __uint_as_float(u1_ & 0xFFFF0000u);         \
        const unsigned u2_ = __float_as_uint(r1_);                         \
        const float r2_ = r1_ - __uint_as_float(u2_ & 0xFFFF0000u);        \
        h1[j] = (short)(u1_ >> 16);                                        \
        h2[j] = (short)(u2_ >> 16);                                        \
        h3[j] = (short)(__float_as_uint(r2_) >> 16);                       \
    }

// split fp32 -> 2 bf16 planes
#define SPL2(x, j)                                                         \
    {                                                                      \
        const float x_ = (x);                                              \
        const unsigned u1_ = __float_as_uint(x_);                          \
        const float r1_ = x_ - __uint_as_float(u1_ & 0xFFFF0000u);         \
        h1[j] = (short)(u1_ >> 16);                                        \
        h2[j] = (short)(__float_as_uint(r1_) >> 16);                       \
    }

// split 8 floats into 2 packed bf16x8 planes
__device__ __forceinline__ void split2x8(const float* v, uint4v& U1, uint4v& U2)
{
    unsigned b1[8], b2[8];
#pragma unroll
    for (int j = 0; j < 8; ++j) {
        const unsigned u = __float_as_uint(v[j]);
        b1[j] = u;
        const float r = v[j] - __uint_as_float(u & 0xFFFF0000u);
        b2[j] = __float_as_uint(r);
    }
    U1 = (uint4v){ (b1[0]>>16)|(b1[1]&0xFFFF0000u), (b1[2]>>16)|(b1[3]&0xFFFF0000u),
                   (b1[4]>>16)|(b1[5]&0xFFFF0000u), (b1[6]>>16)|(b1[7]&0xFFFF0000u) };
    U2 = (uint4v){ (b2[0]>>16)|(b2[1]&0xFFFF0000u), (b2[2]>>16)|(b2[3]&0xFFFF0000u),
                   (b2[4]>>16)|(b2[5]&0xFFFF0000u), (b2[6]>>16)|(b2[7]&0xFFFF0000u) };
}

// ---------------------------------------------------------------------------
// GEMM:  C[M,N] = A[M,K] * B[N,K]^T + bias[N]   via bf16-split MFMA.
// A split x3, B split x2, 4 products (a1b1,a2b1,a1b2,a3b1; dropped a2b2).
// ---------------------------------------------------------------------------
__global__ __launch_bounds__(256, 2)
void gemm_bt_mfma(const float* __restrict__ A, int lda,
                  const float* __restrict__ B, int ldb,
                  const float* __restrict__ bias,
                  float* __restrict__ C, int ldc, int K,
                  int nbx, size_t segA, size_t segB, int segBias, size_t segC)
{
    __shared__ __align__(16) float As[2][128 * 32];
    __shared__ __align__(16) float Bs[2][128 * 32];

    const int seg = blockIdx.x / nbx;
    const int bxs = blockIdx.x - seg * nbx;
    const int bm  = blockIdx.y * 128;
    const int bn  = bxs * 128;
    A    += (size_t)seg * segA;
    B    += (size_t)seg * segB;
    bias += seg * segBias;
    C    += (size_t)seg * segC;

    const int t    = threadIdx.x;
    const int wid  = t >> 6;
    const int lane = t & 63;
    const int wr   = wid >> 1;
    const int wc   = wid & 1;
    const int cl   = lane & 15;
    const int kq   = lane >> 4;
    const int lrow = lane >> 3;
    const int gs   = lane & 7;

    auto stage = [&](int buf, int k0) {
        const int gl = gs ^ lrow;
#pragma unroll
        for (int q = 0; q < 4; ++q) {
            const int r0  = (wid * 4 + q) * 8;
            const int row = r0 + lrow;
            async_copy16(A + (size_t)(bm + row) * lda + k0 + (gl << 2),
                         &As[buf][r0 * 32]);
            async_copy16(B + (size_t)(bn + row) * ldb + k0 + (gl << 2),
                         &Bs[buf][r0 * 32]);
        }
    };

    f32x4 acc[4][4];
#pragma unroll
    for (int m = 0; m < 4; ++m)
#pragma unroll
        for (int n = 0; n < 4; ++n) acc[m][n] = (f32x4)(0.f);

    const int NT = K >> 5;
    stage(0, 0);

    for (int it = 0; it < NT; ++it) {
        __syncthreads();
        if (it + 1 < NT)
            stage((it + 1) & 1, (it + 1) << 5);

        const float* as = As[it & 1];
        const float* bs = Bs[it & 1];

        short8v A1[4], A2[4], A3[4], B1[4], B2[4];
#pragma unroll
        for (int m = 0; m < 4; ++m) {
            const int r  = wr * 64 + m * 16 + cl;
            const int s1 = (2 * kq) ^ (r & 7);
            const float4 lo = *reinterpret_cast<const float4*>(as + r * 32 + (s1 << 2));
            const float4 hi = *reinterpret_cast<const float4*>(as + r * 32 + ((s1 ^ 1) << 2));
            short8v h1, h2, h3;
            SPL(lo.x, 0) SPL(lo.y, 1) SPL(lo.z, 2) SPL(lo.w, 3)
            SPL(hi.x, 4) SPL(hi.y, 5) SPL(hi.z, 6) SPL(hi.w, 7)
            A1[m] = h1; A2[m] = h2; A3[m] = h3;
        }
#pragma unroll
        for (int n = 0; n < 4; ++n) {
            const int r  = wc * 64 + n * 16 + cl;
            const int s1 = (2 * kq) ^ (r & 7);
            const float4 lo = *reinterpret_cast<const float4*>(bs + r * 32 + (s1 << 2));
            const float4 hi = *reinterpret_cast<const float4*>(bs + r * 32 + ((s1 ^ 1) << 2));
            short8v h1, h2;
            SPL2(lo.x, 0) SPL2(lo.y, 1) SPL2(lo.z, 2) SPL2(lo.w, 3)
            SPL2(hi.x, 4) SPL2(hi.y, 5) SPL2(hi.z, 6) SPL2(hi.w, 7)
            B1[n] = h1; B2[n] = h2;
        }

#pragma unroll
        for (int m = 0; m < 4; ++m)
#pragma unroll
            for (int n = 0; n < 4; ++n) {
                f32x4 c = acc[m][n];
                c = __builtin_amdgcn_mfma_f32_16x16x32_bf16(A1[m], B1[n], c, 0, 0, 0);
                c = __builtin_amdgcn_mfma_f32_16x16x32_bf16(A2[m], B1[n], c, 0, 0, 0);
                c = __builtin_amdgcn_mfma_f32_16x16x32_bf16(A1[m], B2[n], c, 0, 0, 0);
                c = __builtin_amdgcn_mfma_f32_16x16x32_bf16(A3[m], B1[n], c, 0, 0, 0);
                acc[m][n] = c;
            }
    }

    const int rw = lane >> 4;
#pragma unroll
    for (int n = 0; n < 4; ++n) {
        const int col = bn + wc * 64 + n * 16 + cl;
        const float bv = bias[col];
#pragma unroll
        for (int m = 0; m < 4; ++m) {
            const size_t rbase = (size_t)(bm + wr * 64 + m * 16 + rw * 4);
#pragma unroll
            for (int i = 0; i < 4; ++i)
                C[(rbase + i) * ldc + col] = acc[m][n][i] + bv;
        }
    }
}

// ---------------------------------------------------------------------------
// RoPE
// ---------------------------------------------------------------------------
__global__ void rope_table(float* __restrict__ tab)
{
    const int idx = blockIdx.x * 256 + threadIdx.x;
    const int s = idx >> 5;
    const int i = idx & 31;
    const double inv = pow(10000.0, -(double)(2 * i) / 64.0);
    const double f = (double)s * inv;
    tab[idx * 2 + 0] = (float)cos(f);
    tab[idx * 2 + 1] = (float)sin(f);
}

__global__ void rope_apply(float* __restrict__ comb, const float* __restrict__ tab)
{
    const int idx = blockIdx.x * 256 + threadIdx.x;
    const int i     = idx & 31;
    const int h     = (idx >> 5) & 15;
    const int row   = (idx >> 9) & (ROWS - 1);
    const int which = idx >> 21;
    const int s     = row & (SEQ - 1);

    const float c  = tab[(s * 32 + i) * 2 + 0];
    const float sn = tab[(s * 32 + i) * 2 + 1];

    float* base = comb + (size_t)row * THREE_D + which * D_MODEL + h * H_DIM;
    const float t1 = base[i];
    const float t2 = base[i + 32];
    base[i]      = t1 * c - t2 * sn;
    base[i + 32] = t2 * c + t1 * sn;
}

// ---------------------------------------------------------------------------
// Flash attention, bf16-split MFMA, kv-split 2x.
// grid = (SEQ/128, BATCH*N_HEADS, 2).  256 threads = 4 waves x 32 q-rows.
// R4 inline-staging schedule (VGPR-lean) + swz8 conflict-free LDS keys +
// setprio around MFMA clusters.  Q x2 planes, K x2 -> 3-product QK; PV 3.
// ---------------------------------------------------------------------------
__global__ __launch_bounds__(256)
void attn_mfma(const float* __restrict__ Qg, const float* __restrict__ Kg,
               const float* __restrict__ Vg,
               float* __restrict__ Pacc, float* __restrict__ Pml)
{
    __shared__ __align__(16) short Ks1[64 * 64];
    __shared__ __align__(16) short Ks2[64 * 64];
    __shared__ __align__(16) short Vt1[64 * 64];
    __shared__ __align__(16) short Vt2[64 * 64];
    __shared__ __align__(16) short Ps[4 * 2 * 16 * 64];   // [wave][plane][q16][k64]

    const int bh   = blockIdx.y;
    const int b    = bh >> 4;
    const int h    = bh & 15;
    const int q0   = blockIdx.x * 128;
    const int half = blockIdx.z;
    const size_t rowBase = (size_t)b * SEQ;
    const int hOff = h * H_DIM;

    const int t    = threadIdx.x;
    const int w    = t >> 6;
    const int lane = t & 63;
    const int cl   = lane & 15;
    const int g    = lane >> 4;

    // staging lane roles
    const int krow = t >> 2;            // K: row k
    const int dob  = (t & 3) * 2;       // K: logical octet base
    const int vkq  = t >> 4;            // V: k = 4*vkq + r
    const int vdq  = t & 15;            // V: d = 4*vdq + rr

    // ---- Q fragments (B-operand), 2 planes, pre-scaled
    Frag qf[2][2][2];   // [qs][c][plane]
#pragma unroll
    for (int qs = 0; qs < 2; ++qs)
#pragma unroll
        for (int c = 0; c < 2; ++c) {
            const float* qp = Qg + (rowBase + q0 + w * 32 + qs * 16 + cl) * D_MODEL
                              + hOff + c * 32 + g * 8;
            const float4 f0 = *reinterpret_cast<const float4*>(qp);
            const float4 f1 = *reinterpret_cast<const float4*>(qp + 4);
            float v[8] = { f0.x * QK_SCALE, f0.y * QK_SCALE, f0.z * QK_SCALE, f0.w * QK_SCALE,
                           f1.x * QK_SCALE, f1.y * QK_SCALE, f1.z * QK_SCALE, f1.w * QK_SCALE };
            split2x8(v, qf[qs][c][0].u, qf[qs][c][1].u);
        }

    f32x4 acc[2][4];
#pragma unroll
    for (int qs = 0; qs < 2; ++qs)
#pragma unroll
        for (int s = 0; s < 4; ++s) acc[qs][s] = (f32x4)(0.f);
    float m[2] = { -1e30f, -1e30f };
    float l[2] = { 0.f, 0.f };

    const int kbase = half * (SEQ / 2);
    for (int kt = 0; kt < SEQ / 2; kt += 64) {
        const int k0 = kbase + kt;
        __syncthreads();   // previous tile LDS reads complete

        // ---- stage K: rows k (64), cols d (64), 2 planes, swz8 octets
        {
            const float* kp = Kg + (rowBase + k0 + krow) * D_MODEL + hOff + dob * 8;
            float v[16];
            *reinterpret_cast<float4*>(&v[0])  = reinterpret_cast<const float4*>(kp)[0];
            *reinterpret_cast<float4*>(&v[4])  = reinterpret_cast<const float4*>(kp)[1];
            *reinterpret_cast<float4*>(&v[8])  = reinterpret_cast<const float4*>(kp)[2];
            *reinterpret_cast<float4*>(&v[12]) = reinterpret_cast<const float4*>(kp)[3];
            uint4v a1, a2, b1, b2;
            split2x8(v,     a1, a2);
            split2x8(v + 8, b1, b2);
            short* kb1 = Ks1 + krow * 64;
            short* kb2 = Ks2 + krow * 64;
            *reinterpret_cast<uint4v*>(kb1 + swz8(krow, dob    ) * 8) = a1;
            *reinterpret_cast<uint4v*>(kb1 + swz8(krow, dob + 1) * 8) = b1;
            *reinterpret_cast<uint4v*>(kb2 + swz8(krow, dob    ) * 8) = a2;
            *reinterpret_cast<uint4v*>(kb2 + swz8(krow, dob + 1) * 8) = b2;
        }

        // ---- stage V^T: rows d (64), cols k (64), 2 planes, 4x4 reg transpose
        {
            const float* vp = Vg + (rowBase + k0 + vkq * 4) * D_MODEL + hOff + vdq * 4;
            float va[4][4];
            *reinterpret_cast<float4*>(va[0]) = *reinterpret_cast<const float4*>(vp);
            *reinterpret_cast<float4*>(va[1]) = *reinterpret_cast<const float4*>(vp + D_MODEL);
            *reinterpret_cast<float4*>(va[2]) = *reinterpret_cast<const float4*>(vp + 2 * D_MODEL);
            *reinterpret_cast<float4*>(va[3]) = *reinterpret_cast<const float4*>(vp + 3 * D_MODEL);
            const int lo = vkq >> 1;
            const int hf = (vkq & 1) * 4;
#pragma unroll
            for (int rr = 0; rr < 4; ++rr) {
                const int row = 4 * vdq + rr;
                unsigned ub[4], rb[4];
#pragma unroll
                for (int r = 0; r < 4; ++r) {
                    const float x = va[r][rr];
                    const unsigned u = __float_as_uint(x);
                    ub[r] = u;
                    rb[r] = __float_as_uint(x - __uint_as_float(u & 0xFFFF0000u));
                }
                uint2v w1, w2;
                w1.x = (ub[0] >> 16) | (ub[1] & 0xFFFF0000u);
                w1.y = (ub[2] >> 16) | (ub[3] & 0xFFFF0000u);
                w2.x = (rb[0] >> 16) | (rb[1] & 0xFFFF0000u);
                w2.y = (rb[2] >> 16) | (rb[3] & 0xFFFF0000u);
                const int o = row * 64 + swz8(row, lo) * 8 + hf;
                *reinterpret_cast<uint2v*>(&Vt1[o]) = w1;
                *reinterpret_cast<uint2v*>(&Vt2[o]) = w2;
            }
        }
        __syncthreads();

        // ---- QK^T (swapped): sacc[qs][ks], k = 16ks+4g+i, q = cl
        f32x4 sacc[2][4];
#pragma unroll
        for (int qs = 0; qs < 2; ++qs)
#pragma unroll
            for (int ks = 0; ks < 4; ++ks) sacc[qs][ks] = (f32x4)(0.f);

        __builtin_amdgcn_s_setprio(1);
#pragma unroll
        for (int ks = 0; ks < 4; ++ks)
#pragma unroll
            for (int c = 0; c < 2; ++c) {
                const int row = ks * 16 + cl;
                const int po  = row * 64 + swz8(row, 4 * c + g) * 8;
                Frag ka1, ka2;
                ka1.s = *reinterpret_cast<const short8v*>(&Ks1[po]);
                ka2.s = *reinterpret_cast<const short8v*>(&Ks2[po]);
#pragma unroll
                for (int qs = 0; qs < 2; ++qs) {
                    f32x4 s = sacc[qs][ks];
                    s = __builtin_amdgcn_mfma_f32_16x16x32_bf16(ka1.s, qf[qs][c][0].s, s, 0, 0, 0);
                    s = __builtin_amdgcn_mfma_f32_16x16x32_bf16(ka2.s, qf[qs][c][0].s, s, 0, 0, 0);
                    s = __builtin_amdgcn_mfma_f32_16x16x32_bf16(ka1.s, qf[qs][c][1].s, s, 0, 0, 0);
                    sacc[qs][ks] = s;
                }
            }
        __builtin_amdgcn_s_setprio(0);

        // ---- per-qs: softmax -> P (per-wave LDS, 2 planes) -> PV
        short* pb1 = Ps + ((w * 2 + 0) * 16 + cl) * 64;
        short* pb2 = Ps + ((w * 2 + 1) * 16 + cl) * 64;

#pragma unroll
        for (int qs = 0; qs < 2; ++qs) {
            float tm = -1e30f;
#pragma unroll
            for (int ks = 0; ks < 4; ++ks)
#pragma unroll
                for (int i = 0; i < 4; ++i) tm = fmaxf(tm, sacc[qs][ks][i]);
            tm = fmaxf(tm, __shfl_xor(tm, 16));
            tm = fmaxf(tm, __shfl_xor(tm, 32));

            const float mn = fmaxf(m[qs], tm);
            const float sc = __builtin_amdgcn_exp2f(m[qs] - mn);
            m[qs] = mn;

            float rs = 0.f;
            uint2v P1[4], P2[4];
#pragma unroll
            for (int ks = 0; ks < 4; ++ks) {
                float p[4];
                unsigned ub[4], rb[4];
#pragma unroll
                for (int i = 0; i < 4; ++i) {
                    p[i] = __builtin_amdgcn_exp2f(sacc[qs][ks][i] - mn);
                    rs += p[i];
                    const unsigned u = __float_as_uint(p[i]);
                    ub[i] = u;
                    rb[i] = __float_as_uint(p[i] - __uint_as_float(u & 0xFFFF0000u));
                }
                P1[ks] = (uint2v){ (ub[0] >> 16) | (ub[1] & 0xFFFF0000u),
                                   (ub[2] >> 16) | (ub[3] & 0xFFFF0000u) };
                P2[ks] = (uint2v){ (rb[0] >> 16) | (rb[1] & 0xFFFF0000u),
                                   (rb[2] >> 16) | (rb[3] & 0xFFFF0000u) };
            }
            rs += __shfl_xor(rs, 16);
            rs += __shfl_xor(rs, 32);
            l[qs] = l[qs] * sc + rs;

            // rescale acc rows (q = 4g+i; sc lives at lane cl = q)
            float scv[4];
#pragma unroll
            for (int i = 0; i < 4; ++i) scv[i] = __shfl(sc, 4 * g + i);
#pragma unroll
            for (int s = 0; s < 4; ++s)
#pragma unroll
                for (int i = 0; i < 4; ++i) acc[qs][s][i] *= scv[i];

            // write P to per-wave LDS (row q = cl, k = 16ks+4g+i)
#pragma unroll
            for (int ks = 0; ks < 4; ++ks) {
                const int off = swz8(cl, 2 * ks + (g >> 1)) * 8 + (g & 1) * 4;
                *reinterpret_cast<uint2v*>(pb1 + off) = P1[ks];
                *reinterpret_cast<uint2v*>(pb2 + off) = P2[ks];
            }

            // PV: A = P (A-frag: row q = cl), B = V^T
            __builtin_amdgcn_s_setprio(1);
#pragma unroll
            for (int c = 0; c < 2; ++c) {
                const int po = swz8(cl, 4 * c + g) * 8;
                Frag pa1, pa2;
                pa1.s = *reinterpret_cast<const short8v*>(pb1 + po);
                pa2.s = *reinterpret_cast<const short8v*>(pb2 + po);
#pragma unroll
                for (int s = 0; s < 4; ++s) {
                    const int row = s * 16 + cl;
                    const int vo  = row * 64 + swz8(row, 4 * c + g) * 8;
                    Frag vb1, vb2;
                    vb1.s = *reinterpret_cast<const short8v*>(&Vt1[vo]);
                    vb2.s = *reinterpret_cast<const short8v*>(&Vt2[vo]);
                    f32x4 a = acc[qs][s];
                    a = __builtin_amdgcn_mfma_f32_16x16x32_bf16(pa1.s, vb1.s, a, 0, 0, 0);
                    a = __builtin_amdgcn_mfma_f32_16x16x32_bf16(pa2.s, vb1.s, a, 0, 0, 0);
                    a = __builtin_amdgcn_mfma_f32_16x16x32_bf16(pa1.s, vb2.s, a, 0, 0, 0);
                    acc[qs][s] = a;
                }
            }
            __builtin_amdgcn_s_setprio(0);
        }
    }

    // ---- store partials (raw acc + m,l); combine kernel normalizes
    const int pblk = (half * 32 + bh) * 16 + blockIdx.x;
    float* ab = Pacc + (size_t)pblk * (128 * 64);
#pragma unroll
    for (int qs = 0; qs < 2; ++qs) {
#pragma unroll
        for (int s = 0; s < 4; ++s)
#pragma unroll
            for (int i = 0; i < 4; ++i)
                ab[(w * 32 + qs * 16 + 4 * g + i) * 64 + s * 16 + cl] = acc[qs][s][i];
        if (g == 0) {
            float2 ml; ml.x = m[qs]; ml.y = l[qs];
            reinterpret_cast<float2*>(Pml)[pblk * 128 + w * 32 + qs * 16 + cl] = ml;
        }
    }
}

// ---------------------------------------------------------------------------
// Combine the two kv-half partials and normalize -> ctx.
// ---------------------------------------------------------------------------
__global__ __launch_bounds__(256)
void attn_combine(const float* __restrict__ Pacc, const float* __restrict__ Pml,
                  float* __restrict__ ctx)
{
    const int tid = blockIdx.x * 256 + threadIdx.x;    // 0 .. ROWS*D_MODEL/4-1
    const int col = (tid & 255) * 4;                   // 0..1020
    const int row = tid >> 8;                          // 0..4095
    const int b = row >> 11, s = row & 2047;
    const int h = col >> 6,  d = col & 63;
    const int p0 = (b * 16 + h) * 16 + (s >> 7);
    const int q  = s & 127;

    const float2 mlA = reinterpret_cast<const float2*>(Pml)[p0 * 128 + q];
    const float2 mlB = reinterpret_cast<const float2*>(Pml)[(p0 + 512) * 128 + q];
    const float4 a = *reinterpret_cast<const float4*>(
        Pacc + ((size_t)p0 * 128 + q) * 64 + d);
    const float4 c = *reinterpret_cast<const float4*>(
        Pacc + ((size_t)(p0 + 512) * 128 + q) * 64 + d);

    const float mf = fmaxf(mlA.x, mlB.x);
    const float wa = __builtin_amdgcn_exp2f(mlA.x - mf);
    const float wb = __builtin_amdgcn_exp2f(mlB.x - mf);
    const float inv = 1.f / (wa * mlA.y + wb * mlB.y);

    float4 o;
    o.x = (wa * a.x + wb * c.x) * inv;
    o.y = (wa * a.y + wb * c.y) * inv;
    o.z = (wa * a.z + wb * c.z) * inv;
    o.w = (wa * a.w + wb * c.w) * inv;
    *reinterpret_cast<float4*>(&ctx[(size_t)row * D_MODEL + col]) = o;
}

// ---------------------------------------------------------------------------
extern "C" void kernel_launch(void* const* d_in, const int* in_sizes, int n_in,
                              void* d_out, int out_size, void* d_ws, size_t ws_size,
                              hipStream_t stream)
{
    const float* x    = (const float*)d_in[0];
    const float* Win  = (const float*)d_in[1];   // (3072, 1024)
    const float* bin  = (const float*)d_in[2];   // (3072,)
    const float* Wout = (const float*)d_in[3];   // (1024, 1024)
    const float* bout = (const float*)d_in[4];   // (1024,)
    float* out = (float*)d_out;

    float* combined = (float*)d_ws;                                  // ROWS x 3072
    float* qkv  = combined + (size_t)ROWS * THREE_D;                 // 3 x ROWS x 1024
    float* qbuf = qkv;
    float* kbuf = qkv + (size_t)ROWS * D_MODEL;
    float* vbuf = kbuf + (size_t)ROWS * D_MODEL;
    float* tab  = vbuf + (size_t)ROWS * D_MODEL;                     // SEQ*32*2
    float* Pml  = tab + (size_t)SEQ * 64;                            // 1024*128*2
    float* ctx  = combined;                                          // ROWS x 1024
    float* Pacc = combined + (size_t)ROWS * D_MODEL;                 // 1024*128*64

    const dim3 blk(256);

    rope_table<<<dim3(SEQ * 32 / 256), blk, 0, stream>>>(tab);

    // GEMM1: combined = x @ Win^T + bin
    gemm_bt_mfma<<<dim3(24, 32), blk, 0, stream>>>(
        x, D_MODEL, Win, D_MODEL, bin, combined, THREE_D, D_MODEL,
        24, (size_t)0, (size_t)0, 0, (size_t)0);

    // RoPE in place on q/k thirds of combined
    rope_apply<<<dim3((2 * ROWS * N_HEADS * 32) / 256), blk, 0, stream>>>(combined, tab);

    // fused q/k/v second projection
    gemm_bt_mfma<<<dim3(24, 32), blk, 0, stream>>>(
        combined, THREE_D, Win, D_MODEL, bin, qkv, D_MODEL, D_MODEL,
        8, (size_t)D_MODEL, (size_t)D_MODEL * D_MODEL, D_MODEL,
        (size_t)ROWS * D_MODEL);

    // attention partials (kv-split 2x) then combine -> ctx
    attn_mfma<<<dim3(SEQ / 128, BATCH * N_HEADS, 2), blk, 0, stream>>>(
        qbuf, kbuf, vbuf, Pacc, Pml);
    attn_combine<<<dim3(ROWS * D_MODEL / 4 / 256), blk, 0, stream>>>(Pacc, Pml, ctx);

    // GEMM3: out = ctx @ Wout^T + bout
    gemm_bt_mfma<<<dim3(8, 32), blk, 0, stream>>>(
        ctx, D_MODEL, Wout, D_MODEL, bout, out, D_MODEL, D_MODEL,
        8, (size_t)0, (size_t)0, 0, (size_t)0);
}

// Round 8
// 521.200 us; speedup vs baseline: 1.1305x; 1.0200x over previous
//
#include <hip/hip_runtime.h>
#include <math.h>

#define D_MODEL   1024
#define N_HEADS   16
#define H_DIM     64
#define SEQ       2048
#define BATCH     2
#define ROWS      (BATCH * SEQ)        // 4096
#define THREE_D   (3 * D_MODEL)       // 3072

// q pre-scale: 1/sqrt(64) * log2(e)  -> softmax in exp2 domain
#define QK_SCALE  (0.125f * 1.44269504088896340736f)

typedef __attribute__((ext_vector_type(8))) short short8v;   // 8 bf16
typedef __attribute__((ext_vector_type(4))) float f32x4;
typedef __attribute__((ext_vector_type(4))) unsigned int uint4v;
typedef __attribute__((ext_vector_type(2))) unsigned int uint2v;

union Frag { uint4v u; short8v s; };

__device__ __forceinline__ void async_copy16(const float* g, float* l)
{
    __builtin_amdgcn_global_load_lds(
        (const __attribute__((address_space(1))) void*)g,
        (__attribute__((address_space(3))) void*)l,
        16, 0, 0);
}

// LDS octet swizzle key: spreads banks for BOTH row-strided (stride-4) write
// groups and 16-row fragment read groups.  Used at every K/V/P LDS site.
__device__ __forceinline__ int swz8(int row, int oct)
{
    return oct ^ ((row ^ (row >> 2)) & 7);
}

// split fp32 -> 3 bf16 planes (truncation)
#define SPL(x, j)                                                          \
    {                                                                      \
        const float x_ = (x);                                              \
        const unsigned u1_ = __float_as_uint(x_);                          \
        const float r1_ = x_ - __uint_as_float(u1_ & 0xFFFF0000u);         \
        const unsigned u2_ = __float_as_uint(r1_);                         \
        const float r2_ = r1_ - __uint_as_float(u2_ & 0xFFFF0000u);        \
        h1[j] = (short)(u1_ >> 16);                                        \
        h2[j] = (short)(u2_ >> 16);                                        \
        h3[j] = (short)(__float_as_uint(r2_) >> 16);                       \
    }

// split fp32 -> 2 bf16 planes
#define SPL2(x, j)                                                         \
    {                                                                      \
        const float x_ = (x);                                              \
        const unsigned u1_ = __float_as_uint(x_);                          \
        const float r1_ = x_ - __uint_as_float(u1_ & 0xFFFF0000u);         \
        h1[j] = (short)(u1_ >> 16);                                        \
        h2[j] = (short)(__float_as_uint(r1_) >> 16);                       \
    }

// split 8 floats into 2 packed bf16x8 planes
__device__ __forceinline__ void split2x8(const float* v, uint4v& U1, uint4v& U2)
{
    unsigned b1[8], b2[8];
#pragma unroll
    for (int j = 0; j < 8; ++j) {
        const unsigned u = __float_as_uint(v[j]);
        b1[j] = u;
        const float r = v[j] - __uint_as_float(u & 0xFFFF0000u);
        b2[j] = __float_as_uint(r);
    }
    U1 = (uint4v){ (b1[0]>>16)|(b1[1]&0xFFFF0000u), (b1[2]>>16)|(b1[3]&0xFFFF0000u),
                   (b1[4]>>16)|(b1[5]&0xFFFF0000u), (b1[6]>>16)|(b1[7]&0xFFFF0000u) };
    U2 = (uint4v){ (b2[0]>>16)|(b2[1]&0xFFFF0000u), (b2[2]>>16)|(b2[3]&0xFFFF0000u),
                   (b2[4]>>16)|(b2[5]&0xFFFF0000u), (b2[6]>>16)|(b2[7]&0xFFFF0000u) };
}

// ---------------------------------------------------------------------------
// GEMM:  C[M,N] = A[M,K] * B[N,K]^T + bias[N]   via bf16-split MFMA.
// A split x3, B split x2, 4 products (a1b1,a2b1,a1b2,a3b1; dropped a2b2).
// ---------------------------------------------------------------------------
__global__ __launch_bounds__(256, 2)
void gemm_bt_mfma(const float* __restrict__ A, int lda,
                  const float* __restrict__ B, int ldb,
                  const float* __restrict__ bias,
                  float* __restrict__ C, int ldc, int K,
                  int nbx, size_t segA, size_t segB, int segBias, size_t segC)
{
    __shared__ __align__(16) float As[2][128 * 32];
    __shared__ __align__(16) float Bs[2][128 * 32];

    const int seg = blockIdx.x / nbx;
    const int bxs = blockIdx.x - seg * nbx;
    const int bm  = blockIdx.y * 128;
    const int bn  = bxs * 128;
    A    += (size_t)seg * segA;
    B    += (size_t)seg * segB;
    bias += seg * segBias;
    C    += (size_t)seg * segC;

    const int t    = threadIdx.x;
    const int wid  = t >> 6;
    const int lane = t & 63;
    const int wr   = wid >> 1;
    const int wc   = wid & 1;
    const int cl   = lane & 15;
    const int kq   = lane >> 4;
    const int lrow = lane >> 3;
    const int gs   = lane & 7;

    auto stage = [&](int buf, int k0) {
        const int gl = gs ^ lrow;
#pragma unroll
        for (int q = 0; q < 4; ++q) {
            const int r0  = (wid * 4 + q) * 8;
            const int row = r0 + lrow;
            async_copy16(A + (size_t)(bm + row) * lda + k0 + (gl << 2),
                         &As[buf][r0 * 32]);
            async_copy16(B + (size_t)(bn + row) * ldb + k0 + (gl << 2),
                         &Bs[buf][r0 * 32]);
        }
    };

    f32x4 acc[4][4];
#pragma unroll
    for (int m = 0; m < 4; ++m)
#pragma unroll
        for (int n = 0; n < 4; ++n) acc[m][n] = (f32x4)(0.f);

    const int NT = K >> 5;
    stage(0, 0);

    for (int it = 0; it < NT; ++it) {
        __syncthreads();
        if (it + 1 < NT)
            stage((it + 1) & 1, (it + 1) << 5);

        const float* as = As[it & 1];
        const float* bs = Bs[it & 1];

        short8v A1[4], A2[4], A3[4], B1[4], B2[4];
#pragma unroll
        for (int m = 0; m < 4; ++m) {
            const int r  = wr * 64 + m * 16 + cl;
            const int s1 = (2 * kq) ^ (r & 7);
            const float4 lo = *reinterpret_cast<const float4*>(as + r * 32 + (s1 << 2));
            const float4 hi = *reinterpret_cast<const float4*>(as + r * 32 + ((s1 ^ 1) << 2));
            short8v h1, h2, h3;
            SPL(lo.x, 0) SPL(lo.y, 1) SPL(lo.z, 2) SPL(lo.w, 3)
            SPL(hi.x, 4) SPL(hi.y, 5) SPL(hi.z, 6) SPL(hi.w, 7)
            A1[m] = h1; A2[m] = h2; A3[m] = h3;
        }
#pragma unroll
        for (int n = 0; n < 4; ++n) {
            const int r  = wc * 64 + n * 16 + cl;
            const int s1 = (2 * kq) ^ (r & 7);
            const float4 lo = *reinterpret_cast<const float4*>(bs + r * 32 + (s1 << 2));
            const float4 hi = *reinterpret_cast<const float4*>(bs + r * 32 + ((s1 ^ 1) << 2));
            short8v h1, h2;
            SPL2(lo.x, 0) SPL2(lo.y, 1) SPL2(lo.z, 2) SPL2(lo.w, 3)
            SPL2(hi.x, 4) SPL2(hi.y, 5) SPL2(hi.z, 6) SPL2(hi.w, 7)
            B1[n] = h1; B2[n] = h2;
        }

#pragma unroll
        for (int m = 0; m < 4; ++m)
#pragma unroll
            for (int n = 0; n < 4; ++n) {
                f32x4 c = acc[m][n];
                c = __builtin_amdgcn_mfma_f32_16x16x32_bf16(A1[m], B1[n], c, 0, 0, 0);
                c = __builtin_amdgcn_mfma_f32_16x16x32_bf16(A2[m], B1[n], c, 0, 0, 0);
                c = __builtin_amdgcn_mfma_f32_16x16x32_bf16(A1[m], B2[n], c, 0, 0, 0);
                c = __builtin_amdgcn_mfma_f32_16x16x32_bf16(A3[m], B1[n], c, 0, 0, 0);
                acc[m][n] = c;
            }
    }

    const int rw = lane >> 4;
#pragma unroll
    for (int n = 0; n < 4; ++n) {
        const int col = bn + wc * 64 + n * 16 + cl;
        const float bv = bias[col];
#pragma unroll
        for (int m = 0; m < 4; ++m) {
            const size_t rbase = (size_t)(bm + wr * 64 + m * 16 + rw * 4);
#pragma unroll
            for (int i = 0; i < 4; ++i)
                C[(rbase + i) * ldc + col] = acc[m][n][i] + bv;
        }
    }
}

// ---------------------------------------------------------------------------
// RoPE
// ---------------------------------------------------------------------------
__global__ void rope_table(float* __restrict__ tab)
{
    const int idx = blockIdx.x * 256 + threadIdx.x;
    const int s = idx >> 5;
    const int i = idx & 31;
    const double inv = pow(10000.0, -(double)(2 * i) / 64.0);
    const double f = (double)s * inv;
    tab[idx * 2 + 0] = (float)cos(f);
    tab[idx * 2 + 1] = (float)sin(f);
}

__global__ void rope_apply(float* __restrict__ comb, const float* __restrict__ tab)
{
    const int idx = blockIdx.x * 256 + threadIdx.x;
    const int i     = idx & 31;
    const int h     = (idx >> 5) & 15;
    const int row   = (idx >> 9) & (ROWS - 1);
    const int which = idx >> 21;
    const int s     = row & (SEQ - 1);

    const float c  = tab[(s * 32 + i) * 2 + 0];
    const float sn = tab[(s * 32 + i) * 2 + 1];

    float* base = comb + (size_t)row * THREE_D + which * D_MODEL + h * H_DIM;
    const float t1 = base[i];
    const float t2 = base[i + 32];
    base[i]      = t1 * c - t2 * sn;
    base[i + 32] = t2 * c + t1 * sn;
}

// ---------------------------------------------------------------------------
// Flash attention, bf16-split MFMA, kv-split 2x.
// grid = (SEQ/128, BATCH*N_HEADS, 2).  256 threads = 4 waves x 32 q-rows.
// R4 inline-staging schedule + swz8 conflict-free LDS keys.  Q x2 planes,
// K x2 -> 3-product QK; PV 3 products.  launch_bounds(256,4) pins VGPR<=128
// (the m69 occupancy cliff: >128 VGPR halves waves/SIMD).  No setprio
// (4-wave lockstep block = m190 regime where setprio measured negative).
// ---------------------------------------------------------------------------
__global__ __launch_bounds__(256, 4)
void attn_mfma(const float* __restrict__ Qg, const float* __restrict__ Kg,
               const float* __restrict__ Vg,
               float* __restrict__ Pacc, float* __restrict__ Pml)
{
    __shared__ __align__(16) short Ks1[64 * 64];
    __shared__ __align__(16) short Ks2[64 * 64];
    __shared__ __align__(16) short Vt1[64 * 64];
    __shared__ __align__(16) short Vt2[64 * 64];
    __shared__ __align__(16) short Ps[4 * 2 * 16 * 64];   // [wave][plane][q16][k64]

    const int bh   = blockIdx.y;
    const int b    = bh >> 4;
    const int h    = bh & 15;
    const int q0   = blockIdx.x * 128;
    const int half = blockIdx.z;
    const size_t rowBase = (size_t)b * SEQ;
    const int hOff = h * H_DIM;

    const int t    = threadIdx.x;
    const int w    = t >> 6;
    const int lane = t & 63;
    const int cl   = lane & 15;
    const int g    = lane >> 4;

    // staging lane roles
    const int krow = t >> 2;            // K: row k
    const int dob  = (t & 3) * 2;       // K: logical octet base
    const int vkq  = t >> 4;            // V: k = 4*vkq + r
    const int vdq  = t & 15;            // V: d = 4*vdq + rr

    // ---- Q fragments (B-operand), 2 planes, pre-scaled
    Frag qf[2][2][2];   // [qs][c][plane]
#pragma unroll
    for (int qs = 0; qs < 2; ++qs)
#pragma unroll
        for (int c = 0; c < 2; ++c) {
            const float* qp = Qg + (rowBase + q0 + w * 32 + qs * 16 + cl) * D_MODEL
                              + hOff + c * 32 + g * 8;
            const float4 f0 = *reinterpret_cast<const float4*>(qp);
            const float4 f1 = *reinterpret_cast<const float4*>(qp + 4);
            float v[8] = { f0.x * QK_SCALE, f0.y * QK_SCALE, f0.z * QK_SCALE, f0.w * QK_SCALE,
                           f1.x * QK_SCALE, f1.y * QK_SCALE, f1.z * QK_SCALE, f1.w * QK_SCALE };
            split2x8(v, qf[qs][c][0].u, qf[qs][c][1].u);
        }

    f32x4 acc[2][4];
#pragma unroll
    for (int qs = 0; qs < 2; ++qs)
#pragma unroll
        for (int s = 0; s < 4; ++s) acc[qs][s] = (f32x4)(0.f);
    float m[2] = { -1e30f, -1e30f };
    float l[2] = { 0.f, 0.f };

    const int kbase = half * (SEQ / 2);
    for (int kt = 0; kt < SEQ / 2; kt += 64) {
        const int k0 = kbase + kt;
        __syncthreads();   // previous tile LDS reads complete

        // ---- stage K: rows k (64), cols d (64), 2 planes, swz8 octets
        {
            const float* kp = Kg + (rowBase + k0 + krow) * D_MODEL + hOff + dob * 8;
            float v[16];
            *reinterpret_cast<float4*>(&v[0])  = reinterpret_cast<const float4*>(kp)[0];
            *reinterpret_cast<float4*>(&v[4])  = reinterpret_cast<const float4*>(kp)[1];
            *reinterpret_cast<float4*>(&v[8])  = reinterpret_cast<const float4*>(kp)[2];
            *reinterpret_cast<float4*>(&v[12]) = reinterpret_cast<const float4*>(kp)[3];
            uint4v a1, a2, b1, b2;
            split2x8(v,     a1, a2);
            split2x8(v + 8, b1, b2);
            short* kb1 = Ks1 + krow * 64;
            short* kb2 = Ks2 + krow * 64;
            *reinterpret_cast<uint4v*>(kb1 + swz8(krow, dob    ) * 8) = a1;
            *reinterpret_cast<uint4v*>(kb1 + swz8(krow, dob + 1) * 8) = b1;
            *reinterpret_cast<uint4v*>(kb2 + swz8(krow, dob    ) * 8) = a2;
            *reinterpret_cast<uint4v*>(kb2 + swz8(krow, dob + 1) * 8) = b2;
        }

        // ---- stage V^T: rows d (64), cols k (64), 2 planes, 4x4 reg transpose
        {
            const float* vp = Vg + (rowBase + k0 + vkq * 4) * D_MODEL + hOff + vdq * 4;
            float va[4][4];
            *reinterpret_cast<float4*>(va[0]) = *reinterpret_cast<const float4*>(vp);
            *reinterpret_cast<float4*>(va[1]) = *reinterpret_cast<const float4*>(vp + D_MODEL);
            *reinterpret_cast<float4*>(va[2]) = *reinterpret_cast<const float4*>(vp + 2 * D_MODEL);
            *reinterpret_cast<float4*>(va[3]) = *reinterpret_cast<const float4*>(vp + 3 * D_MODEL);
            const int lo = vkq >> 1;
            const int hf = (vkq & 1) * 4;
#pragma unroll
            for (int rr = 0; rr < 4; ++rr) {
                const int row = 4 * vdq + rr;
                unsigned ub[4], rb[4];
#pragma unroll
                for (int r = 0; r < 4; ++r) {
                    const float x = va[r][rr];
                    const unsigned u = __float_as_uint(x);
                    ub[r] = u;
                    rb[r] = __float_as_uint(x - __uint_as_float(u & 0xFFFF0000u));
                }
                uint2v w1, w2;
                w1.x = (ub[0] >> 16) | (ub[1] & 0xFFFF0000u);
                w1.y = (ub[2] >> 16) | (ub[3] & 0xFFFF0000u);
                w2.x = (rb[0] >> 16) | (rb[1] & 0xFFFF0000u);
                w2.y = (rb[2] >> 16) | (rb[3] & 0xFFFF0000u);
                const int o = row * 64 + swz8(row, lo) * 8 + hf;
                *reinterpret_cast<uint2v*>(&Vt1[o]) = w1;
                *reinterpret_cast<uint2v*>(&Vt2[o]) = w2;
            }
        }
        __syncthreads();

        // ---- QK^T (swapped): sacc[qs][ks], k = 16ks+4g+i, q = cl
        f32x4 sacc[2][4];
#pragma unroll
        for (int qs = 0; qs < 2; ++qs)
#pragma unroll
            for (int ks = 0; ks < 4; ++ks) sacc[qs][ks] = (f32x4)(0.f);

#pragma unroll
        for (int ks = 0; ks < 4; ++ks)
#pragma unroll
            for (int c = 0; c < 2; ++c) {
                const int row = ks * 16 + cl;
                const int po  = row * 64 + swz8(row, 4 * c + g) * 8;
                Frag ka1, ka2;
                ka1.s = *reinterpret_cast<const short8v*>(&Ks1[po]);
                ka2.s = *reinterpret_cast<const short8v*>(&Ks2[po]);
#pragma unroll
                for (int qs = 0; qs < 2; ++qs) {
                    f32x4 s = sacc[qs][ks];
                    s = __builtin_amdgcn_mfma_f32_16x16x32_bf16(ka1.s, qf[qs][c][0].s, s, 0, 0, 0);
                    s = __builtin_amdgcn_mfma_f32_16x16x32_bf16(ka2.s, qf[qs][c][0].s, s, 0, 0, 0);
                    s = __builtin_amdgcn_mfma_f32_16x16x32_bf16(ka1.s, qf[qs][c][1].s, s, 0, 0, 0);
                    sacc[qs][ks] = s;
                }
            }

        // ---- per-qs: softmax -> P (per-wave LDS, 2 planes) -> PV
        short* pb1 = Ps + ((w * 2 + 0) * 16 + cl) * 64;
        short* pb2 = Ps + ((w * 2 + 1) * 16 + cl) * 64;

#pragma unroll
        for (int qs = 0; qs < 2; ++qs) {
            float tm = -1e30f;
#pragma unroll
            for (int ks = 0; ks < 4; ++ks)
#pragma unroll
                for (int i = 0; i < 4; ++i) tm = fmaxf(tm, sacc[qs][ks][i]);
            tm = fmaxf(tm, __shfl_xor(tm, 16));
            tm = fmaxf(tm, __shfl_xor(tm, 32));

            const float mn = fmaxf(m[qs], tm);
            const float sc = __builtin_amdgcn_exp2f(m[qs] - mn);
            m[qs] = mn;

            float rs = 0.f;
            uint2v P1[4], P2[4];
#pragma unroll
            for (int ks = 0; ks < 4; ++ks) {
                float p[4];
                unsigned ub[4], rb[4];
#pragma unroll
                for (int i = 0; i < 4; ++i) {
                    p[i] = __builtin_amdgcn_exp2f(sacc[qs][ks][i] - mn);
                    rs += p[i];
                    const unsigned u = __float_as_uint(p[i]);
                    ub[i] = u;
                    rb[i] = __float_as_uint(p[i] - __uint_as_float(u & 0xFFFF0000u));
                }
                P1[ks] = (uint2v){ (ub[0] >> 16) | (ub[1] & 0xFFFF0000u),
                                   (ub[2] >> 16) | (ub[3] & 0xFFFF0000u) };
                P2[ks] = (uint2v){ (rb[0] >> 16) | (rb[1] & 0xFFFF0000u),
                                   (rb[2] >> 16) | (rb[3] & 0xFFFF0000u) };
            }
            rs += __shfl_xor(rs, 16);
            rs += __shfl_xor(rs, 32);
            l[qs] = l[qs] * sc + rs;

            // rescale acc rows (q = 4g+i; sc lives at lane cl = q)
            float scv[4];
#pragma unroll
            for (int i = 0; i < 4; ++i) scv[i] = __shfl(sc, 4 * g + i);
#pragma unroll
            for (int s = 0; s < 4; ++s)
#pragma unroll
                for (int i = 0; i < 4; ++i) acc[qs][s][i] *= scv[i];

            // write P to per-wave LDS (row q = cl, k = 16ks+4g+i)
#pragma unroll
            for (int ks = 0; ks < 4; ++ks) {
                const int off = swz8(cl, 2 * ks + (g >> 1)) * 8 + (g & 1) * 4;
                *reinterpret_cast<uint2v*>(pb1 + off) = P1[ks];
                *reinterpret_cast<uint2v*>(pb2 + off) = P2[ks];
            }

            // PV: A = P (A-frag: row q = cl), B = V^T
#pragma unroll
            for (int c = 0; c < 2; ++c) {
                const int po = swz8(cl, 4 * c + g) * 8;
                Frag pa1, pa2;
                pa1.s = *reinterpret_cast<const short8v*>(pb1 + po);
                pa2.s = *reinterpret_cast<const short8v*>(pb2 + po);
#pragma unroll
                for (int s = 0; s < 4; ++s) {
                    const int row = s * 16 + cl;
                    const int vo  = row * 64 + swz8(row, 4 * c + g) * 8;
                    Frag vb1, vb2;
                    vb1.s = *reinterpret_cast<const short8v*>(&Vt1[vo]);
                    vb2.s = *reinterpret_cast<const short8v*>(&Vt2[vo]);
                    f32x4 a = acc[qs][s];
                    a = __builtin_amdgcn_mfma_f32_16x16x32_bf16(pa1.s, vb1.s, a, 0, 0, 0);
                    a = __builtin_amdgcn_mfma_f32_16x16x32_bf16(pa2.s, vb1.s, a, 0, 0, 0);
                    a = __builtin_amdgcn_mfma_f32_16x16x32_bf16(pa1.s, vb2.s, a, 0, 0, 0);
                    acc[qs][s] = a;
                }
            }
        }
    }

    // ---- store partials (raw acc + m,l); combine kernel normalizes
    const int pblk = (half * 32 + bh) * 16 + blockIdx.x;
    float* ab = Pacc + (size_t)pblk * (128 * 64);
#pragma unroll
    for (int qs = 0; qs < 2; ++qs) {
#pragma unroll
        for (int s = 0; s < 4; ++s)
#pragma unroll
            for (int i = 0; i < 4; ++i)
                ab[(w * 32 + qs * 16 + 4 * g + i) * 64 + s * 16 + cl] = acc[qs][s][i];
        if (g == 0) {
            float2 ml; ml.x = m[qs]; ml.y = l[qs];
            reinterpret_cast<float2*>(Pml)[pblk * 128 + w * 32 + qs * 16 + cl] = ml;
        }
    }
}

// ---------------------------------------------------------------------------
// Combine the two kv-half partials and normalize -> ctx.
// ---------------------------------------------------------------------------
__global__ __launch_bounds__(256)
void attn_combine(const float* __restrict__ Pacc, const float* __restrict__ Pml,
                  float* __restrict__ ctx)
{
    const int tid = blockIdx.x * 256 + threadIdx.x;    // 0 .. ROWS*D_MODEL/4-1
    const int col = (tid & 255) * 4;                   // 0..1020
    const int row = tid >> 8;                          // 0..4095
    const int b = row >> 11, s = row & 2047;
    const int h = col >> 6,  d = col & 63;
    const int p0 = (b * 16 + h) * 16 + (s >> 7);
    const int q  = s & 127;

    const float2 mlA = reinterpret_cast<const float2*>(Pml)[p0 * 128 + q];
    const float2 mlB = reinterpret_cast<const float2*>(Pml)[(p0 + 512) * 128 + q];
    const float4 a = *reinterpret_cast<const float4*>(
        Pacc + ((size_t)p0 * 128 + q) * 64 + d);
    const float4 c = *reinterpret_cast<const float4*>(
        Pacc + ((size_t)(p0 + 512) * 128 + q) * 64 + d);

    const float mf = fmaxf(mlA.x, mlB.x);
    const float wa = __builtin_amdgcn_exp2f(mlA.x - mf);
    const float wb = __builtin_amdgcn_exp2f(mlB.x - mf);
    const float inv = 1.f / (wa * mlA.y + wb * mlB.y);

    float4 o;
    o.x = (wa * a.x + wb * c.x) * inv;
    o.y = (wa * a.y + wb * c.y) * inv;
    o.z = (wa * a.z + wb * c.z) * inv;
    o.w = (wa * a.w + wb * c.w) * inv;
    *reinterpret_cast<float4*>(&ctx[(size_t)row * D_MODEL + col]) = o;
}

// ---------------------------------------------------------------------------
extern "C" void kernel_launch(void* const* d_in, const int* in_sizes, int n_in,
                              void* d_out, int out_size, void* d_ws, size_t ws_size,
                              hipStream_t stream)
{
    const float* x    = (const float*)d_in[0];
    const float* Win  = (const float*)d_in[1];   // (3072, 1024)
    const float* bin  = (const float*)d_in[2];   // (3072,)
    const float* Wout = (const float*)d_in[3];   // (1024, 1024)
    const float* bout = (const float*)d_in[4];   // (1024,)
    float* out = (float*)d_out;

    float* combined = (float*)d_ws;                                  // ROWS x 3072
    float* qkv  = combined + (size_t)ROWS * THREE_D;                 // 3 x ROWS x 1024
    float* qbuf = qkv;
    float* kbuf = qkv + (size_t)ROWS * D_MODEL;
    float* vbuf = kbuf + (size_t)ROWS * D_MODEL;
    float* tab  = vbuf + (size_t)ROWS * D_MODEL;                     // SEQ*32*2
    float* Pml  = tab + (size_t)SEQ * 64;                            // 1024*128*2
    float* ctx  = combined;                                          // ROWS x 1024
    float* Pacc = combined + (size_t)ROWS * D_MODEL;                 // 1024*128*64

    const dim3 blk(256);

    rope_table<<<dim3(SEQ * 32 / 256), blk, 0, stream>>>(tab);

    // GEMM1: combined = x @ Win^T + bin
    gemm_bt_mfma<<<dim3(24, 32), blk, 0, stream>>>(
        x, D_MODEL, Win, D_MODEL, bin, combined, THREE_D, D_MODEL,
        24, (size_t)0, (size_t)0, 0, (size_t)0);

    // RoPE in place on q/k thirds of combined
    rope_apply<<<dim3((2 * ROWS * N_HEADS * 32) / 256), blk, 0, stream>>>(combined, tab);

    // fused q/k/v second projection
    gemm_bt_mfma<<<dim3(24, 32), blk, 0, stream>>>(
        combined, THREE_D, Win, D_MODEL, bin, qkv, D_MODEL, D_MODEL,
        8, (size_t)D_MODEL, (size_t)D_MODEL * D_MODEL, D_MODEL,
        (size_t)ROWS * D_MODEL);

    // attention partials (kv-split 2x) then combine -> ctx
    attn_mfma<<<dim3(SEQ / 128, BATCH * N_HEADS, 2), blk, 0, stream>>>(
        qbuf, kbuf, vbuf, Pacc, Pml);
    attn_combine<<<dim3(ROWS * D_MODEL / 4 / 256), blk, 0, stream>>>(Pacc, Pml, ctx);

    // GEMM3: out = ctx @ Wout^T + bout
    gemm_bt_mfma<<<dim3(8, 32), blk, 0, stream>>>(
        ctx, D_MODEL, Wout, D_MODEL, bout, out, D_MODEL, D_MODEL,
        8, (size_t)0, (size_t)0, 0, (size_t)0);
}

// Round 9
// 475.970 us; speedup vs baseline: 1.2379x; 1.0950x over previous
//
#include <hip/hip_runtime.h>
#include <math.h>

#define D_MODEL   1024
#define N_HEADS   16
#define H_DIM     64
#define SEQ       2048
#define BATCH     2
#define ROWS      (BATCH * SEQ)        // 4096
#define THREE_D   (3 * D_MODEL)       // 3072

// q pre-scale: 1/sqrt(64) * log2(e)  -> softmax in exp2 domain
#define QK_SCALE  (0.125f * 1.44269504088896340736f)

typedef __attribute__((ext_vector_type(8))) short short8v;   // 8 bf16
typedef __attribute__((ext_vector_type(4))) float f32x4;
typedef __attribute__((ext_vector_type(4))) unsigned int uint4v;
typedef __attribute__((ext_vector_type(2))) unsigned int uint2v;

union Frag { uint4v u; short8v s; };

__device__ __forceinline__ void async_copy16(const float* g, float* l)
{
    __builtin_amdgcn_global_load_lds(
        (const __attribute__((address_space(1))) void*)g,
        (__attribute__((address_space(3))) void*)l,
        16, 0, 0);
}

// LDS octet swizzle key: spreads banks for BOTH row-strided (stride-4) write
// groups and 16-row fragment read groups.  Used at every K/V/P LDS site.
__device__ __forceinline__ int swz8(int row, int oct)
{
    return oct ^ ((row ^ (row >> 2)) & 7);
}

// split fp32 -> 3 bf16 planes (truncation)
#define SPL(x, j)                                                          \
    {                                                                      \
        const float x_ = (x);                                              \
        const unsigned u1_ = __float_as_uint(x_);                          \
        const float r1_ = x_ - __uint_as_float(u1_ & 0xFFFF0000u);         \
        const unsigned u2_ = __float_as_uint(r1_);                         \
        const float r2_ = r1_ - __uint_as_float(u2_ & 0xFFFF0000u);        \
        h1[j] = (short)(u1_ >> 16);                                        \
        h2[j] = (short)(u2_ >> 16);                                        \
        h3[j] = (short)(__float_as_uint(r2_) >> 16);                       \
    }

// split fp32 -> 2 bf16 planes
#define SPL2(x, j)                                                         \
    {                                                                      \
        const float x_ = (x);                                              \
        const unsigned u1_ = __float_as_uint(x_);                          \
        const float r1_ = x_ - __uint_as_float(u1_ & 0xFFFF0000u);         \
        h1[j] = (short)(u1_ >> 16);                                        \
        h2[j] = (short)(__float_as_uint(r1_) >> 16);                       \
    }

// split 8 floats into 2 packed bf16x8 planes
__device__ __forceinline__ void split2x8(const float* v, uint4v& U1, uint4v& U2)
{
    unsigned b1[8], b2[8];
#pragma unroll
    for (int j = 0; j < 8; ++j) {
        const unsigned u = __float_as_uint(v[j]);
        b1[j] = u;
        const float r = v[j] - __uint_as_float(u & 0xFFFF0000u);
        b2[j] = __float_as_uint(r);
    }
    U1 = (uint4v){ (b1[0]>>16)|(b1[1]&0xFFFF0000u), (b1[2]>>16)|(b1[3]&0xFFFF0000u),
                   (b1[4]>>16)|(b1[5]&0xFFFF0000u), (b1[6]>>16)|(b1[7]&0xFFFF0000u) };
    U2 = (uint4v){ (b2[0]>>16)|(b2[1]&0xFFFF0000u), (b2[2]>>16)|(b2[3]&0xFFFF0000u),
                   (b2[4]>>16)|(b2[5]&0xFFFF0000u), (b2[6]>>16)|(b2[7]&0xFFFF0000u) };
}

// ---------------------------------------------------------------------------
// GEMM:  C[M,N] = A[M,K] * B[N,K]^T + bias[N]   via bf16-split MFMA.
// A split x3, B split x2, 4 products.  (unchanged — verified)
// ---------------------------------------------------------------------------
__global__ __launch_bounds__(256, 2)
void gemm_bt_mfma(const float* __restrict__ A, int lda,
                  const float* __restrict__ B, int ldb,
                  const float* __restrict__ bias,
                  float* __restrict__ C, int ldc, int K,
                  int nbx, size_t segA, size_t segB, int segBias, size_t segC)
{
    __shared__ __align__(16) float As[2][128 * 32];
    __shared__ __align__(16) float Bs[2][128 * 32];

    const int seg = blockIdx.x / nbx;
    const int bxs = blockIdx.x - seg * nbx;
    const int bm  = blockIdx.y * 128;
    const int bn  = bxs * 128;
    A    += (size_t)seg * segA;
    B    += (size_t)seg * segB;
    bias += seg * segBias;
    C    += (size_t)seg * segC;

    const int t    = threadIdx.x;
    const int wid  = t >> 6;
    const int lane = t & 63;
    const int wr   = wid >> 1;
    const int wc   = wid & 1;
    const int cl   = lane & 15;
    const int kq   = lane >> 4;
    const int lrow = lane >> 3;
    const int gs   = lane & 7;

    auto stage = [&](int buf, int k0) {
        const int gl = gs ^ lrow;
#pragma unroll
        for (int q = 0; q < 4; ++q) {
            const int r0  = (wid * 4 + q) * 8;
            const int row = r0 + lrow;
            async_copy16(A + (size_t)(bm + row) * lda + k0 + (gl << 2),
                         &As[buf][r0 * 32]);
            async_copy16(B + (size_t)(bn + row) * ldb + k0 + (gl << 2),
                         &Bs[buf][r0 * 32]);
        }
    };

    f32x4 acc[4][4];
#pragma unroll
    for (int m = 0; m < 4; ++m)
#pragma unroll
        for (int n = 0; n < 4; ++n) acc[m][n] = (f32x4)(0.f);

    const int NT = K >> 5;
    stage(0, 0);

    for (int it = 0; it < NT; ++it) {
        __syncthreads();
        if (it + 1 < NT)
            stage((it + 1) & 1, (it + 1) << 5);

        const float* as = As[it & 1];
        const float* bs = Bs[it & 1];

        short8v A1[4], A2[4], A3[4], B1[4], B2[4];
#pragma unroll
        for (int m = 0; m < 4; ++m) {
            const int r  = wr * 64 + m * 16 + cl;
            const int s1 = (2 * kq) ^ (r & 7);
            const float4 lo = *reinterpret_cast<const float4*>(as + r * 32 + (s1 << 2));
            const float4 hi = *reinterpret_cast<const float4*>(as + r * 32 + ((s1 ^ 1) << 2));
            short8v h1, h2, h3;
            SPL(lo.x, 0) SPL(lo.y, 1) SPL(lo.z, 2) SPL(lo.w, 3)
            SPL(hi.x, 4) SPL(hi.y, 5) SPL(hi.z, 6) SPL(hi.w, 7)
            A1[m] = h1; A2[m] = h2; A3[m] = h3;
        }
#pragma unroll
        for (int n = 0; n < 4; ++n) {
            const int r  = wc * 64 + n * 16 + cl;
            const int s1 = (2 * kq) ^ (r & 7);
            const float4 lo = *reinterpret_cast<const float4*>(bs + r * 32 + (s1 << 2));
            const float4 hi = *reinterpret_cast<const float4*>(bs + r * 32 + ((s1 ^ 1) << 2));
            short8v h1, h2;
            SPL2(lo.x, 0) SPL2(lo.y, 1) SPL2(lo.z, 2) SPL2(lo.w, 3)
            SPL2(hi.x, 4) SPL2(hi.y, 5) SPL2(hi.z, 6) SPL2(hi.w, 7)
            B1[n] = h1; B2[n] = h2;
        }

#pragma unroll
        for (int m = 0; m < 4; ++m)
#pragma unroll
            for (int n = 0; n < 4; ++n) {
                f32x4 c = acc[m][n];
                c = __builtin_amdgcn_mfma_f32_16x16x32_bf16(A1[m], B1[n], c, 0, 0, 0);
                c = __builtin_amdgcn_mfma_f32_16x16x32_bf16(A2[m], B1[n], c, 0, 0, 0);
                c = __builtin_amdgcn_mfma_f32_16x16x32_bf16(A1[m], B2[n], c, 0, 0, 0);
                c = __builtin_amdgcn_mfma_f32_16x16x32_bf16(A3[m], B1[n], c, 0, 0, 0);
                acc[m][n] = c;
            }
    }

    const int rw = lane >> 4;
#pragma unroll
    for (int n = 0; n < 4; ++n) {
        const int col = bn + wc * 64 + n * 16 + cl;
        const float bv = bias[col];
#pragma unroll
        for (int m = 0; m < 4; ++m) {
            const size_t rbase = (size_t)(bm + wr * 64 + m * 16 + rw * 4);
#pragma unroll
            for (int i = 0; i < 4; ++i)
                C[(rbase + i) * ldc + col] = acc[m][n][i] + bv;
        }
    }
}

// ---------------------------------------------------------------------------
// RoPE
// ---------------------------------------------------------------------------
__global__ void rope_table(float* __restrict__ tab)
{
    const int idx = blockIdx.x * 256 + threadIdx.x;
    const int s = idx >> 5;
    const int i = idx & 31;
    const double inv = pow(10000.0, -(double)(2 * i) / 64.0);
    const double f = (double)s * inv;
    tab[idx * 2 + 0] = (float)cos(f);
    tab[idx * 2 + 1] = (float)sin(f);
}

__global__ void rope_apply(float* __restrict__ comb, const float* __restrict__ tab)
{
    const int idx = blockIdx.x * 256 + threadIdx.x;
    const int i     = idx & 31;
    const int h     = (idx >> 5) & 15;
    const int row   = (idx >> 9) & (ROWS - 1);
    const int which = idx >> 21;
    const int s     = row & (SEQ - 1);

    const float c  = tab[(s * 32 + i) * 2 + 0];
    const float sn = tab[(s * 32 + i) * 2 + 1];

    float* base = comb + (size_t)row * THREE_D + which * D_MODEL + h * H_DIM;
    const float t1 = base[i];
    const float t2 = base[i + 32];
    base[i]      = t1 * c - t2 * sn;
    base[i + 32] = t2 * c + t1 * sn;
}

// ---------------------------------------------------------------------------
// Flash attention, bf16-split MFMA.
// grid = (SEQ/128, BATCH*N_HEADS), 512 threads = 8 waves x 16 q-rows each.
// Per-thread state halved vs the 4-wave version (qf/sacc/acc/P all 16 VGPR)
// -> natural VGPR < 128 (the m69 occupancy cliff).  LDS 64 KB -> 2 blocks/CU
// -> 16 waves/CU resident.  Wave-specialized staging: waves 0-3 K, 4-7 V.
// Q x2 planes, K x2 -> 3-product QK; PV 3 products; swz8 bank keys; exp2.
// No kv-split: writes ctx directly (combine kernel removed).
// ---------------------------------------------------------------------------
__global__ __launch_bounds__(512)
void attn_mfma(const float* __restrict__ Qg, const float* __restrict__ Kg,
               const float* __restrict__ Vg, float* __restrict__ ctx)
{
    __shared__ __align__(16) short Ks1[64 * 64];
    __shared__ __align__(16) short Ks2[64 * 64];
    __shared__ __align__(16) short Vt1[64 * 64];
    __shared__ __align__(16) short Vt2[64 * 64];
    __shared__ __align__(16) short Ps[8 * 2 * 16 * 64];   // [wave][plane][q16][k64]

    const int bh   = blockIdx.y;
    const int b    = bh >> 4;
    const int h    = bh & 15;
    const int q0   = blockIdx.x * 128;
    const size_t rowBase = (size_t)b * SEQ;
    const int hOff = h * H_DIM;

    const int t    = threadIdx.x;
    const int w    = t >> 6;
    const int lane = t & 63;
    const int cl   = lane & 15;
    const int g    = lane >> 4;

    // ---- Q fragments (B-operand), 2 planes, pre-scaled: wave w owns 16 q
    Frag qf[2][2];   // [c][plane]
#pragma unroll
    for (int c = 0; c < 2; ++c) {
        const float* qp = Qg + (rowBase + q0 + w * 16 + cl) * D_MODEL
                          + hOff + c * 32 + g * 8;
        const float4 f0 = *reinterpret_cast<const float4*>(qp);
        const float4 f1 = *reinterpret_cast<const float4*>(qp + 4);
        float v[8] = { f0.x * QK_SCALE, f0.y * QK_SCALE, f0.z * QK_SCALE, f0.w * QK_SCALE,
                       f1.x * QK_SCALE, f1.y * QK_SCALE, f1.z * QK_SCALE, f1.w * QK_SCALE };
        split2x8(v, qf[c][0].u, qf[c][1].u);
    }

    f32x4 acc[4];
#pragma unroll
    for (int s = 0; s < 4; ++s) acc[s] = (f32x4)(0.f);
    float m = -1e30f;
    float l = 0.f;

    // per-wave P buffer base
    short* pb1 = Ps + ((w * 2 + 0) * 16 + cl) * 64;
    short* pb2 = Ps + ((w * 2 + 1) * 16 + cl) * 64;

    for (int k0 = 0; k0 < SEQ; k0 += 64) {
        __syncthreads();   // previous tile LDS reads complete

        if (w < 4) {
            // ---- stage K (waves 0-3): rows k (64), cols d (64), 2 planes
            const int krow = t >> 2;            // 0..63
            const int dob  = (t & 3) * 2;       // logical octet base
            const float* kp = Kg + (rowBase + k0 + krow) * D_MODEL + hOff + dob * 8;
            float v[16];
            *reinterpret_cast<float4*>(&v[0])  = reinterpret_cast<const float4*>(kp)[0];
            *reinterpret_cast<float4*>(&v[4])  = reinterpret_cast<const float4*>(kp)[1];
            *reinterpret_cast<float4*>(&v[8])  = reinterpret_cast<const float4*>(kp)[2];
            *reinterpret_cast<float4*>(&v[12]) = reinterpret_cast<const float4*>(kp)[3];
            uint4v a1, a2, b1, b2;
            split2x8(v,     a1, a2);
            split2x8(v + 8, b1, b2);
            short* kb1 = Ks1 + krow * 64;
            short* kb2 = Ks2 + krow * 64;
            *reinterpret_cast<uint4v*>(kb1 + swz8(krow, dob    ) * 8) = a1;
            *reinterpret_cast<uint4v*>(kb1 + swz8(krow, dob + 1) * 8) = b1;
            *reinterpret_cast<uint4v*>(kb2 + swz8(krow, dob    ) * 8) = a2;
            *reinterpret_cast<uint4v*>(kb2 + swz8(krow, dob + 1) * 8) = b2;
        } else {
            // ---- stage V^T (waves 4-7): rows d (64), cols k (64), 2 planes
            const int t2  = t - 256;
            const int vkq = t2 >> 4;            // k = 4*vkq + r
            const int vdq = t2 & 15;            // d = 4*vdq + rr
            const float* vp = Vg + (rowBase + k0 + vkq * 4) * D_MODEL + hOff + vdq * 4;
            float va[4][4];
            *reinterpret_cast<float4*>(va[0]) = *reinterpret_cast<const float4*>(vp);
            *reinterpret_cast<float4*>(va[1]) = *reinterpret_cast<const float4*>(vp + D_MODEL);
            *reinterpret_cast<float4*>(va[2]) = *reinterpret_cast<const float4*>(vp + 2 * D_MODEL);
            *reinterpret_cast<float4*>(va[3]) = *reinterpret_cast<const float4*>(vp + 3 * D_MODEL);
            const int lo = vkq >> 1;
            const int hf = (vkq & 1) * 4;
#pragma unroll
            for (int rr = 0; rr < 4; ++rr) {
                const int row = 4 * vdq + rr;
                unsigned ub[4], rb[4];
#pragma unroll
                for (int r = 0; r < 4; ++r) {
                    const float x = va[r][rr];
                    const unsigned u = __float_as_uint(x);
                    ub[r] = u;
                    rb[r] = __float_as_uint(x - __uint_as_float(u & 0xFFFF0000u));
                }
                uint2v w1, w2;
                w1.x = (ub[0] >> 16) | (ub[1] & 0xFFFF0000u);
                w1.y = (ub[2] >> 16) | (ub[3] & 0xFFFF0000u);
                w2.x = (rb[0] >> 16) | (rb[1] & 0xFFFF0000u);
                w2.y = (rb[2] >> 16) | (rb[3] & 0xFFFF0000u);
                const int o = row * 64 + swz8(row, lo) * 8 + hf;
                *reinterpret_cast<uint2v*>(&Vt1[o]) = w1;
                *reinterpret_cast<uint2v*>(&Vt2[o]) = w2;
            }
        }
        __syncthreads();

        // ---- QK^T (swapped): sacc[ks], k = 16ks+4g+i, q = cl
        f32x4 sacc[4];
#pragma unroll
        for (int ks = 0; ks < 4; ++ks) sacc[ks] = (f32x4)(0.f);

#pragma unroll
        for (int ks = 0; ks < 4; ++ks)
#pragma unroll
            for (int c = 0; c < 2; ++c) {
                const int row = ks * 16 + cl;
                const int po  = row * 64 + swz8(row, 4 * c + g) * 8;
                Frag ka1, ka2;
                ka1.s = *reinterpret_cast<const short8v*>(&Ks1[po]);
                ka2.s = *reinterpret_cast<const short8v*>(&Ks2[po]);
                f32x4 s = sacc[ks];
                s = __builtin_amdgcn_mfma_f32_16x16x32_bf16(ka1.s, qf[c][0].s, s, 0, 0, 0);
                s = __builtin_amdgcn_mfma_f32_16x16x32_bf16(ka2.s, qf[c][0].s, s, 0, 0, 0);
                s = __builtin_amdgcn_mfma_f32_16x16x32_bf16(ka1.s, qf[c][1].s, s, 0, 0, 0);
                sacc[ks] = s;
            }

        // ---- online softmax (exp2 domain), q row = cl
        float tm = -1e30f;
#pragma unroll
        for (int ks = 0; ks < 4; ++ks)
#pragma unroll
            for (int i = 0; i < 4; ++i) tm = fmaxf(tm, sacc[ks][i]);
        tm = fmaxf(tm, __shfl_xor(tm, 16));
        tm = fmaxf(tm, __shfl_xor(tm, 32));

        const float mn = fmaxf(m, tm);
        const float sc = __builtin_amdgcn_exp2f(m - mn);
        m = mn;

        float rs = 0.f;
        uint2v P1[4], P2[4];
#pragma unroll
        for (int ks = 0; ks < 4; ++ks) {
            float p[4];
            unsigned ub[4], rb[4];
#pragma unroll
            for (int i = 0; i < 4; ++i) {
                p[i] = __builtin_amdgcn_exp2f(sacc[ks][i] - mn);
                rs += p[i];
                const unsigned u = __float_as_uint(p[i]);
                ub[i] = u;
                rb[i] = __float_as_uint(p[i] - __uint_as_float(u & 0xFFFF0000u));
            }
            P1[ks] = (uint2v){ (ub[0] >> 16) | (ub[1] & 0xFFFF0000u),
                               (ub[2] >> 16) | (ub[3] & 0xFFFF0000u) };
            P2[ks] = (uint2v){ (rb[0] >> 16) | (rb[1] & 0xFFFF0000u),
                               (rb[2] >> 16) | (rb[3] & 0xFFFF0000u) };
        }
        rs += __shfl_xor(rs, 16);
        rs += __shfl_xor(rs, 32);
        l = l * sc + rs;

        // rescale acc rows (q = 4g+i; sc lives at lane cl = q)
        float scv[4];
#pragma unroll
        for (int i = 0; i < 4; ++i) scv[i] = __shfl(sc, 4 * g + i);
#pragma unroll
        for (int s = 0; s < 4; ++s)
#pragma unroll
            for (int i = 0; i < 4; ++i) acc[s][i] *= scv[i];

        // write P to per-wave LDS (row q = cl, k = 16ks+4g+i)
#pragma unroll
        for (int ks = 0; ks < 4; ++ks) {
            const int off = swz8(cl, 2 * ks + (g >> 1)) * 8 + (g & 1) * 4;
            *reinterpret_cast<uint2v*>(pb1 + off) = P1[ks];
            *reinterpret_cast<uint2v*>(pb2 + off) = P2[ks];
        }

        // ---- PV: A = P (A-frag: row q = cl), B = V^T
#pragma unroll
        for (int c = 0; c < 2; ++c) {
            const int po = swz8(cl, 4 * c + g) * 8;
            Frag pa1, pa2;
            pa1.s = *reinterpret_cast<const short8v*>(pb1 + po);
            pa2.s = *reinterpret_cast<const short8v*>(pb2 + po);
#pragma unroll
            for (int s = 0; s < 4; ++s) {
                const int row = s * 16 + cl;
                const int vo  = row * 64 + swz8(row, 4 * c + g) * 8;
                Frag vb1, vb2;
                vb1.s = *reinterpret_cast<const short8v*>(&Vt1[vo]);
                vb2.s = *reinterpret_cast<const short8v*>(&Vt2[vo]);
                f32x4 a = acc[s];
                a = __builtin_amdgcn_mfma_f32_16x16x32_bf16(pa1.s, vb1.s, a, 0, 0, 0);
                a = __builtin_amdgcn_mfma_f32_16x16x32_bf16(pa2.s, vb1.s, a, 0, 0, 0);
                a = __builtin_amdgcn_mfma_f32_16x16x32_bf16(pa1.s, vb2.s, a, 0, 0, 0);
                acc[s] = a;
            }
        }
    }

    // ---- epilogue: divide by l (l lives at lane cl = q) and store directly
    const float inv = 1.f / l;
    float iv[4];
#pragma unroll
    for (int i = 0; i < 4; ++i) iv[i] = __shfl(inv, 4 * g + i);
#pragma unroll
    for (int s = 0; s < 4; ++s)
#pragma unroll
        for (int i = 0; i < 4; ++i)
            ctx[(rowBase + q0 + w * 16 + 4 * g + i) * D_MODEL + hOff + s * 16 + cl]
                = acc[s][i] * iv[i];
}

// ---------------------------------------------------------------------------
extern "C" void kernel_launch(void* const* d_in, const int* in_sizes, int n_in,
                              void* d_out, int out_size, void* d_ws, size_t ws_size,
                              hipStream_t stream)
{
    const float* x    = (const float*)d_in[0];
    const float* Win  = (const float*)d_in[1];   // (3072, 1024)
    const float* bin  = (const float*)d_in[2];   // (3072,)
    const float* Wout = (const float*)d_in[3];   // (1024, 1024)
    const float* bout = (const float*)d_in[4];   // (1024,)
    float* out = (float*)d_out;

    float* combined = (float*)d_ws;                                  // ROWS x 3072
    float* qkv  = combined + (size_t)ROWS * THREE_D;                 // 3 x ROWS x 1024
    float* qbuf = qkv;
    float* kbuf = qkv + (size_t)ROWS * D_MODEL;
    float* vbuf = kbuf + (size_t)ROWS * D_MODEL;
    float* tab  = vbuf + (size_t)ROWS * D_MODEL;                     // SEQ*32*2
    float* ctx  = combined;                                          // ROWS x 1024

    const dim3 blk(256);

    rope_table<<<dim3(SEQ * 32 / 256), blk, 0, stream>>>(tab);

    // GEMM1: combined = x @ Win^T + bin
    gemm_bt_mfma<<<dim3(24, 32), blk, 0, stream>>>(
        x, D_MODEL, Win, D_MODEL, bin, combined, THREE_D, D_MODEL,
        24, (size_t)0, (size_t)0, 0, (size_t)0);

    // RoPE in place on q/k thirds of combined
    rope_apply<<<dim3((2 * ROWS * N_HEADS * 32) / 256), blk, 0, stream>>>(combined, tab);

    // fused q/k/v second projection
    gemm_bt_mfma<<<dim3(24, 32), blk, 0, stream>>>(
        combined, THREE_D, Win, D_MODEL, bin, qkv, D_MODEL, D_MODEL,
        8, (size_t)D_MODEL, (size_t)D_MODEL * D_MODEL, D_MODEL,
        (size_t)ROWS * D_MODEL);

    // attention -> ctx directly (8-wave blocks, no kv-split, no combine)
    attn_mfma<<<dim3(SEQ / 128, BATCH * N_HEADS), dim3(512), 0, stream>>>(
        qbuf, kbuf, vbuf, ctx);

    // GEMM3: out = ctx @ Wout^T + bout
    gemm_bt_mfma<<<dim3(8, 32), blk, 0, stream>>>(
        ctx, D_MODEL, Wout, D_MODEL, bout, out, D_MODEL, D_MODEL,
        8, (size_t)0, (size_t)0, 0, (size_t)0);
}

// Round 10
// 413.283 us; speedup vs baseline: 1.4257x; 1.1517x over previous
//
#include <hip/hip_runtime.h>
#include <math.h>

#define D_MODEL   1024
#define N_HEADS   16
#define H_DIM     64
#define SEQ       2048
#define BATCH     2
#define ROWS      (BATCH * SEQ)        // 4096
#define THREE_D   (3 * D_MODEL)       // 3072

// q pre-scale: 1/sqrt(64) * log2(e)  -> softmax in exp2 domain
#define QK_SCALE  (0.125f * 1.44269504088896340736f)

typedef __attribute__((ext_vector_type(8))) short short8v;   // 8 bf16
typedef __attribute__((ext_vector_type(4))) float f32x4;
typedef __attribute__((ext_vector_type(4))) unsigned int uint4v;
typedef __attribute__((ext_vector_type(2))) unsigned int uint2v;

union Frag { uint4v u; short8v s; };

__device__ __forceinline__ void async_copy16(const float* g, float* l)
{
    __builtin_amdgcn_global_load_lds(
        (const __attribute__((address_space(1))) void*)g,
        (__attribute__((address_space(3))) void*)l,
        16, 0, 0);
}

// LDS octet swizzle key: spreads banks for BOTH row-strided (stride-4) write
// groups and 16-row fragment read groups.  Used at every K/V/P LDS site.
__device__ __forceinline__ int swz8(int row, int oct)
{
    return oct ^ ((row ^ (row >> 2)) & 7);
}

// split fp32 -> 2 bf16 planes
#define SPL2(x, j)                                                         \
    {                                                                      \
        const float x_ = (x);                                              \
        const unsigned u1_ = __float_as_uint(x_);                          \
        const float r1_ = x_ - __uint_as_float(u1_ & 0xFFFF0000u);         \
        h1[j] = (short)(u1_ >> 16);                                        \
        h2[j] = (short)(__float_as_uint(r1_) >> 16);                       \
    }

// split 8 floats into 2 packed bf16x8 planes
__device__ __forceinline__ void split2x8(const float* v, uint4v& U1, uint4v& U2)
{
    unsigned b1[8], b2[8];
#pragma unroll
    for (int j = 0; j < 8; ++j) {
        const unsigned u = __float_as_uint(v[j]);
        b1[j] = u;
        const float r = v[j] - __uint_as_float(u & 0xFFFF0000u);
        b2[j] = __float_as_uint(r);
    }
    U1 = (uint4v){ (b1[0]>>16)|(b1[1]&0xFFFF0000u), (b1[2]>>16)|(b1[3]&0xFFFF0000u),
                   (b1[4]>>16)|(b1[5]&0xFFFF0000u), (b1[6]>>16)|(b1[7]&0xFFFF0000u) };
    U2 = (uint4v){ (b2[0]>>16)|(b2[1]&0xFFFF0000u), (b2[2]>>16)|(b2[3]&0xFFFF0000u),
                   (b2[4]>>16)|(b2[5]&0xFFFF0000u), (b2[6]>>16)|(b2[7]&0xFFFF0000u) };
}

// ---------------------------------------------------------------------------
// GEMM:  C[M,N] = A[M,K] * B[N,K]^T + bias[N]   via bf16-split MFMA.
// A split x2, B split x2, 3 products (a1b1, a2b1, a1b2).  Dropped terms
// (a2b2, a3*) are 2^-16-class -> ~3e-5 absolute after sqrt(K) random walk,
// far under the fp32-accumulation floor (~1e-3) that dominates absmax.
// ---------------------------------------------------------------------------
__global__ __launch_bounds__(256, 2)
void gemm_bt_mfma(const float* __restrict__ A, int lda,
                  const float* __restrict__ B, int ldb,
                  const float* __restrict__ bias,
                  float* __restrict__ C, int ldc, int K,
                  int nbx, size_t segA, size_t segB, int segBias, size_t segC)
{
    __shared__ __align__(16) float As[2][128 * 32];
    __shared__ __align__(16) float Bs[2][128 * 32];

    const int seg = blockIdx.x / nbx;
    const int bxs = blockIdx.x - seg * nbx;
    const int bm  = blockIdx.y * 128;
    const int bn  = bxs * 128;
    A    += (size_t)seg * segA;
    B    += (size_t)seg * segB;
    bias += seg * segBias;
    C    += (size_t)seg * segC;

    const int t    = threadIdx.x;
    const int wid  = t >> 6;
    const int lane = t & 63;
    const int wr   = wid >> 1;
    const int wc   = wid & 1;
    const int cl   = lane & 15;
    const int kq   = lane >> 4;
    const int lrow = lane >> 3;
    const int gs   = lane & 7;

    auto stage = [&](int buf, int k0) {
        const int gl = gs ^ lrow;
#pragma unroll
        for (int q = 0; q < 4; ++q) {
            const int r0  = (wid * 4 + q) * 8;
            const int row = r0 + lrow;
            async_copy16(A + (size_t)(bm + row) * lda + k0 + (gl << 2),
                         &As[buf][r0 * 32]);
            async_copy16(B + (size_t)(bn + row) * ldb + k0 + (gl << 2),
                         &Bs[buf][r0 * 32]);
        }
    };

    f32x4 acc[4][4];
#pragma unroll
    for (int m = 0; m < 4; ++m)
#pragma unroll
        for (int n = 0; n < 4; ++n) acc[m][n] = (f32x4)(0.f);

    const int NT = K >> 5;
    stage(0, 0);

    for (int it = 0; it < NT; ++it) {
        __syncthreads();
        if (it + 1 < NT)
            stage((it + 1) & 1, (it + 1) << 5);

        const float* as = As[it & 1];
        const float* bs = Bs[it & 1];

        short8v A1[4], A2[4], B1[4], B2[4];
#pragma unroll
        for (int m = 0; m < 4; ++m) {
            const int r  = wr * 64 + m * 16 + cl;
            const int s1 = (2 * kq) ^ (r & 7);
            const float4 lo = *reinterpret_cast<const float4*>(as + r * 32 + (s1 << 2));
            const float4 hi = *reinterpret_cast<const float4*>(as + r * 32 + ((s1 ^ 1) << 2));
            short8v h1, h2;
            SPL2(lo.x, 0) SPL2(lo.y, 1) SPL2(lo.z, 2) SPL2(lo.w, 3)
            SPL2(hi.x, 4) SPL2(hi.y, 5) SPL2(hi.z, 6) SPL2(hi.w, 7)
            A1[m] = h1; A2[m] = h2;
        }
#pragma unroll
        for (int n = 0; n < 4; ++n) {
            const int r  = wc * 64 + n * 16 + cl;
            const int s1 = (2 * kq) ^ (r & 7);
            const float4 lo = *reinterpret_cast<const float4*>(bs + r * 32 + (s1 << 2));
            const float4 hi = *reinterpret_cast<const float4*>(bs + r * 32 + ((s1 ^ 1) << 2));
            short8v h1, h2;
            SPL2(lo.x, 0) SPL2(lo.y, 1) SPL2(lo.z, 2) SPL2(lo.w, 3)
            SPL2(hi.x, 4) SPL2(hi.y, 5) SPL2(hi.z, 6) SPL2(hi.w, 7)
            B1[n] = h1; B2[n] = h2;
        }

#pragma unroll
        for (int m = 0; m < 4; ++m)
#pragma unroll
            for (int n = 0; n < 4; ++n) {
                f32x4 c = acc[m][n];
                c = __builtin_amdgcn_mfma_f32_16x16x32_bf16(A1[m], B1[n], c, 0, 0, 0);
                c = __builtin_amdgcn_mfma_f32_16x16x32_bf16(A2[m], B1[n], c, 0, 0, 0);
                c = __builtin_amdgcn_mfma_f32_16x16x32_bf16(A1[m], B2[n], c, 0, 0, 0);
                acc[m][n] = c;
            }
    }

    const int rw = lane >> 4;
#pragma unroll
    for (int n = 0; n < 4; ++n) {
        const int col = bn + wc * 64 + n * 16 + cl;
        const float bv = bias[col];
#pragma unroll
        for (int m = 0; m < 4; ++m) {
            const size_t rbase = (size_t)(bm + wr * 64 + m * 16 + rw * 4);
#pragma unroll
            for (int i = 0; i < 4; ++i)
                C[(rbase + i) * ldc + col] = acc[m][n][i] + bv;
        }
    }
}

// ---------------------------------------------------------------------------
// RoPE
// ---------------------------------------------------------------------------
__global__ void rope_table(float* __restrict__ tab)
{
    const int idx = blockIdx.x * 256 + threadIdx.x;
    const int s = idx >> 5;
    const int i = idx & 31;
    const double inv = pow(10000.0, -(double)(2 * i) / 64.0);
    const double f = (double)s * inv;
    tab[idx * 2 + 0] = (float)cos(f);
    tab[idx * 2 + 1] = (float)sin(f);
}

__global__ void rope_apply(float* __restrict__ comb, const float* __restrict__ tab)
{
    const int idx = blockIdx.x * 256 + threadIdx.x;
    const int i     = idx & 31;
    const int h     = (idx >> 5) & 15;
    const int row   = (idx >> 9) & (ROWS - 1);
    const int which = idx >> 21;
    const int s     = row & (SEQ - 1);

    const float c  = tab[(s * 32 + i) * 2 + 0];
    const float sn = tab[(s * 32 + i) * 2 + 1];

    float* base = comb + (size_t)row * THREE_D + which * D_MODEL + h * H_DIM;
    const float t1 = base[i];
    const float t2 = base[i + 32];
    base[i]      = t1 * c - t2 * sn;
    base[i + 32] = t2 * c + t1 * sn;
}

// ---------------------------------------------------------------------------
// Flash attention, bf16-split MFMA, 8 waves x 16 q-rows, T14 async staging.
// grid = (16, 32) remapped internally so each XCD owns 4 (b,h) pairs
// (K/V working set 4 MB/XCD = L2-resident).  Wave-specialized reg staging:
// waves 0-3 hold K tile (16 VGPR), waves 4-7 hold V tile; loads for t+1 are
// issued before compute on tile t (HBM latency hidden), split+ds_write after
// the reads-done barrier.  Q x2 planes, 3-product QK, 3-product PV, swz8.
// ---------------------------------------------------------------------------
__global__ __launch_bounds__(512)
void attn_mfma(const float* __restrict__ Qg, const float* __restrict__ Kg,
               const float* __restrict__ Vg, float* __restrict__ ctx)
{
    __shared__ __align__(16) short Ks1[64 * 64];
    __shared__ __align__(16) short Ks2[64 * 64];
    __shared__ __align__(16) short Vt1[64 * 64];
    __shared__ __align__(16) short Vt2[64 * 64];
    __shared__ __align__(16) short Ps[8 * 2 * 16 * 64];   // [wave][plane][q16][k64]

    // XCD-aware remap: fid%8 = XCD (dispatch heuristic); XCD x gets bh in
    // {4x..4x+3}, all 16 q-blocks of each bh on one XCD.
    const int fid = blockIdx.y * gridDim.x + blockIdx.x;   // 0..511
    const int bh  = (fid & 7) * 4 + ((fid >> 3) & 3);
    const int q0  = (fid >> 5) * 128;
    const int b   = bh >> 4;
    const int h   = bh & 15;
    const size_t rowBase = (size_t)b * SEQ;
    const int hOff = h * H_DIM;

    const int t    = threadIdx.x;
    const int w    = t >> 6;
    const int lane = t & 63;
    const int cl   = lane & 15;
    const int g    = lane >> 4;

    // staging lane roles (wave-specialized)
    const int krow = t >> 2;            // waves 0-3: K row
    const int dob  = (t & 3) * 2;       // waves 0-3: logical octet base
    const int t2   = t - 256;
    const int vkq  = t2 >> 4;           // waves 4-7: k = 4*vkq + r
    const int vdq  = t2 & 15;           // waves 4-7: d = 4*vdq + rr

    // ---- Q fragments (B-operand), 2 planes, pre-scaled: wave w owns 16 q
    Frag qf[2][2];   // [c][plane]
#pragma unroll
    for (int c = 0; c < 2; ++c) {
        const float* qp = Qg + (rowBase + q0 + w * 16 + cl) * D_MODEL
                          + hOff + c * 32 + g * 8;
        const float4 f0 = *reinterpret_cast<const float4*>(qp);
        const float4 f1 = *reinterpret_cast<const float4*>(qp + 4);
        float v[8] = { f0.x * QK_SCALE, f0.y * QK_SCALE, f0.z * QK_SCALE, f0.w * QK_SCALE,
                       f1.x * QK_SCALE, f1.y * QK_SCALE, f1.z * QK_SCALE, f1.w * QK_SCALE };
        split2x8(v, qf[c][0].u, qf[c][1].u);
    }

    f32x4 acc[4];
#pragma unroll
    for (int s = 0; s < 4; ++s) acc[s] = (f32x4)(0.f);
    float m = -1e30f;
    float l = 0.f;

    // per-wave P buffer base
    short* pb1 = Ps + ((w * 2 + 0) * 16 + cl) * 64;
    short* pb2 = Ps + ((w * 2 + 1) * 16 + cl) * 64;

    // staged-tile registers (16 VGPR; role depends on wave half)
    float4 sr0, sr1, sr2, sr3;

    auto load_tile = [&](int k0) {
        if (w < 4) {
            const float* kp = Kg + (rowBase + k0 + krow) * D_MODEL + hOff + dob * 8;
            sr0 = reinterpret_cast<const float4*>(kp)[0];
            sr1 = reinterpret_cast<const float4*>(kp)[1];
            sr2 = reinterpret_cast<const float4*>(kp)[2];
            sr3 = reinterpret_cast<const float4*>(kp)[3];
        } else {
            const float* vp = Vg + (rowBase + k0 + vkq * 4) * D_MODEL + hOff + vdq * 4;
            sr0 = *reinterpret_cast<const float4*>(vp);
            sr1 = *reinterpret_cast<const float4*>(vp + D_MODEL);
            sr2 = *reinterpret_cast<const float4*>(vp + 2 * D_MODEL);
            sr3 = *reinterpret_cast<const float4*>(vp + 3 * D_MODEL);
        }
    };

    auto write_tile = [&]() {
        if (w < 4) {
            // K: rows k (64), cols d (64), 2 planes, swz8 octets
            float v[16];
            *reinterpret_cast<float4*>(&v[0])  = sr0;
            *reinterpret_cast<float4*>(&v[4])  = sr1;
            *reinterpret_cast<float4*>(&v[8])  = sr2;
            *reinterpret_cast<float4*>(&v[12]) = sr3;
            uint4v a1, a2, b1, b2;
            split2x8(v,     a1, a2);
            split2x8(v + 8, b1, b2);
            short* kb1 = Ks1 + krow * 64;
            short* kb2 = Ks2 + krow * 64;
            *reinterpret_cast<uint4v*>(kb1 + swz8(krow, dob    ) * 8) = a1;
            *reinterpret_cast<uint4v*>(kb1 + swz8(krow, dob + 1) * 8) = b1;
            *reinterpret_cast<uint4v*>(kb2 + swz8(krow, dob    ) * 8) = a2;
            *reinterpret_cast<uint4v*>(kb2 + swz8(krow, dob + 1) * 8) = b2;
        } else {
            // V^T: rows d (64), cols k (64), 2 planes, 4x4 reg transpose
            float va[4][4];
            *reinterpret_cast<float4*>(va[0]) = sr0;
            *reinterpret_cast<float4*>(va[1]) = sr1;
            *reinterpret_cast<float4*>(va[2]) = sr2;
            *reinterpret_cast<float4*>(va[3]) = sr3;
            const int lo = vkq >> 1;
            const int hf = (vkq & 1) * 4;
#pragma unroll
            for (int rr = 0; rr < 4; ++rr) {
                const int row = 4 * vdq + rr;
                unsigned ub[4], rb[4];
#pragma unroll
                for (int r = 0; r < 4; ++r) {
                    const float x = va[r][rr];
                    const unsigned u = __float_as_uint(x);
                    ub[r] = u;
                    rb[r] = __float_as_uint(x - __uint_as_float(u & 0xFFFF0000u));
                }
                uint2v w1, w2;
                w1.x = (ub[0] >> 16) | (ub[1] & 0xFFFF0000u);
                w1.y = (ub[2] >> 16) | (ub[3] & 0xFFFF0000u);
                w2.x = (rb[0] >> 16) | (rb[1] & 0xFFFF0000u);
                w2.y = (rb[2] >> 16) | (rb[3] & 0xFFFF0000u);
                const int o = row * 64 + swz8(row, lo) * 8 + hf;
                *reinterpret_cast<uint2v*>(&Vt1[o]) = w1;
                *reinterpret_cast<uint2v*>(&Vt2[o]) = w2;
            }
        }
    };

    const int NT = SEQ / 64;            // 32 tiles

    load_tile(0);
    write_tile();

    for (int it = 0; it < NT; ++it) {
        __syncthreads();   // tile `it` LDS writes visible
        if (it + 1 < NT)
            load_tile((it + 1) * 64);   // global loads hidden under compute

        // ---- QK^T (swapped): sacc[ks], k = 16ks+4g+i, q = cl
        f32x4 sacc[4];
#pragma unroll
        for (int ks = 0; ks < 4; ++ks) sacc[ks] = (f32x4)(0.f);

#pragma unroll
        for (int ks = 0; ks < 4; ++ks)
#pragma unroll
            for (int c = 0; c < 2; ++c) {
                const int row = ks * 16 + cl;
                const int po  = row * 64 + swz8(row, 4 * c + g) * 8;
                Frag ka1, ka2;
                ka1.s = *reinterpret_cast<const short8v*>(&Ks1[po]);
                ka2.s = *reinterpret_cast<const short8v*>(&Ks2[po]);
                f32x4 s = sacc[ks];
                s = __builtin_amdgcn_mfma_f32_16x16x32_bf16(ka1.s, qf[c][0].s, s, 0, 0, 0);
                s = __builtin_amdgcn_mfma_f32_16x16x32_bf16(ka2.s, qf[c][0].s, s, 0, 0, 0);
                s = __builtin_amdgcn_mfma_f32_16x16x32_bf16(ka1.s, qf[c][1].s, s, 0, 0, 0);
                sacc[ks] = s;
            }

        // ---- online softmax (exp2 domain), q row = cl
        float tm = -1e30f;
#pragma unroll
        for (int ks = 0; ks < 4; ++ks)
#pragma unroll
            for (int i = 0; i < 4; ++i) tm = fmaxf(tm, sacc[ks][i]);
        tm = fmaxf(tm, __shfl_xor(tm, 16));
        tm = fmaxf(tm, __shfl_xor(tm, 32));

        const float mn = fmaxf(m, tm);
        const float sc = __builtin_amdgcn_exp2f(m - mn);
        m = mn;

        float rs = 0.f;
        uint2v P1[4], P2[4];
#pragma unroll
        for (int ks = 0; ks < 4; ++ks) {
            float p[4];
            unsigned ub[4], rb[4];
#pragma unroll
            for (int i = 0; i < 4; ++i) {
                p[i] = __builtin_amdgcn_exp2f(sacc[ks][i] - mn);
                rs += p[i];
                const unsigned u = __float_as_uint(p[i]);
                ub[i] = u;
                rb[i] = __float_as_uint(p[i] - __uint_as_float(u & 0xFFFF0000u));
            }
            P1[ks] = (uint2v){ (ub[0] >> 16) | (ub[1] & 0xFFFF0000u),
                               (ub[2] >> 16) | (ub[3] & 0xFFFF0000u) };
            P2[ks] = (uint2v){ (rb[0] >> 16) | (rb[1] & 0xFFFF0000u),
                               (rb[2] >> 16) | (rb[3] & 0xFFFF0000u) };
        }
        rs += __shfl_xor(rs, 16);
        rs += __shfl_xor(rs, 32);
        l = l * sc + rs;

        // rescale acc rows (q = 4g+i; sc lives at lane cl = q)
        float scv[4];
#pragma unroll
        for (int i = 0; i < 4; ++i) scv[i] = __shfl(sc, 4 * g + i);
#pragma unroll
        for (int s = 0; s < 4; ++s)
#pragma unroll
            for (int i = 0; i < 4; ++i) acc[s][i] *= scv[i];

        // write P to per-wave LDS (row q = cl, k = 16ks+4g+i)
#pragma unroll
        for (int ks = 0; ks < 4; ++ks) {
            const int off = swz8(cl, 2 * ks + (g >> 1)) * 8 + (g & 1) * 4;
            *reinterpret_cast<uint2v*>(pb1 + off) = P1[ks];
            *reinterpret_cast<uint2v*>(pb2 + off) = P2[ks];
        }

        // ---- PV: A = P (A-frag: row q = cl), B = V^T
#pragma unroll
        for (int c = 0; c < 2; ++c) {
            const int po = swz8(cl, 4 * c + g) * 8;
            Frag pa1, pa2;
            pa1.s = *reinterpret_cast<const short8v*>(pb1 + po);
            pa2.s = *reinterpret_cast<const short8v*>(pb2 + po);
#pragma unroll
            for (int s = 0; s < 4; ++s) {
                const int row = s * 16 + cl;
                const int vo  = row * 64 + swz8(row, 4 * c + g) * 8;
                Frag vb1, vb2;
                vb1.s = *reinterpret_cast<const short8v*>(&Vt1[vo]);
                vb2.s = *reinterpret_cast<const short8v*>(&Vt2[vo]);
                f32x4 a = acc[s];
                a = __builtin_amdgcn_mfma_f32_16x16x32_bf16(pa1.s, vb1.s, a, 0, 0, 0);
                a = __builtin_amdgcn_mfma_f32_16x16x32_bf16(pa2.s, vb1.s, a, 0, 0, 0);
                a = __builtin_amdgcn_mfma_f32_16x16x32_bf16(pa1.s, vb2.s, a, 0, 0, 0);
                acc[s] = a;
            }
        }

        __syncthreads();   // all LDS reads of tile `it` complete
        if (it + 1 < NT)
            write_tile();  // split + ds_write tile it+1 (regs loaded above)
    }

    // ---- epilogue: divide by l (l lives at lane cl = q) and store directly
    const float inv = 1.f / l;
    float iv[4];
#pragma unroll
    for (int i = 0; i < 4; ++i) iv[i] = __shfl(inv, 4 * g + i);
#pragma unroll
    for (int s = 0; s < 4; ++s)
#pragma unroll
        for (int i = 0; i < 4; ++i)
            ctx[(rowBase + q0 + w * 16 + 4 * g + i) * D_MODEL + hOff + s * 16 + cl]
                = acc[s][i] * iv[i];
}

// ---------------------------------------------------------------------------
extern "C" void kernel_launch(void* const* d_in, const int* in_sizes, int n_in,
                              void* d_out, int out_size, void* d_ws, size_t ws_size,
                              hipStream_t stream)
{
    const float* x    = (const float*)d_in[0];
    const float* Win  = (const float*)d_in[1];   // (3072, 1024)
    const float* bin  = (const float*)d_in[2];   // (3072,)
    const float* Wout = (const float*)d_in[3];   // (1024, 1024)
    const float* bout = (const float*)d_in[4];   // (1024,)
    float* out = (float*)d_out;

    float* combined = (float*)d_ws;                                  // ROWS x 3072
    float* qkv  = combined + (size_t)ROWS * THREE_D;                 // 3 x ROWS x 1024
    float* qbuf = qkv;
    float* kbuf = qkv + (size_t)ROWS * D_MODEL;
    float* vbuf = kbuf + (size_t)ROWS * D_MODEL;
    float* tab  = vbuf + (size_t)ROWS * D_MODEL;                     // SEQ*32*2
    float* ctx  = combined;                                          // ROWS x 1024

    const dim3 blk(256);

    rope_table<<<dim3(SEQ * 32 / 256), blk, 0, stream>>>(tab);

    // GEMM1: combined = x @ Win^T + bin
    gemm_bt_mfma<<<dim3(24, 32), blk, 0, stream>>>(
        x, D_MODEL, Win, D_MODEL, bin, combined, THREE_D, D_MODEL,
        24, (size_t)0, (size_t)0, 0, (size_t)0);

    // RoPE in place on q/k thirds of combined
    rope_apply<<<dim3((2 * ROWS * N_HEADS * 32) / 256), blk, 0, stream>>>(combined, tab);

    // fused q/k/v second projection
    gemm_bt_mfma<<<dim3(24, 32), blk, 0, stream>>>(
        combined, THREE_D, Win, D_MODEL, bin, qkv, D_MODEL, D_MODEL,
        8, (size_t)D_MODEL, (size_t)D_MODEL * D_MODEL, D_MODEL,
        (size_t)ROWS * D_MODEL);

    // attention -> ctx directly (8-wave blocks, T14 staging, XCD remap)
    attn_mfma<<<dim3(SEQ / 128, BATCH * N_HEADS), dim3(512), 0, stream>>>(
        qbuf, kbuf, vbuf, ctx);

    // GEMM3: out = ctx @ Wout^T + bout
    gemm_bt_mfma<<<dim3(8, 32), blk, 0, stream>>>(
        ctx, D_MODEL, Wout, D_MODEL, bout, out, D_MODEL, D_MODEL,
        8, (size_t)0, (size_t)0, 0, (size_t)0);
}

// Round 11
// 380.622 us; speedup vs baseline: 1.5480x; 1.0858x over previous
//
#include <hip/hip_runtime.h>
#include <math.h>

#define D_MODEL   1024
#define N_HEADS   16
#define H_DIM     64
#define SEQ       2048
#define BATCH     2
#define ROWS      (BATCH * SEQ)        // 4096
#define THREE_D   (3 * D_MODEL)       // 3072

// q pre-scale: 1/sqrt(64) * log2(e)  -> softmax in exp2 domain
#define QK_SCALE  (0.125f * 1.44269504088896340736f)

typedef __attribute__((ext_vector_type(8))) short short8v;   // 8 bf16
typedef __attribute__((ext_vector_type(4))) float f32x4;
typedef __attribute__((ext_vector_type(4))) unsigned int uint4v;
typedef __attribute__((ext_vector_type(2))) unsigned int uint2v;

union Frag { uint4v u; short8v s; };

__device__ __forceinline__ void async_copy16(const void* g, void* l)
{
    __builtin_amdgcn_global_load_lds(
        (const __attribute__((address_space(1))) void*)g,
        (__attribute__((address_space(3))) void*)l,
        16, 0, 0);
}

// LDS octet swizzle key (attn): spreads banks for row-strided write groups
// and 16-row fragment read groups.
__device__ __forceinline__ int swz8(int row, int oct)
{
    return oct ^ ((row ^ (row >> 2)) & 7);
}

// split 8 floats into 2 packed bf16x8 planes (truncation)
__device__ __forceinline__ void split2x8(const float* v, uint4v& U1, uint4v& U2)
{
    unsigned b1[8], b2[8];
#pragma unroll
    for (int j = 0; j < 8; ++j) {
        const unsigned u = __float_as_uint(v[j]);
        b1[j] = u;
        const float r = v[j] - __uint_as_float(u & 0xFFFF0000u);
        b2[j] = __float_as_uint(r);
    }
    U1 = (uint4v){ (b1[0]>>16)|(b1[1]&0xFFFF0000u), (b1[2]>>16)|(b1[3]&0xFFFF0000u),
                   (b1[4]>>16)|(b1[5]&0xFFFF0000u), (b1[6]>>16)|(b1[7]&0xFFFF0000u) };
    U2 = (uint4v){ (b2[0]>>16)|(b2[1]&0xFFFF0000u), (b2[2]>>16)|(b2[3]&0xFFFF0000u),
                   (b2[4]>>16)|(b2[5]&0xFFFF0000u), (b2[6]>>16)|(b2[7]&0xFFFF0000u) };
}

// ---------------------------------------------------------------------------
// Packed-plane layout: fp32 row-major [M][K] -> bf16 [M][K/32][2][32]
// (plane1 = truncated bf16, plane2 = residual bf16; 4 B/elem, same bytes).
// Flat formula (K multiple of 32): short_off(e) = ((e>>5)<<6) + (e&31),
// plane2 at +32.  Row stride = K*2 shorts.
// ---------------------------------------------------------------------------
__global__ __launch_bounds__(256)
void split_pack(const float* __restrict__ in, unsigned short* __restrict__ out)
{
    const size_t e0 = ((size_t)blockIdx.x * 256 + threadIdx.x) * 8;
    const float4 a0 = *reinterpret_cast<const float4*>(in + e0);
    const float4 a1 = *reinterpret_cast<const float4*>(in + e0 + 4);
    float v[8] = { a0.x, a0.y, a0.z, a0.w, a1.x, a1.y, a1.z, a1.w };
    uint4v U1, U2;
    split2x8(v, U1, U2);
    unsigned short* d = out + ((e0 >> 5) << 6) + (e0 & 31);
    *reinterpret_cast<uint4v*>(d)      = U1;
    *reinterpret_cast<uint4v*>(d + 32) = U2;
}

// ---------------------------------------------------------------------------
// RoPE cos/sin table (fp64 accuracy)
// ---------------------------------------------------------------------------
__global__ void rope_table(float* __restrict__ tab)
{
    const int idx = blockIdx.x * 256 + threadIdx.x;
    const int s = idx >> 5;
    const int i = idx & 31;
    const double inv = pow(10000.0, -(double)(2 * i) / 64.0);
    const double f = (double)s * inv;
    tab[idx * 2 + 0] = (float)cos(f);
    tab[idx * 2 + 1] = (float)sin(f);
}

// ---------------------------------------------------------------------------
// rope_pack: read combined fp32, apply RoPE to q/k thirds, write ALL thirds
// as packed bf16 planes.  One block per row, 384 threads (8 cols each).
// First-half threads (hcol<32) process the (i, i+32) pair; second-half
// threads in q/k region idle; v third is passthrough split.
// ---------------------------------------------------------------------------
__global__ __launch_bounds__(384)
void rope_pack(const float* __restrict__ comb, const float* __restrict__ tab,
               unsigned short* __restrict__ out)
{
    const int row  = blockIdx.x;
    const int col0 = threadIdx.x * 8;
    const float* rp = comb + (size_t)row * THREE_D;
    unsigned short* op = out + (size_t)row * (THREE_D * 2);

    if (col0 < 2 * D_MODEL) {
        if ((col0 & 63) >= 32) return;          // partner handled below
        const int s  = row & (SEQ - 1);
        const int i0 = col0 & 31;
        const float4 a0 = *reinterpret_cast<const float4*>(rp + col0);
        const float4 a1 = *reinterpret_cast<const float4*>(rp + col0 + 4);
        const float4 b0 = *reinterpret_cast<const float4*>(rp + col0 + 32);
        const float4 b1 = *reinterpret_cast<const float4*>(rp + col0 + 36);
        const float t1[8] = { a0.x, a0.y, a0.z, a0.w, a1.x, a1.y, a1.z, a1.w };
        const float t2[8] = { b0.x, b0.y, b0.z, b0.w, b1.x, b1.y, b1.z, b1.w };
        float r1[8], r2[8];
#pragma unroll
        for (int j = 0; j < 8; ++j) {
            const float c  = tab[(s * 32 + i0 + j) * 2 + 0];
            const float sn = tab[(s * 32 + i0 + j) * 2 + 1];
            r1[j] = t1[j] * c - t2[j] * sn;
            r2[j] = t2[j] * c + t1[j] * sn;
        }
        uint4v U1, U2;
        split2x8(r1, U1, U2);
        unsigned short* d1 = op + ((col0 >> 5) << 6) + (col0 & 31);
        *reinterpret_cast<uint4v*>(d1)      = U1;
        *reinterpret_cast<uint4v*>(d1 + 32) = U2;
        split2x8(r2, U1, U2);
        const int c2 = col0 + 32;
        unsigned short* d2 = op + ((c2 >> 5) << 6) + (c2 & 31);
        *reinterpret_cast<uint4v*>(d2)      = U1;
        *reinterpret_cast<uint4v*>(d2 + 32) = U2;
    } else {
        const float4 a0 = *reinterpret_cast<const float4*>(rp + col0);
        const float4 a1 = *reinterpret_cast<const float4*>(rp + col0 + 4);
        float v[8] = { a0.x, a0.y, a0.z, a0.w, a1.x, a1.y, a1.z, a1.w };
        uint4v U1, U2;
        split2x8(v, U1, U2);
        unsigned short* d = op + ((col0 >> 5) << 6) + (col0 & 31);
        *reinterpret_cast<uint4v*>(d)      = U1;
        *reinterpret_cast<uint4v*>(d + 32) = U2;
    }
}

// ---------------------------------------------------------------------------
// GEMM on packed planes:  C[M,N] = A[M,K] * B[N,K]^T + bias[N].
// A,B are packed bf16 [rows][K/32][2][32]; 3 MFMA products (a1b1,a2b1,a1b2)
// — numerically identical to the verified in-kernel-split version, but ZERO
// split VALU in the loop.  128x128 tile, BK=32, double-buffered LDS staged
// with global_load_lds; identical byte-level swizzle structure (128-B rows,
// 8 16-B octets, key row&7) as the verified fp32 path.
// ---------------------------------------------------------------------------
__global__ __launch_bounds__(256, 2)
void gemm_p(const unsigned short* __restrict__ Ap, int ldA2,
            const unsigned short* __restrict__ Bp, int ldB2,
            const float* __restrict__ bias,
            float* __restrict__ C, int ldc, int K,
            int nbx, size_t segA, size_t segB, int segBias, size_t segC)
{
    __shared__ __align__(16) unsigned short As[2][128 * 64];
    __shared__ __align__(16) unsigned short Bs[2][128 * 64];

    const int seg = blockIdx.x / nbx;
    const int bxs = blockIdx.x - seg * nbx;
    const int bm  = blockIdx.y * 128;
    const int bn  = bxs * 128;
    Ap   += (size_t)seg * segA;
    Bp   += (size_t)seg * segB;
    bias += seg * segBias;
    C    += (size_t)seg * segC;

    const int t    = threadIdx.x;
    const int wid  = t >> 6;
    const int lane = t & 63;
    const int wr   = wid >> 1;
    const int wc   = wid & 1;
    const int cl   = lane & 15;
    const int kq   = lane >> 4;     // 0..3 : k-octet of fragment
    const int lrow = lane >> 3;
    const int gs   = lane & 7;

    // stored octet s of row r holds logical octet s ^ (r&7); achieved by
    // pre-swizzling the per-lane GLOBAL source (LDS dest linear).
    auto stage = [&](int buf, int k0) {
        const int gl = gs ^ lrow;
#pragma unroll
        for (int q = 0; q < 4; ++q) {
            const int r0  = (wid * 4 + q) * 8;
            const int row = r0 + lrow;
            async_copy16(Ap + (size_t)(bm + row) * ldA2 + (k0 << 1) + (gl << 3),
                         &As[buf][r0 * 64]);
            async_copy16(Bp + (size_t)(bn + row) * ldB2 + (k0 << 1) + (gl << 3),
                         &Bs[buf][r0 * 64]);
        }
    };

    f32x4 acc[4][4];
#pragma unroll
    for (int m = 0; m < 4; ++m)
#pragma unroll
        for (int n = 0; n < 4; ++n) acc[m][n] = (f32x4)(0.f);

    const int NT = K >> 5;
    stage(0, 0);

    for (int it = 0; it < NT; ++it) {
        __syncthreads();
        if (it + 1 < NT)
            stage((it + 1) & 1, (it + 1) << 5);

        const unsigned short* as = As[it & 1];
        const unsigned short* bs = Bs[it & 1];

        short8v A1[4], A2[4], B1[4], B2[4];
#pragma unroll
        for (int m = 0; m < 4; ++m) {
            const int r = wr * 64 + m * 16 + cl;
            const unsigned short* ar = as + r * 64;
            A1[m] = *reinterpret_cast<const short8v*>(ar + (( kq      ^ (r & 7)) << 3));
            A2[m] = *reinterpret_cast<const short8v*>(ar + (((kq + 4) ^ (r & 7)) << 3));
        }
#pragma unroll
        for (int n = 0; n < 4; ++n) {
            const int r = wc * 64 + n * 16 + cl;
            const unsigned short* br = bs + r * 64;
            B1[n] = *reinterpret_cast<const short8v*>(br + (( kq      ^ (r & 7)) << 3));
            B2[n] = *reinterpret_cast<const short8v*>(br + (((kq + 4) ^ (r & 7)) << 3));
        }

#pragma unroll
        for (int m = 0; m < 4; ++m)
#pragma unroll
            for (int n = 0; n < 4; ++n) {
                f32x4 c = acc[m][n];
                c = __builtin_amdgcn_mfma_f32_16x16x32_bf16(A1[m], B1[n], c, 0, 0, 0);
                c = __builtin_amdgcn_mfma_f32_16x16x32_bf16(A2[m], B1[n], c, 0, 0, 0);
                c = __builtin_amdgcn_mfma_f32_16x16x32_bf16(A1[m], B2[n], c, 0, 0, 0);
                acc[m][n] = c;
            }
    }

    const int rw = lane >> 4;
#pragma unroll
    for (int n = 0; n < 4; ++n) {
        const int col = bn + wc * 64 + n * 16 + cl;
        const float bv = bias[col];
#pragma unroll
        for (int m = 0; m < 4; ++m) {
            const size_t rbase = (size_t)(bm + wr * 64 + m * 16 + rw * 4);
#pragma unroll
            for (int i = 0; i < 4; ++i)
                C[(rbase + i) * ldc + col] = acc[m][n][i] + bv;
        }
    }
}

// ---------------------------------------------------------------------------
// Flash attention, bf16-split MFMA, 8 waves x 16 q-rows, T14 async staging,
// XCD-aware block remap.  (R10 kernel; epilogue now writes packed planes.)
// ---------------------------------------------------------------------------
__global__ __launch_bounds__(512)
void attn_mfma(const float* __restrict__ Qg, const float* __restrict__ Kg,
               const float* __restrict__ Vg, unsigned short* __restrict__ pctx)
{
    __shared__ __align__(16) short Ks1[64 * 64];
    __shared__ __align__(16) short Ks2[64 * 64];
    __shared__ __align__(16) short Vt1[64 * 64];
    __shared__ __align__(16) short Vt2[64 * 64];
    __shared__ __align__(16) short Ps[8 * 2 * 16 * 64];   // [wave][plane][q16][k64]

    // XCD-aware remap: fid%8 = XCD; XCD x gets bh in {4x..4x+3}.
    const int fid = blockIdx.y * gridDim.x + blockIdx.x;   // 0..511
    const int bh  = (fid & 7) * 4 + ((fid >> 3) & 3);
    const int q0  = (fid >> 5) * 128;
    const int b   = bh >> 4;
    const int h   = bh & 15;
    const size_t rowBase = (size_t)b * SEQ;
    const int hOff = h * H_DIM;

    const int t    = threadIdx.x;
    const int w    = t >> 6;
    const int lane = t & 63;
    const int cl   = lane & 15;
    const int g    = lane >> 4;

    // staging lane roles (wave-specialized)
    const int krow = t >> 2;            // waves 0-3: K row
    const int dob  = (t & 3) * 2;       // waves 0-3: logical octet base
    const int t2   = t - 256;
    const int vkq  = t2 >> 4;           // waves 4-7: k = 4*vkq + r
    const int vdq  = t2 & 15;           // waves 4-7: d = 4*vdq + rr

    // ---- Q fragments (B-operand), 2 planes, pre-scaled
    Frag qf[2][2];   // [c][plane]
#pragma unroll
    for (int c = 0; c < 2; ++c) {
        const float* qp = Qg + (rowBase + q0 + w * 16 + cl) * D_MODEL
                          + hOff + c * 32 + g * 8;
        const float4 f0 = *reinterpret_cast<const float4*>(qp);
        const float4 f1 = *reinterpret_cast<const float4*>(qp + 4);
        float v[8] = { f0.x * QK_SCALE, f0.y * QK_SCALE, f0.z * QK_SCALE, f0.w * QK_SCALE,
                       f1.x * QK_SCALE, f1.y * QK_SCALE, f1.z * QK_SCALE, f1.w * QK_SCALE };
        split2x8(v, qf[c][0].u, qf[c][1].u);
    }

    f32x4 acc[4];
#pragma unroll
    for (int s = 0; s < 4; ++s) acc[s] = (f32x4)(0.f);
    float m = -1e30f;
    float l = 0.f;

    short* pb1 = Ps + ((w * 2 + 0) * 16 + cl) * 64;
    short* pb2 = Ps + ((w * 2 + 1) * 16 + cl) * 64;

    float4 sr0, sr1, sr2, sr3;

    auto load_tile = [&](int k0) {
        if (w < 4) {
            const float* kp = Kg + (rowBase + k0 + krow) * D_MODEL + hOff + dob * 8;
            sr0 = reinterpret_cast<const float4*>(kp)[0];
            sr1 = reinterpret_cast<const float4*>(kp)[1];
            sr2 = reinterpret_cast<const float4*>(kp)[2];
            sr3 = reinterpret_cast<const float4*>(kp)[3];
        } else {
            const float* vp = Vg + (rowBase + k0 + vkq * 4) * D_MODEL + hOff + vdq * 4;
            sr0 = *reinterpret_cast<const float4*>(vp);
            sr1 = *reinterpret_cast<const float4*>(vp + D_MODEL);
            sr2 = *reinterpret_cast<const float4*>(vp + 2 * D_MODEL);
            sr3 = *reinterpret_cast<const float4*>(vp + 3 * D_MODEL);
        }
    };

    auto write_tile = [&]() {
        if (w < 4) {
            float v[16];
            *reinterpret_cast<float4*>(&v[0])  = sr0;
            *reinterpret_cast<float4*>(&v[4])  = sr1;
            *reinterpret_cast<float4*>(&v[8])  = sr2;
            *reinterpret_cast<float4*>(&v[12]) = sr3;
            uint4v a1, a2, b1, b2;
            split2x8(v,     a1, a2);
            split2x8(v + 8, b1, b2);
            short* kb1 = Ks1 + krow * 64;
            short* kb2 = Ks2 + krow * 64;
            *reinterpret_cast<uint4v*>(kb1 + swz8(krow, dob    ) * 8) = a1;
            *reinterpret_cast<uint4v*>(kb1 + swz8(krow, dob + 1) * 8) = b1;
            *reinterpret_cast<uint4v*>(kb2 + swz8(krow, dob    ) * 8) = a2;
            *reinterpret_cast<uint4v*>(kb2 + swz8(krow, dob + 1) * 8) = b2;
        } else {
            float va[4][4];
            *reinterpret_cast<float4*>(va[0]) = sr0;
            *reinterpret_cast<float4*>(va[1]) = sr1;
            *reinterpret_cast<float4*>(va[2]) = sr2;
            *reinterpret_cast<float4*>(va[3]) = sr3;
            const int lo = vkq >> 1;
            const int hf = (vkq & 1) * 4;
#pragma unroll
            for (int rr = 0; rr < 4; ++rr) {
                const int row = 4 * vdq + rr;
                unsigned ub[4], rb[4];
#pragma unroll
                for (int r = 0; r < 4; ++r) {
                    const float x = va[r][rr];
                    const unsigned u = __float_as_uint(x);
                    ub[r] = u;
                    rb[r] = __float_as_uint(x - __uint_as_float(u & 0xFFFF0000u));
                }
                uint2v w1, w2;
                w1.x = (ub[0] >> 16) | (ub[1] & 0xFFFF0000u);
                w1.y = (ub[2] >> 16) | (ub[3] & 0xFFFF0000u);
                w2.x = (rb[0] >> 16) | (rb[1] & 0xFFFF0000u);
                w2.y = (rb[2] >> 16) | (rb[3] & 0xFFFF0000u);
                const int o = row * 64 + swz8(row, lo) * 8 + hf;
                *reinterpret_cast<uint2v*>(&Vt1[o]) = w1;
                *reinterpret_cast<uint2v*>(&Vt2[o]) = w2;
            }
        }
    };

    const int NT = SEQ / 64;            // 32 tiles

    load_tile(0);
    write_tile();

    for (int it = 0; it < NT; ++it) {
        __syncthreads();   // tile `it` LDS writes visible
        if (it + 1 < NT)
            load_tile((it + 1) * 64);   // global loads hidden under compute

        // ---- QK^T (swapped): sacc[ks], k = 16ks+4g+i, q = cl
        f32x4 sacc[4];
#pragma unroll
        for (int ks = 0; ks < 4; ++ks) sacc[ks] = (f32x4)(0.f);

#pragma unroll
        for (int ks = 0; ks < 4; ++ks)
#pragma unroll
            for (int c = 0; c < 2; ++c) {
                const int row = ks * 16 + cl;
                const int po  = row * 64 + swz8(row, 4 * c + g) * 8;
                Frag ka1, ka2;
                ka1.s = *reinterpret_cast<const short8v*>(&Ks1[po]);
                ka2.s = *reinterpret_cast<const short8v*>(&Ks2[po]);
                f32x4 s = sacc[ks];
                s = __builtin_amdgcn_mfma_f32_16x16x32_bf16(ka1.s, qf[c][0].s, s, 0, 0, 0);
                s = __builtin_amdgcn_mfma_f32_16x16x32_bf16(ka2.s, qf[c][0].s, s, 0, 0, 0);
                s = __builtin_amdgcn_mfma_f32_16x16x32_bf16(ka1.s, qf[c][1].s, s, 0, 0, 0);
                sacc[ks] = s;
            }

        // ---- online softmax (exp2 domain), q row = cl
        float tm = -1e30f;
#pragma unroll
        for (int ks = 0; ks < 4; ++ks)
#pragma unroll
            for (int i = 0; i < 4; ++i) tm = fmaxf(tm, sacc[ks][i]);
        tm = fmaxf(tm, __shfl_xor(tm, 16));
        tm = fmaxf(tm, __shfl_xor(tm, 32));

        const float mn = fmaxf(m, tm);
        const float sc = __builtin_amdgcn_exp2f(m - mn);
        m = mn;

        float rs = 0.f;
        uint2v P1[4], P2[4];
#pragma unroll
        for (int ks = 0; ks < 4; ++ks) {
            float p[4];
            unsigned ub[4], rb[4];
#pragma unroll
            for (int i = 0; i < 4; ++i) {
                p[i] = __builtin_amdgcn_exp2f(sacc[ks][i] - mn);
                rs += p[i];
                const unsigned u = __float_as_uint(p[i]);
                ub[i] = u;
                rb[i] = __float_as_uint(p[i] - __uint_as_float(u & 0xFFFF0000u));
            }
            P1[ks] = (uint2v){ (ub[0] >> 16) | (ub[1] & 0xFFFF0000u),
                               (ub[2] >> 16) | (ub[3] & 0xFFFF0000u) };
            P2[ks] = (uint2v){ (rb[0] >> 16) | (rb[1] & 0xFFFF0000u),
                               (rb[2] >> 16) | (rb[3] & 0xFFFF0000u) };
        }
        rs += __shfl_xor(rs, 16);
        rs += __shfl_xor(rs, 32);
        l = l * sc + rs;

        float scv[4];
#pragma unroll
        for (int i = 0; i < 4; ++i) scv[i] = __shfl(sc, 4 * g + i);
#pragma unroll
        for (int s = 0; s < 4; ++s)
#pragma unroll
            for (int i = 0; i < 4; ++i) acc[s][i] *= scv[i];

#pragma unroll
        for (int ks = 0; ks < 4; ++ks) {
            const int off = swz8(cl, 2 * ks + (g >> 1)) * 8 + (g & 1) * 4;
            *reinterpret_cast<uint2v*>(pb1 + off) = P1[ks];
            *reinterpret_cast<uint2v*>(pb2 + off) = P2[ks];
        }

        // ---- PV: A = P (A-frag: row q = cl), B = V^T
#pragma unroll
        for (int c = 0; c < 2; ++c) {
            const int po = swz8(cl, 4 * c + g) * 8;
            Frag pa1, pa2;
            pa1.s = *reinterpret_cast<const short8v*>(pb1 + po);
            pa2.s = *reinterpret_cast<const short8v*>(pb2 + po);
#pragma unroll
            for (int s = 0; s < 4; ++s) {
                const int row = s * 16 + cl;
                const int vo  = row * 64 + swz8(row, 4 * c + g) * 8;
                Frag vb1, vb2;
                vb1.s = *reinterpret_cast<const short8v*>(&Vt1[vo]);
                vb2.s = *reinterpret_cast<const short8v*>(&Vt2[vo]);
                f32x4 a = acc[s];
                a = __builtin_amdgcn_mfma_f32_16x16x32_bf16(pa1.s, vb1.s, a, 0, 0, 0);
                a = __builtin_amdgcn_mfma_f32_16x16x32_bf16(pa2.s, vb1.s, a, 0, 0, 0);
                a = __builtin_amdgcn_mfma_f32_16x16x32_bf16(pa1.s, vb2.s, a, 0, 0, 0);
                acc[s] = a;
            }
        }

        __syncthreads();   // all LDS reads of tile `it` complete
        if (it + 1 < NT)
            write_tile();
    }

    // ---- epilogue: divide by l and store as packed bf16 planes
    const float inv = 1.f / l;
    float iv[4];
#pragma unroll
    for (int i = 0; i < 4; ++i) iv[i] = __shfl(inv, 4 * g + i);
#pragma unroll
    for (int s = 0; s < 4; ++s)
#pragma unroll
        for (int i = 0; i < 4; ++i) {
            const float val = acc[s][i] * iv[i];
            const size_t grow = rowBase + q0 + w * 16 + 4 * g + i;
            const int gc = hOff + s * 16 + cl;
            unsigned short* d = pctx + ((((size_t)grow * D_MODEL + gc) >> 5) << 6)
                                + (gc & 31);
            const unsigned u = __float_as_uint(val);
            d[0]  = (unsigned short)(u >> 16);
            const float r = val - __uint_as_float(u & 0xFFFF0000u);
            d[32] = (unsigned short)(__float_as_uint(r) >> 16);
        }
}

// ---------------------------------------------------------------------------
extern "C" void kernel_launch(void* const* d_in, const int* in_sizes, int n_in,
                              void* d_out, int out_size, void* d_ws, size_t ws_size,
                              hipStream_t stream)
{
    const float* x    = (const float*)d_in[0];
    const float* Win  = (const float*)d_in[1];   // (3072, 1024)
    const float* bin  = (const float*)d_in[2];   // (3072,)
    const float* Wout = (const float*)d_in[3];   // (1024, 1024)
    const float* bout = (const float*)d_in[4];   // (1024,)
    float* out = (float*)d_out;

    // Region plan (floats):
    //   R1 [12.58M]: combined fp32 (GEMM1 out, rope_pack in) -> qkv fp32
    //   R2 [12.58M]: px (packed x) -> pcomb (packed roped combined) -> pctx
    //   pW [3.15M], pWo [1.05M], tab [0.13M]
    float* R1 = (float*)d_ws;
    float* R2 = R1 + (size_t)ROWS * THREE_D;
    unsigned short* pW  = (unsigned short*)(R2 + (size_t)ROWS * THREE_D);
    unsigned short* pWo = pW + (size_t)THREE_D * D_MODEL * 2;
    float* tab = (float*)(pWo + (size_t)D_MODEL * D_MODEL * 2);

    float* combined = R1;
    float* qkv      = R1;
    unsigned short* px    = (unsigned short*)R2;
    unsigned short* pcomb = (unsigned short*)R2;
    unsigned short* pctx  = (unsigned short*)R2;

    float* qbuf = qkv;
    float* kbuf = qkv + (size_t)ROWS * D_MODEL;
    float* vbuf = kbuf + (size_t)ROWS * D_MODEL;

    const dim3 blk(256);

    rope_table<<<dim3(SEQ * 32 / 256), blk, 0, stream>>>(tab);

    // pack inputs/weights to bf16 planes (one-time, memory-bound)
    split_pack<<<dim3(ROWS * D_MODEL / 8 / 256), blk, 0, stream>>>(x, px);
    split_pack<<<dim3(THREE_D * D_MODEL / 8 / 256), blk, 0, stream>>>(Win, pW);
    split_pack<<<dim3(D_MODEL * D_MODEL / 8 / 256), blk, 0, stream>>>(Wout, pWo);

    // GEMM1: combined = x @ Win^T + bin
    gemm_p<<<dim3(24, 32), blk, 0, stream>>>(
        px, D_MODEL * 2, pW, D_MODEL * 2, bin, combined, THREE_D, D_MODEL,
        24, (size_t)0, (size_t)0, 0, (size_t)0);

    // rope + pack combined -> pcomb (overwrites px; px dead)
    rope_pack<<<dim3(ROWS), dim3(384), 0, stream>>>(combined, tab, pcomb);

    // fused q/k/v second projection: qkv fp32 (overwrites combined; dead)
    gemm_p<<<dim3(24, 32), blk, 0, stream>>>(
        pcomb, THREE_D * 2, pW, D_MODEL * 2, bin, qkv, D_MODEL, D_MODEL,
        8, (size_t)(D_MODEL * 2), (size_t)D_MODEL * D_MODEL * 2, D_MODEL,
        (size_t)ROWS * D_MODEL);

    // attention -> pctx packed planes (overwrites pcomb start; dead)
    attn_mfma<<<dim3(SEQ / 128, BATCH * N_HEADS), dim3(512), 0, stream>>>(
        qbuf, kbuf, vbuf, pctx);

    // GEMM3: out = ctx @ Wout^T + bout
    gemm_p<<<dim3(8, 32), blk, 0, stream>>>(
        pctx, D_MODEL * 2, pWo, D_MODEL * 2, bout, out, D_MODEL, D_MODEL,
        8, (size_t)0, (size_t)0, 0, (size_t)0);
}

// Round 12
// 367.986 us; speedup vs baseline: 1.6011x; 1.0343x over previous
//
#include <hip/hip_runtime.h>
#include <math.h>

#define D_MODEL   1024
#define N_HEADS   16
#define H_DIM     64
#define SEQ       2048
#define BATCH     2
#define ROWS      (BATCH * SEQ)        // 4096
#define THREE_D   (3 * D_MODEL)       // 3072

// q pre-scale: 1/sqrt(64) * log2(e)  -> softmax in exp2 domain
#define QK_SCALE  (0.125f * 1.44269504088896340736f)

typedef __attribute__((ext_vector_type(8))) short short8v;   // 8 bf16
typedef __attribute__((ext_vector_type(4))) float f32x4;
typedef __attribute__((ext_vector_type(4))) unsigned int uint4v;
typedef __attribute__((ext_vector_type(2))) unsigned int uint2v;

union Frag { uint4v u; short8v s; };

__device__ __forceinline__ void async_copy16(const void* g, void* l)
{
    __builtin_amdgcn_global_load_lds(
        (const __attribute__((address_space(1))) void*)g,
        (__attribute__((address_space(3))) void*)l,
        16, 0, 0);
}

// LDS octet swizzle key (attn)
__device__ __forceinline__ int swz8(int row, int oct)
{
    return oct ^ ((row ^ (row >> 2)) & 7);
}

// split 8 floats into 2 packed bf16x8 planes (truncation)
__device__ __forceinline__ void split2x8(const float* v, uint4v& U1, uint4v& U2)
{
    unsigned b1[8], b2[8];
#pragma unroll
    for (int j = 0; j < 8; ++j) {
        const unsigned u = __float_as_uint(v[j]);
        b1[j] = u;
        const float r = v[j] - __uint_as_float(u & 0xFFFF0000u);
        b2[j] = __float_as_uint(r);
    }
    U1 = (uint4v){ (b1[0]>>16)|(b1[1]&0xFFFF0000u), (b1[2]>>16)|(b1[3]&0xFFFF0000u),
                   (b1[4]>>16)|(b1[5]&0xFFFF0000u), (b1[6]>>16)|(b1[7]&0xFFFF0000u) };
    U2 = (uint4v){ (b2[0]>>16)|(b2[1]&0xFFFF0000u), (b2[2]>>16)|(b2[3]&0xFFFF0000u),
                   (b2[4]>>16)|(b2[5]&0xFFFF0000u), (b2[6]>>16)|(b2[7]&0xFFFF0000u) };
}

// packed-plane flat formula: short_off(e) = ((e>>5)<<6) + (e&31), plane2 +32
__device__ __forceinline__ void pack_store(unsigned short* rowp, int col, float val)
{
    unsigned short* d = rowp + ((col >> 5) << 6) + (col & 31);
    const unsigned u = __float_as_uint(val);
    d[0]  = (unsigned short)(u >> 16);
    const float r = val - __uint_as_float(u & 0xFFFF0000u);
    d[32] = (unsigned short)(__float_as_uint(r) >> 16);
}

// ---------------------------------------------------------------------------
// split_pack: fp32 row-major -> packed bf16 planes [.][K/32][2][32]
// ---------------------------------------------------------------------------
__global__ __launch_bounds__(256)
void split_pack(const float* __restrict__ in, unsigned short* __restrict__ out)
{
    const size_t e0 = ((size_t)blockIdx.x * 256 + threadIdx.x) * 8;
    const float4 a0 = *reinterpret_cast<const float4*>(in + e0);
    const float4 a1 = *reinterpret_cast<const float4*>(in + e0 + 4);
    float v[8] = { a0.x, a0.y, a0.z, a0.w, a1.x, a1.y, a1.z, a1.w };
    uint4v U1, U2;
    split2x8(v, U1, U2);
    unsigned short* d = out + ((e0 >> 5) << 6) + (e0 & 31);
    *reinterpret_cast<uint4v*>(d)      = U1;
    *reinterpret_cast<uint4v*>(d + 32) = U2;
}

// ---------------------------------------------------------------------------
// RoPE cos/sin table (fp64 accuracy)
// ---------------------------------------------------------------------------
__global__ void rope_table(float* __restrict__ tab)
{
    const int idx = blockIdx.x * 256 + threadIdx.x;
    const int s = idx >> 5;
    const int i = idx & 31;
    const double inv = pow(10000.0, -(double)(2 * i) / 64.0);
    const double f = (double)s * inv;
    tab[idx * 2 + 0] = (float)cos(f);
    tab[idx * 2 + 1] = (float)sin(f);
}

// ---------------------------------------------------------------------------
// gemm_p: packed-plane GEMM, fp32 C out (QKV + out-proj).  3 MFMA products.
// ---------------------------------------------------------------------------
__global__ __launch_bounds__(256, 2)
void gemm_p(const unsigned short* __restrict__ Ap, int ldA2,
            const unsigned short* __restrict__ Bp, int ldB2,
            const float* __restrict__ bias,
            float* __restrict__ C, int ldc, int K,
            int nbx, size_t segA, size_t segB, int segBias, size_t segC)
{
    __shared__ __align__(16) unsigned short As[2][128 * 64];
    __shared__ __align__(16) unsigned short Bs[2][128 * 64];

    const int seg = blockIdx.x / nbx;
    const int bxs = blockIdx.x - seg * nbx;
    const int bm  = blockIdx.y * 128;
    const int bn  = bxs * 128;
    Ap   += (size_t)seg * segA;
    Bp   += (size_t)seg * segB;
    bias += seg * segBias;
    C    += (size_t)seg * segC;

    const int t    = threadIdx.x;
    const int wid  = t >> 6;
    const int lane = t & 63;
    const int wr   = wid >> 1;
    const int wc   = wid & 1;
    const int cl   = lane & 15;
    const int kq   = lane >> 4;
    const int lrow = lane >> 3;
    const int gs   = lane & 7;

    auto stage = [&](int buf, int k0) {
        const int gl = gs ^ lrow;
#pragma unroll
        for (int q = 0; q < 4; ++q) {
            const int r0  = (wid * 4 + q) * 8;
            const int row = r0 + lrow;
            async_copy16(Ap + (size_t)(bm + row) * ldA2 + (k0 << 1) + (gl << 3),
                         &As[buf][r0 * 64]);
            async_copy16(Bp + (size_t)(bn + row) * ldB2 + (k0 << 1) + (gl << 3),
                         &Bs[buf][r0 * 64]);
        }
    };

    f32x4 acc[4][4];
#pragma unroll
    for (int m = 0; m < 4; ++m)
#pragma unroll
        for (int n = 0; n < 4; ++n) acc[m][n] = (f32x4)(0.f);

    const int NT = K >> 5;
    stage(0, 0);

    for (int it = 0; it < NT; ++it) {
        __syncthreads();
        if (it + 1 < NT)
            stage((it + 1) & 1, (it + 1) << 5);

        const unsigned short* as = As[it & 1];
        const unsigned short* bs = Bs[it & 1];

        short8v A1[4], A2[4], B1[4], B2[4];
#pragma unroll
        for (int m = 0; m < 4; ++m) {
            const int r = wr * 64 + m * 16 + cl;
            const unsigned short* ar = as + r * 64;
            A1[m] = *reinterpret_cast<const short8v*>(ar + (( kq      ^ (r & 7)) << 3));
            A2[m] = *reinterpret_cast<const short8v*>(ar + (((kq + 4) ^ (r & 7)) << 3));
        }
#pragma unroll
        for (int n = 0; n < 4; ++n) {
            const int r = wc * 64 + n * 16 + cl;
            const unsigned short* br = bs + r * 64;
            B1[n] = *reinterpret_cast<const short8v*>(br + (( kq      ^ (r & 7)) << 3));
            B2[n] = *reinterpret_cast<const short8v*>(br + (((kq + 4) ^ (r & 7)) << 3));
        }

#pragma unroll
        for (int m = 0; m < 4; ++m)
#pragma unroll
            for (int n = 0; n < 4; ++n) {
                f32x4 c = acc[m][n];
                c = __builtin_amdgcn_mfma_f32_16x16x32_bf16(A1[m], B1[n], c, 0, 0, 0);
                c = __builtin_amdgcn_mfma_f32_16x16x32_bf16(A2[m], B1[n], c, 0, 0, 0);
                c = __builtin_amdgcn_mfma_f32_16x16x32_bf16(A1[m], B2[n], c, 0, 0, 0);
                acc[m][n] = c;
            }
    }

    const int rw = lane >> 4;
#pragma unroll
    for (int n = 0; n < 4; ++n) {
        const int col = bn + wc * 64 + n * 16 + cl;
        const float bv = bias[col];
#pragma unroll
        for (int m = 0; m < 4; ++m) {
            const size_t rbase = (size_t)(bm + wr * 64 + m * 16 + rw * 4);
#pragma unroll
            for (int i = 0; i < 4; ++i)
                C[(rbase + i) * ldc + col] = acc[m][n][i] + bv;
        }
    }
}

// ---------------------------------------------------------------------------
// gemm_p_rope: GEMM1 with RoPE fused into the epilogue; writes packed planes.
// Within a 64-col head, rotation pair (d, d+32) = acc[m][n] / acc[m][n+2] of
// the SAME thread (d = 16n+cl, n in {0,1}).  v third (col>=2048): no rope.
// ---------------------------------------------------------------------------
__global__ __launch_bounds__(256, 2)
void gemm_p_rope(const unsigned short* __restrict__ Ap, int ldA2,
                 const unsigned short* __restrict__ Bp, int ldB2,
                 const float* __restrict__ bias,
                 const float* __restrict__ tab,
                 unsigned short* __restrict__ out, int K)
{
    __shared__ __align__(16) unsigned short As[2][128 * 64];
    __shared__ __align__(16) unsigned short Bs[2][128 * 64];

    const int bm  = blockIdx.y * 128;
    const int bn  = blockIdx.x * 128;

    const int t    = threadIdx.x;
    const int wid  = t >> 6;
    const int lane = t & 63;
    const int wr   = wid >> 1;
    const int wc   = wid & 1;
    const int cl   = lane & 15;
    const int kq   = lane >> 4;
    const int lrow = lane >> 3;
    const int gs   = lane & 7;

    auto stage = [&](int buf, int k0) {
        const int gl = gs ^ lrow;
#pragma unroll
        for (int q = 0; q < 4; ++q) {
            const int r0  = (wid * 4 + q) * 8;
            const int row = r0 + lrow;
            async_copy16(Ap + (size_t)(bm + row) * ldA2 + (k0 << 1) + (gl << 3),
                         &As[buf][r0 * 64]);
            async_copy16(Bp + (size_t)(bn + row) * ldB2 + (k0 << 1) + (gl << 3),
                         &Bs[buf][r0 * 64]);
        }
    };

    f32x4 acc[4][4];
#pragma unroll
    for (int m = 0; m < 4; ++m)
#pragma unroll
        for (int n = 0; n < 4; ++n) acc[m][n] = (f32x4)(0.f);

    const int NT = K >> 5;
    stage(0, 0);

    for (int it = 0; it < NT; ++it) {
        __syncthreads();
        if (it + 1 < NT)
            stage((it + 1) & 1, (it + 1) << 5);

        const unsigned short* as = As[it & 1];
        const unsigned short* bs = Bs[it & 1];

        short8v A1[4], A2[4], B1[4], B2[4];
#pragma unroll
        for (int m = 0; m < 4; ++m) {
            const int r = wr * 64 + m * 16 + cl;
            const unsigned short* ar = as + r * 64;
            A1[m] = *reinterpret_cast<const short8v*>(ar + (( kq      ^ (r & 7)) << 3));
            A2[m] = *reinterpret_cast<const short8v*>(ar + (((kq + 4) ^ (r & 7)) << 3));
        }
#pragma unroll
        for (int n = 0; n < 4; ++n) {
            const int r = wc * 64 + n * 16 + cl;
            const unsigned short* br = bs + r * 64;
            B1[n] = *reinterpret_cast<const short8v*>(br + (( kq      ^ (r & 7)) << 3));
            B2[n] = *reinterpret_cast<const short8v*>(br + (((kq + 4) ^ (r & 7)) << 3));
        }

#pragma unroll
        for (int m = 0; m < 4; ++m)
#pragma unroll
            for (int n = 0; n < 4; ++n) {
                f32x4 c = acc[m][n];
                c = __builtin_amdgcn_mfma_f32_16x16x32_bf16(A1[m], B1[n], c, 0, 0, 0);
                c = __builtin_amdgcn_mfma_f32_16x16x32_bf16(A2[m], B1[n], c, 0, 0, 0);
                c = __builtin_amdgcn_mfma_f32_16x16x32_bf16(A1[m], B2[n], c, 0, 0, 0);
                acc[m][n] = c;
            }
    }

    // ---- epilogue: rope (q/k thirds) + packed-plane store
    const int rw = lane >> 4;
    const bool doRope = (bn < 2 * D_MODEL);      // tile is head-aligned
#pragma unroll
    for (int n = 0; n < 2; ++n) {
        const int colA = bn + wc * 64 + n * 16 + cl;   // d = 16n+cl in [0,32)
        const int colB = colA + 32;
        const float bvA = bias[colA];
        const float bvB = bias[colB];
        const int d = n * 16 + cl;
#pragma unroll
        for (int m = 0; m < 4; ++m) {
            const size_t rbase = (size_t)(bm + wr * 64 + m * 16 + rw * 4);
#pragma unroll
            for (int i = 0; i < 4; ++i) {
                const size_t row = rbase + i;
                const float t1 = acc[m][n][i]     + bvA;
                const float t2 = acc[m][n + 2][i] + bvB;
                float r1 = t1, r2 = t2;
                if (doRope) {
                    const int s = (int)(row & (SEQ - 1));
                    const float c  = tab[(s * 32 + d) * 2 + 0];
                    const float sn = tab[(s * 32 + d) * 2 + 1];
                    r1 = t1 * c - t2 * sn;
                    r2 = t2 * c + t1 * sn;
                }
                unsigned short* op = out + row * (size_t)(THREE_D * 2);
                pack_store(op, colA, r1);
                pack_store(op, colB, r2);
            }
        }
    }
}

// ---------------------------------------------------------------------------
// Flash attention, bf16-split MFMA, 8 waves x 16 q-rows, T14 async staging,
// XCD-aware remap.  P single plane (PV 2 products; residual ~1e-3 abs, in
// budget).  LDS 48 KB.  Epilogue writes packed planes.
// ---------------------------------------------------------------------------
__global__ __launch_bounds__(512)
void attn_mfma(const float* __restrict__ Qg, const float* __restrict__ Kg,
               const float* __restrict__ Vg, unsigned short* __restrict__ pctx)
{
    __shared__ __align__(16) short Ks1[64 * 64];
    __shared__ __align__(16) short Ks2[64 * 64];
    __shared__ __align__(16) short Vt1[64 * 64];
    __shared__ __align__(16) short Vt2[64 * 64];
    __shared__ __align__(16) short Ps[8 * 16 * 64];   // [wave][q16][k64], 1 plane

    const int fid = blockIdx.y * gridDim.x + blockIdx.x;   // 0..511
    const int bh  = (fid & 7) * 4 + ((fid >> 3) & 3);
    const int q0  = (fid >> 5) * 128;
    const int b   = bh >> 4;
    const int h   = bh & 15;
    const size_t rowBase = (size_t)b * SEQ;
    const int hOff = h * H_DIM;

    const int t    = threadIdx.x;
    const int w    = t >> 6;
    const int lane = t & 63;
    const int cl   = lane & 15;
    const int g    = lane >> 4;

    const int krow = t >> 2;
    const int dob  = (t & 3) * 2;
    const int t2   = t - 256;
    const int vkq  = t2 >> 4;
    const int vdq  = t2 & 15;

    Frag qf[2][2];   // [c][plane]
#pragma unroll
    for (int c = 0; c < 2; ++c) {
        const float* qp = Qg + (rowBase + q0 + w * 16 + cl) * D_MODEL
                          + hOff + c * 32 + g * 8;
        const float4 f0 = *reinterpret_cast<const float4*>(qp);
        const float4 f1 = *reinterpret_cast<const float4*>(qp + 4);
        float v[8] = { f0.x * QK_SCALE, f0.y * QK_SCALE, f0.z * QK_SCALE, f0.w * QK_SCALE,
                       f1.x * QK_SCALE, f1.y * QK_SCALE, f1.z * QK_SCALE, f1.w * QK_SCALE };
        split2x8(v, qf[c][0].u, qf[c][1].u);
    }

    f32x4 acc[4];
#pragma unroll
    for (int s = 0; s < 4; ++s) acc[s] = (f32x4)(0.f);
    float m = -1e30f;
    float l = 0.f;

    short* pb1 = Ps + (w * 16 + cl) * 64;

    float4 sr0, sr1, sr2, sr3;

    auto load_tile = [&](int k0) {
        if (w < 4) {
            const float* kp = Kg + (rowBase + k0 + krow) * D_MODEL + hOff + dob * 8;
            sr0 = reinterpret_cast<const float4*>(kp)[0];
            sr1 = reinterpret_cast<const float4*>(kp)[1];
            sr2 = reinterpret_cast<const float4*>(kp)[2];
            sr3 = reinterpret_cast<const float4*>(kp)[3];
        } else {
            const float* vp = Vg + (rowBase + k0 + vkq * 4) * D_MODEL + hOff + vdq * 4;
            sr0 = *reinterpret_cast<const float4*>(vp);
            sr1 = *reinterpret_cast<const float4*>(vp + D_MODEL);
            sr2 = *reinterpret_cast<const float4*>(vp + 2 * D_MODEL);
            sr3 = *reinterpret_cast<const float4*>(vp + 3 * D_MODEL);
        }
    };

    auto write_tile = [&]() {
        if (w < 4) {
            float v[16];
            *reinterpret_cast<float4*>(&v[0])  = sr0;
            *reinterpret_cast<float4*>(&v[4])  = sr1;
            *reinterpret_cast<float4*>(&v[8])  = sr2;
            *reinterpret_cast<float4*>(&v[12]) = sr3;
            uint4v a1, a2, b1, b2;
            split2x8(v,     a1, a2);
            split2x8(v + 8, b1, b2);
            short* kb1 = Ks1 + krow * 64;
            short* kb2 = Ks2 + krow * 64;
            *reinterpret_cast<uint4v*>(kb1 + swz8(krow, dob    ) * 8) = a1;
            *reinterpret_cast<uint4v*>(kb1 + swz8(krow, dob + 1) * 8) = b1;
            *reinterpret_cast<uint4v*>(kb2 + swz8(krow, dob    ) * 8) = a2;
            *reinterpret_cast<uint4v*>(kb2 + swz8(krow, dob + 1) * 8) = b2;
        } else {
            float va[4][4];
            *reinterpret_cast<float4*>(va[0]) = sr0;
            *reinterpret_cast<float4*>(va[1]) = sr1;
            *reinterpret_cast<float4*>(va[2]) = sr2;
            *reinterpret_cast<float4*>(va[3]) = sr3;
            const int lo = vkq >> 1;
            const int hf = (vkq & 1) * 4;
#pragma unroll
            for (int rr = 0; rr < 4; ++rr) {
                const int row = 4 * vdq + rr;
                unsigned ub[4], rb[4];
#pragma unroll
                for (int r = 0; r < 4; ++r) {
                    const float x = va[r][rr];
                    const unsigned u = __float_as_uint(x);
                    ub[r] = u;
                    rb[r] = __float_as_uint(x - __uint_as_float(u & 0xFFFF0000u));
                }
                uint2v w1, w2;
                w1.x = (ub[0] >> 16) | (ub[1] & 0xFFFF0000u);
                w1.y = (ub[2] >> 16) | (ub[3] & 0xFFFF0000u);
                w2.x = (rb[0] >> 16) | (rb[1] & 0xFFFF0000u);
                w2.y = (rb[2] >> 16) | (rb[3] & 0xFFFF0000u);
                const int o = row * 64 + swz8(row, lo) * 8 + hf;
                *reinterpret_cast<uint2v*>(&Vt1[o]) = w1;
                *reinterpret_cast<uint2v*>(&Vt2[o]) = w2;
            }
        }
    };

    const int NT = SEQ / 64;            // 32 tiles

    load_tile(0);
    write_tile();

    for (int it = 0; it < NT; ++it) {
        __syncthreads();   // tile `it` LDS writes visible
        if (it + 1 < NT)
            load_tile((it + 1) * 64);

        // ---- QK^T (swapped): sacc[ks], k = 16ks+4g+i, q = cl
        f32x4 sacc[4];
#pragma unroll
        for (int ks = 0; ks < 4; ++ks) sacc[ks] = (f32x4)(0.f);

#pragma unroll
        for (int ks = 0; ks < 4; ++ks)
#pragma unroll
            for (int c = 0; c < 2; ++c) {
                const int row = ks * 16 + cl;
                const int po  = row * 64 + swz8(row, 4 * c + g) * 8;
                Frag ka1, ka2;
                ka1.s = *reinterpret_cast<const short8v*>(&Ks1[po]);
                ka2.s = *reinterpret_cast<const short8v*>(&Ks2[po]);
                f32x4 s = sacc[ks];
                s = __builtin_amdgcn_mfma_f32_16x16x32_bf16(ka1.s, qf[c][0].s, s, 0, 0, 0);
                s = __builtin_amdgcn_mfma_f32_16x16x32_bf16(ka2.s, qf[c][0].s, s, 0, 0, 0);
                s = __builtin_amdgcn_mfma_f32_16x16x32_bf16(ka1.s, qf[c][1].s, s, 0, 0, 0);
                sacc[ks] = s;
            }

        // ---- online softmax (exp2 domain), q row = cl
        float tm = -1e30f;
#pragma unroll
        for (int ks = 0; ks < 4; ++ks)
#pragma unroll
            for (int i = 0; i < 4; ++i) tm = fmaxf(tm, sacc[ks][i]);
        tm = fmaxf(tm, __shfl_xor(tm, 16));
        tm = fmaxf(tm, __shfl_xor(tm, 32));

        const float mn = fmaxf(m, tm);
        const float sc = __builtin_amdgcn_exp2f(m - mn);
        m = mn;

        float rs = 0.f;
        uint2v P1[4];
#pragma unroll
        for (int ks = 0; ks < 4; ++ks) {
            float p[4];
            unsigned ub[4];
#pragma unroll
            for (int i = 0; i < 4; ++i) {
                p[i] = __builtin_amdgcn_exp2f(sacc[ks][i] - mn);
                rs += p[i];
                ub[i] = __float_as_uint(p[i]);
            }
            P1[ks] = (uint2v){ (ub[0] >> 16) | (ub[1] & 0xFFFF0000u),
                               (ub[2] >> 16) | (ub[3] & 0xFFFF0000u) };
        }
        rs += __shfl_xor(rs, 16);
        rs += __shfl_xor(rs, 32);
        l = l * sc + rs;

        float scv[4];
#pragma unroll
        for (int i = 0; i < 4; ++i) scv[i] = __shfl(sc, 4 * g + i);
#pragma unroll
        for (int s = 0; s < 4; ++s)
#pragma unroll
            for (int i = 0; i < 4; ++i) acc[s][i] *= scv[i];

#pragma unroll
        for (int ks = 0; ks < 4; ++ks) {
            const int off = swz8(cl, 2 * ks + (g >> 1)) * 8 + (g & 1) * 4;
            *reinterpret_cast<uint2v*>(pb1 + off) = P1[ks];
        }

        // ---- PV: A = P (single plane), B = V^T (2 planes) -> 2 products
#pragma unroll
        for (int c = 0; c < 2; ++c) {
            const int po = swz8(cl, 4 * c + g) * 8;
            Frag pa1;
            pa1.s = *reinterpret_cast<const short8v*>(pb1 + po);
#pragma unroll
            for (int s = 0; s < 4; ++s) {
                const int row = s * 16 + cl;
                const int vo  = row * 64 + swz8(row, 4 * c + g) * 8;
                Frag vb1, vb2;
                vb1.s = *reinterpret_cast<const short8v*>(&Vt1[vo]);
                vb2.s = *reinterpret_cast<const short8v*>(&Vt2[vo]);
                f32x4 a = acc[s];
                a = __builtin_amdgcn_mfma_f32_16x16x32_bf16(pa1.s, vb1.s, a, 0, 0, 0);
                a = __builtin_amdgcn_mfma_f32_16x16x32_bf16(pa1.s, vb2.s, a, 0, 0, 0);
                acc[s] = a;
            }
        }

        __syncthreads();   // all LDS reads of tile `it` complete
        if (it + 1 < NT)
            write_tile();
    }

    // ---- epilogue: divide by l and store as packed bf16 planes
    const float inv = 1.f / l;
    float iv[4];
#pragma unroll
    for (int i = 0; i < 4; ++i) iv[i] = __shfl(inv, 4 * g + i);
#pragma unroll
    for (int s = 0; s < 4; ++s)
#pragma unroll
        for (int i = 0; i < 4; ++i) {
            const float val = acc[s][i] * iv[i];
            const size_t grow = rowBase + q0 + w * 16 + 4 * g + i;
            const int gc = hOff + s * 16 + cl;
            pack_store(pctx + grow * (size_t)(D_MODEL * 2), gc, val);
        }
}

// ---------------------------------------------------------------------------
extern "C" void kernel_launch(void* const* d_in, const int* in_sizes, int n_in,
                              void* d_out, int out_size, void* d_ws, size_t ws_size,
                              hipStream_t stream)
{
    const float* x    = (const float*)d_in[0];
    const float* Win  = (const float*)d_in[1];   // (3072, 1024)
    const float* bin  = (const float*)d_in[2];   // (3072,)
    const float* Wout = (const float*)d_in[3];   // (1024, 1024)
    const float* bout = (const float*)d_in[4];   // (1024,)
    float* out = (float*)d_out;

    // Region plan (floats):
    //   R1 [12.58M]: px (4.2M-float footprint) -> qkv fp32 (12.58M)
    //   R2 [12.58M]: pcomb (packed roped combined) -> pctx
    //   pW [3.15M], pWo [1.05M], tab [0.13M]
    float* R1 = (float*)d_ws;
    float* R2 = R1 + (size_t)ROWS * THREE_D;
    unsigned short* pW  = (unsigned short*)(R2 + (size_t)ROWS * THREE_D);
    unsigned short* pWo = pW + (size_t)THREE_D * D_MODEL * 2;
    float* tab = (float*)(pWo + (size_t)D_MODEL * D_MODEL * 2);

    unsigned short* px    = (unsigned short*)R1;   // dead once qkv written
    float*          qkv   = R1;
    unsigned short* pcomb = (unsigned short*)R2;
    unsigned short* pctx  = (unsigned short*)R2;   // overwrites pcomb (dead)

    float* qbuf = qkv;
    float* kbuf = qkv + (size_t)ROWS * D_MODEL;
    float* vbuf = kbuf + (size_t)ROWS * D_MODEL;

    const dim3 blk(256);

    rope_table<<<dim3(SEQ * 32 / 256), blk, 0, stream>>>(tab);

    // pack inputs/weights to bf16 planes (one-time, memory-bound)
    split_pack<<<dim3(ROWS * D_MODEL / 8 / 256), blk, 0, stream>>>(x, px);
    split_pack<<<dim3(THREE_D * D_MODEL / 8 / 256), blk, 0, stream>>>(Win, pW);
    split_pack<<<dim3(D_MODEL * D_MODEL / 8 / 256), blk, 0, stream>>>(Wout, pWo);

    // GEMM1 + fused rope: pcomb = pack(rope(x @ Win^T + bin))
    gemm_p_rope<<<dim3(24, 32), blk, 0, stream>>>(
        px, D_MODEL * 2, pW, D_MODEL * 2, bin, tab, pcomb, D_MODEL);

    // fused q/k/v second projection: qkv fp32 (overwrites px; px dead)
    gemm_p<<<dim3(24, 32), blk, 0, stream>>>(
        pcomb, THREE_D * 2, pW, D_MODEL * 2, bin, qkv, D_MODEL, D_MODEL,
        8, (size_t)(D_MODEL * 2), (size_t)D_MODEL * D_MODEL * 2, D_MODEL,
        (size_t)ROWS * D_MODEL);

    // attention -> pctx packed planes (overwrites pcomb; dead)
    attn_mfma<<<dim3(SEQ / 128, BATCH * N_HEADS), dim3(512), 0, stream>>>(
        qbuf, kbuf, vbuf, pctx);

    // GEMM3: out = ctx @ Wout^T + bout
    gemm_p<<<dim3(8, 32), blk, 0, stream>>>(
        pctx, D_MODEL * 2, pWo, D_MODEL * 2, bout, out, D_MODEL, D_MODEL,
        8, (size_t)0, (size_t)0, 0, (size_t)0);
}

// Round 13
// 346.667 us; speedup vs baseline: 1.6996x; 1.0615x over previous
//
#include <hip/hip_runtime.h>
#include <math.h>

#define D_MODEL   1024
#define N_HEADS   16
#define H_DIM     64
#define SEQ       2048
#define BATCH     2
#define ROWS      (BATCH * SEQ)        // 4096
#define THREE_D   (3 * D_MODEL)       // 3072

// q pre-scale: 1/sqrt(64) * log2(e)  -> softmax in exp2 domain
#define QK_SCALE  (0.125f * 1.44269504088896340736f)

typedef __attribute__((ext_vector_type(8))) short short8v;   // 8 bf16
typedef __attribute__((ext_vector_type(4))) float f32x4;
typedef __attribute__((ext_vector_type(4))) unsigned int uint4v;
typedef __attribute__((ext_vector_type(2))) unsigned int uint2v;

union Frag { uint4v u; short8v s; };

__device__ __forceinline__ void async_copy16(const void* g, void* l)
{
    __builtin_amdgcn_global_load_lds(
        (const __attribute__((address_space(1))) void*)g,
        (__attribute__((address_space(3))) void*)l,
        16, 0, 0);
}

// LDS octet swizzle key (attn)
__device__ __forceinline__ int swz8(int row, int oct)
{
    return oct ^ ((row ^ (row >> 2)) & 7);
}

__device__ __forceinline__ uint2v shfl_u2(uint2v v, int src)
{
    uint2v r;
    r.x = (unsigned)__shfl((int)v.x, src);
    r.y = (unsigned)__shfl((int)v.y, src);
    return r;
}

// split 8 floats into 2 packed bf16x8 planes (truncation)
__device__ __forceinline__ void split2x8(const float* v, uint4v& U1, uint4v& U2)
{
    unsigned b1[8], b2[8];
#pragma unroll
    for (int j = 0; j < 8; ++j) {
        const unsigned u = __float_as_uint(v[j]);
        b1[j] = u;
        const float r = v[j] - __uint_as_float(u & 0xFFFF0000u);
        b2[j] = __float_as_uint(r);
    }
    U1 = (uint4v){ (b1[0]>>16)|(b1[1]&0xFFFF0000u), (b1[2]>>16)|(b1[3]&0xFFFF0000u),
                   (b1[4]>>16)|(b1[5]&0xFFFF0000u), (b1[6]>>16)|(b1[7]&0xFFFF0000u) };
    U2 = (uint4v){ (b2[0]>>16)|(b2[1]&0xFFFF0000u), (b2[2]>>16)|(b2[3]&0xFFFF0000u),
                   (b2[4]>>16)|(b2[5]&0xFFFF0000u), (b2[6]>>16)|(b2[7]&0xFFFF0000u) };
}

// packed-plane flat formula: short_off(e) = ((e>>5)<<6) + (e&31), plane2 +32
__device__ __forceinline__ void pack_store(unsigned short* rowp, int col, float val)
{
    unsigned short* d = rowp + ((col >> 5) << 6) + (col & 31);
    const unsigned u = __float_as_uint(val);
    d[0]  = (unsigned short)(u >> 16);
    const float r = val - __uint_as_float(u & 0xFFFF0000u);
    d[32] = (unsigned short)(__float_as_uint(r) >> 16);
}

// ---------------------------------------------------------------------------
// split_pack: fp32 row-major -> packed bf16 planes [.][K/32][2][32]
// ---------------------------------------------------------------------------
__global__ __launch_bounds__(256)
void split_pack(const float* __restrict__ in, unsigned short* __restrict__ out)
{
    const size_t e0 = ((size_t)blockIdx.x * 256 + threadIdx.x) * 8;
    const float4 a0 = *reinterpret_cast<const float4*>(in + e0);
    const float4 a1 = *reinterpret_cast<const float4*>(in + e0 + 4);
    float v[8] = { a0.x, a0.y, a0.z, a0.w, a1.x, a1.y, a1.z, a1.w };
    uint4v U1, U2;
    split2x8(v, U1, U2);
    unsigned short* d = out + ((e0 >> 5) << 6) + (e0 & 31);
    *reinterpret_cast<uint4v*>(d)      = U1;
    *reinterpret_cast<uint4v*>(d + 32) = U2;
}

// ---------------------------------------------------------------------------
// RoPE cos/sin table (fp64 accuracy)
// ---------------------------------------------------------------------------
__global__ void rope_table(float* __restrict__ tab)
{
    const int idx = blockIdx.x * 256 + threadIdx.x;
    const int s = idx >> 5;
    const int i = idx & 31;
    const double inv = pow(10000.0, -(double)(2 * i) / 64.0);
    const double f = (double)s * inv;
    tab[idx * 2 + 0] = (float)cos(f);
    tab[idx * 2 + 1] = (float)sin(f);
}

// ---------------------------------------------------------------------------
// gemm_p: packed-plane GEMM, fp32 C out.  3 MFMA products.  XCD-bijective
// block remap: each XCD owns gridDim.x/8 consecutive bn panels (B-panel L2
// locality).  Requires gridDim.x % 8 == 0.
// ---------------------------------------------------------------------------
__global__ __launch_bounds__(256, 2)
void gemm_p(const unsigned short* __restrict__ Ap, int ldA2,
            const unsigned short* __restrict__ Bp, int ldB2,
            const float* __restrict__ bias,
            float* __restrict__ C, int ldc, int K,
            int nbx, size_t segA, size_t segB, int segBias, size_t segC)
{
    __shared__ __align__(16) unsigned short As[2][128 * 64];
    __shared__ __align__(16) unsigned short Bs[2][128 * 64];

    const int fid  = blockIdx.y * gridDim.x + blockIdx.x;
    const int bxpx = gridDim.x >> 3;            // bn panels per XCD
    const int xcd  = fid & 7;
    const int idx  = fid >> 3;
    const int bxx  = xcd * bxpx + idx % bxpx;
    const int by   = idx / bxpx;

    const int seg = bxx / nbx;
    const int bxs = bxx - seg * nbx;
    const int bm  = by * 128;
    const int bn  = bxs * 128;
    Ap   += (size_t)seg * segA;
    Bp   += (size_t)seg * segB;
    bias += seg * segBias;
    C    += (size_t)seg * segC;

    const int t    = threadIdx.x;
    const int wid  = t >> 6;
    const int lane = t & 63;
    const int wr   = wid >> 1;
    const int wc   = wid & 1;
    const int cl   = lane & 15;
    const int kq   = lane >> 4;
    const int lrow = lane >> 3;
    const int gs   = lane & 7;

    auto stage = [&](int buf, int k0) {
        const int gl = gs ^ lrow;
#pragma unroll
        for (int q = 0; q < 4; ++q) {
            const int r0  = (wid * 4 + q) * 8;
            const int row = r0 + lrow;
            async_copy16(Ap + (size_t)(bm + row) * ldA2 + (k0 << 1) + (gl << 3),
                         &As[buf][r0 * 64]);
            async_copy16(Bp + (size_t)(bn + row) * ldB2 + (k0 << 1) + (gl << 3),
                         &Bs[buf][r0 * 64]);
        }
    };

    f32x4 acc[4][4];
#pragma unroll
    for (int m = 0; m < 4; ++m)
#pragma unroll
        for (int n = 0; n < 4; ++n) acc[m][n] = (f32x4)(0.f);

    const int NT = K >> 5;
    stage(0, 0);

    for (int it = 0; it < NT; ++it) {
        __syncthreads();
        if (it + 1 < NT)
            stage((it + 1) & 1, (it + 1) << 5);

        const unsigned short* as = As[it & 1];
        const unsigned short* bs = Bs[it & 1];

        short8v A1[4], A2[4], B1[4], B2[4];
#pragma unroll
        for (int m = 0; m < 4; ++m) {
            const int r = wr * 64 + m * 16 + cl;
            const unsigned short* ar = as + r * 64;
            A1[m] = *reinterpret_cast<const short8v*>(ar + (( kq      ^ (r & 7)) << 3));
            A2[m] = *reinterpret_cast<const short8v*>(ar + (((kq + 4) ^ (r & 7)) << 3));
        }
#pragma unroll
        for (int n = 0; n < 4; ++n) {
            const int r = wc * 64 + n * 16 + cl;
            const unsigned short* br = bs + r * 64;
            B1[n] = *reinterpret_cast<const short8v*>(br + (( kq      ^ (r & 7)) << 3));
            B2[n] = *reinterpret_cast<const short8v*>(br + (((kq + 4) ^ (r & 7)) << 3));
        }

#pragma unroll
        for (int m = 0; m < 4; ++m)
#pragma unroll
            for (int n = 0; n < 4; ++n) {
                f32x4 c = acc[m][n];
                c = __builtin_amdgcn_mfma_f32_16x16x32_bf16(A1[m], B1[n], c, 0, 0, 0);
                c = __builtin_amdgcn_mfma_f32_16x16x32_bf16(A2[m], B1[n], c, 0, 0, 0);
                c = __builtin_amdgcn_mfma_f32_16x16x32_bf16(A1[m], B2[n], c, 0, 0, 0);
                acc[m][n] = c;
            }
    }

    const int rw = lane >> 4;
#pragma unroll
    for (int n = 0; n < 4; ++n) {
        const int col = bn + wc * 64 + n * 16 + cl;
        const float bv = bias[col];
#pragma unroll
        for (int m = 0; m < 4; ++m) {
            const size_t rbase = (size_t)(bm + wr * 64 + m * 16 + rw * 4);
#pragma unroll
            for (int i = 0; i < 4; ++i)
                C[(rbase + i) * ldc + col] = acc[m][n][i] + bv;
        }
    }
}

// ---------------------------------------------------------------------------
// gemm_p_rope: GEMM1 with RoPE fused into the epilogue; writes packed planes.
// Same XCD-bijective remap (gridDim.x = 24).
// ---------------------------------------------------------------------------
__global__ __launch_bounds__(256, 2)
void gemm_p_rope(const unsigned short* __restrict__ Ap, int ldA2,
                 const unsigned short* __restrict__ Bp, int ldB2,
                 const float* __restrict__ bias,
                 const float* __restrict__ tab,
                 unsigned short* __restrict__ out, int K)
{
    __shared__ __align__(16) unsigned short As[2][128 * 64];
    __shared__ __align__(16) unsigned short Bs[2][128 * 64];

    const int fid  = blockIdx.y * gridDim.x + blockIdx.x;
    const int bxpx = gridDim.x >> 3;
    const int xcd  = fid & 7;
    const int idx  = fid >> 3;
    const int bxx  = xcd * bxpx + idx % bxpx;
    const int by   = idx / bxpx;

    const int bm  = by * 128;
    const int bn  = bxx * 128;

    const int t    = threadIdx.x;
    const int wid  = t >> 6;
    const int lane = t & 63;
    const int wr   = wid >> 1;
    const int wc   = wid & 1;
    const int cl   = lane & 15;
    const int kq   = lane >> 4;
    const int lrow = lane >> 3;
    const int gs   = lane & 7;

    auto stage = [&](int buf, int k0) {
        const int gl = gs ^ lrow;
#pragma unroll
        for (int q = 0; q < 4; ++q) {
            const int r0  = (wid * 4 + q) * 8;
            const int row = r0 + lrow;
            async_copy16(Ap + (size_t)(bm + row) * ldA2 + (k0 << 1) + (gl << 3),
                         &As[buf][r0 * 64]);
            async_copy16(Bp + (size_t)(bn + row) * ldB2 + (k0 << 1) + (gl << 3),
                         &Bs[buf][r0 * 64]);
        }
    };

    f32x4 acc[4][4];
#pragma unroll
    for (int m = 0; m < 4; ++m)
#pragma unroll
        for (int n = 0; n < 4; ++n) acc[m][n] = (f32x4)(0.f);

    const int NT = K >> 5;
    stage(0, 0);

    for (int it = 0; it < NT; ++it) {
        __syncthreads();
        if (it + 1 < NT)
            stage((it + 1) & 1, (it + 1) << 5);

        const unsigned short* as = As[it & 1];
        const unsigned short* bs = Bs[it & 1];

        short8v A1[4], A2[4], B1[4], B2[4];
#pragma unroll
        for (int m = 0; m < 4; ++m) {
            const int r = wr * 64 + m * 16 + cl;
            const unsigned short* ar = as + r * 64;
            A1[m] = *reinterpret_cast<const short8v*>(ar + (( kq      ^ (r & 7)) << 3));
            A2[m] = *reinterpret_cast<const short8v*>(ar + (((kq + 4) ^ (r & 7)) << 3));
        }
#pragma unroll
        for (int n = 0; n < 4; ++n) {
            const int r = wc * 64 + n * 16 + cl;
            const unsigned short* br = bs + r * 64;
            B1[n] = *reinterpret_cast<const short8v*>(br + (( kq      ^ (r & 7)) << 3));
            B2[n] = *reinterpret_cast<const short8v*>(br + (((kq + 4) ^ (r & 7)) << 3));
        }

#pragma unroll
        for (int m = 0; m < 4; ++m)
#pragma unroll
            for (int n = 0; n < 4; ++n) {
                f32x4 c = acc[m][n];
                c = __builtin_amdgcn_mfma_f32_16x16x32_bf16(A1[m], B1[n], c, 0, 0, 0);
                c = __builtin_amdgcn_mfma_f32_16x16x32_bf16(A2[m], B1[n], c, 0, 0, 0);
                c = __builtin_amdgcn_mfma_f32_16x16x32_bf16(A1[m], B2[n], c, 0, 0, 0);
                acc[m][n] = c;
            }
    }

    // ---- epilogue: rope (q/k thirds) + packed-plane store
    const int rw = lane >> 4;
    const bool doRope = (bn < 2 * D_MODEL);
#pragma unroll
    for (int n = 0; n < 2; ++n) {
        const int colA = bn + wc * 64 + n * 16 + cl;
        const int colB = colA + 32;
        const float bvA = bias[colA];
        const float bvB = bias[colB];
        const int d = n * 16 + cl;
#pragma unroll
        for (int m = 0; m < 4; ++m) {
            const size_t rbase = (size_t)(bm + wr * 64 + m * 16 + rw * 4);
#pragma unroll
            for (int i = 0; i < 4; ++i) {
                const size_t row = rbase + i;
                const float t1 = acc[m][n][i]     + bvA;
                const float t2 = acc[m][n + 2][i] + bvB;
                float r1 = t1, r2 = t2;
                if (doRope) {
                    const int s = (int)(row & (SEQ - 1));
                    const float c  = tab[(s * 32 + d) * 2 + 0];
                    const float sn = tab[(s * 32 + d) * 2 + 1];
                    r1 = t1 * c - t2 * sn;
                    r2 = t2 * c + t1 * sn;
                }
                unsigned short* op = out + row * (size_t)(THREE_D * 2);
                pack_store(op, colA, r1);
                pack_store(op, colB, r2);
            }
        }
    }
}

// ---------------------------------------------------------------------------
// Flash attention, bf16-split MFMA, 8 waves x 16 q-rows.
// KV DOUBLE-BUFFERED LDS (64 KB) -> ONE barrier per tile.  P stays fully in
// registers: QK D-layout -> PV A-fragment relayout via the R3-verified shfl
// pattern (srcA = cl + 32*(g&1), select-after-shfl on g>>1).  T14 reg
// staging (waves 0-3 K, 4-7 V), XCD remap, swz8 keys, exp2 softmax.
// QK 3 products, PV 2 products.  Epilogue writes packed planes.
// ---------------------------------------------------------------------------
__global__ __launch_bounds__(512)
void attn_mfma(const float* __restrict__ Qg, const float* __restrict__ Kg,
               const float* __restrict__ Vg, unsigned short* __restrict__ pctx)
{
    __shared__ __align__(16) short Ks1[2][64 * 64];
    __shared__ __align__(16) short Ks2[2][64 * 64];
    __shared__ __align__(16) short Vt1[2][64 * 64];
    __shared__ __align__(16) short Vt2[2][64 * 64];

    const int fid = blockIdx.y * gridDim.x + blockIdx.x;   // 0..511
    const int bh  = (fid & 7) * 4 + ((fid >> 3) & 3);
    const int q0  = (fid >> 5) * 128;
    const int b   = bh >> 4;
    const int h   = bh & 15;
    const size_t rowBase = (size_t)b * SEQ;
    const int hOff = h * H_DIM;

    const int t    = threadIdx.x;
    const int w    = t >> 6;
    const int lane = t & 63;
    const int cl   = lane & 15;
    const int g    = lane >> 4;
    const int g2   = g >> 1;
    const int srcA = cl + 32 * (g & 1);   // R3-verified relayout sources
    const int srcB = srcA + 16;

    const int krow = t >> 2;
    const int dob  = (t & 3) * 2;
    const int t2   = t - 256;
    const int vkq  = t2 >> 4;
    const int vdq  = t2 & 15;

    Frag qf[2][2];   // [c][plane]
#pragma unroll
    for (int c = 0; c < 2; ++c) {
        const float* qp = Qg + (rowBase + q0 + w * 16 + cl) * D_MODEL
                          + hOff + c * 32 + g * 8;
        const float4 f0 = *reinterpret_cast<const float4*>(qp);
        const float4 f1 = *reinterpret_cast<const float4*>(qp + 4);
        float v[8] = { f0.x * QK_SCALE, f0.y * QK_SCALE, f0.z * QK_SCALE, f0.w * QK_SCALE,
                       f1.x * QK_SCALE, f1.y * QK_SCALE, f1.z * QK_SCALE, f1.w * QK_SCALE };
        split2x8(v, qf[c][0].u, qf[c][1].u);
    }

    f32x4 acc[4];
#pragma unroll
    for (int s = 0; s < 4; ++s) acc[s] = (f32x4)(0.f);
    float m = -1e30f;
    float l = 0.f;

    float4 sr0, sr1, sr2, sr3;

    auto load_tile = [&](int k0) {
        if (w < 4) {
            const float* kp = Kg + (rowBase + k0 + krow) * D_MODEL + hOff + dob * 8;
            sr0 = reinterpret_cast<const float4*>(kp)[0];
            sr1 = reinterpret_cast<const float4*>(kp)[1];
            sr2 = reinterpret_cast<const float4*>(kp)[2];
            sr3 = reinterpret_cast<const float4*>(kp)[3];
        } else {
            const float* vp = Vg + (rowBase + k0 + vkq * 4) * D_MODEL + hOff + vdq * 4;
            sr0 = *reinterpret_cast<const float4*>(vp);
            sr1 = *reinterpret_cast<const float4*>(vp + D_MODEL);
            sr2 = *reinterpret_cast<const float4*>(vp + 2 * D_MODEL);
            sr3 = *reinterpret_cast<const float4*>(vp + 3 * D_MODEL);
        }
    };

    auto write_tile = [&](int buf) {
        if (w < 4) {
            float v[16];
            *reinterpret_cast<float4*>(&v[0])  = sr0;
            *reinterpret_cast<float4*>(&v[4])  = sr1;
            *reinterpret_cast<float4*>(&v[8])  = sr2;
            *reinterpret_cast<float4*>(&v[12]) = sr3;
            uint4v a1, a2, b1, b2;
            split2x8(v,     a1, a2);
            split2x8(v + 8, b1, b2);
            short* kb1 = Ks1[buf] + krow * 64;
            short* kb2 = Ks2[buf] + krow * 64;
            *reinterpret_cast<uint4v*>(kb1 + swz8(krow, dob    ) * 8) = a1;
            *reinterpret_cast<uint4v*>(kb1 + swz8(krow, dob + 1) * 8) = b1;
            *reinterpret_cast<uint4v*>(kb2 + swz8(krow, dob    ) * 8) = a2;
            *reinterpret_cast<uint4v*>(kb2 + swz8(krow, dob + 1) * 8) = b2;
        } else {
            float va[4][4];
            *reinterpret_cast<float4*>(va[0]) = sr0;
            *reinterpret_cast<float4*>(va[1]) = sr1;
            *reinterpret_cast<float4*>(va[2]) = sr2;
            *reinterpret_cast<float4*>(va[3]) = sr3;
            const int lo = vkq >> 1;
            const int hf = (vkq & 1) * 4;
#pragma unroll
            for (int rr = 0; rr < 4; ++rr) {
                const int row = 4 * vdq + rr;
                unsigned ub[4], rb[4];
#pragma unroll
                for (int r = 0; r < 4; ++r) {
                    const float x = va[r][rr];
                    const unsigned u = __float_as_uint(x);
                    ub[r] = u;
                    rb[r] = __float_as_uint(x - __uint_as_float(u & 0xFFFF0000u));
                }
                uint2v w1, w2;
                w1.x = (ub[0] >> 16) | (ub[1] & 0xFFFF0000u);
                w1.y = (ub[2] >> 16) | (ub[3] & 0xFFFF0000u);
                w2.x = (rb[0] >> 16) | (rb[1] & 0xFFFF0000u);
                w2.y = (rb[2] >> 16) | (rb[3] & 0xFFFF0000u);
                const int o = row * 64 + swz8(row, lo) * 8 + hf;
                *reinterpret_cast<uint2v*>(&Vt1[buf][o]) = w1;
                *reinterpret_cast<uint2v*>(&Vt2[buf][o]) = w2;
            }
        }
    };

    const int NT = SEQ / 64;            // 32 tiles

    load_tile(0);
    write_tile(0);

    for (int it = 0; it < NT; ++it) {
        __syncthreads();   // buf[it&1] writes visible (single barrier/tile)
        const int bf = it & 1;
        if (it + 1 < NT)
            load_tile((it + 1) * 64);   // global loads hidden under compute

        // ---- QK^T (swapped): sacc[ks], k = 16ks+4g+i, q = cl
        f32x4 sacc[4];
#pragma unroll
        for (int ks = 0; ks < 4; ++ks) sacc[ks] = (f32x4)(0.f);

#pragma unroll
        for (int ks = 0; ks < 4; ++ks)
#pragma unroll
            for (int c = 0; c < 2; ++c) {
                const int row = ks * 16 + cl;
                const int po  = row * 64 + swz8(row, 4 * c + g) * 8;
                Frag ka1, ka2;
                ka1.s = *reinterpret_cast<const short8v*>(&Ks1[bf][po]);
                ka2.s = *reinterpret_cast<const short8v*>(&Ks2[bf][po]);
                f32x4 s = sacc[ks];
                s = __builtin_amdgcn_mfma_f32_16x16x32_bf16(ka1.s, qf[c][0].s, s, 0, 0, 0);
                s = __builtin_amdgcn_mfma_f32_16x16x32_bf16(ka2.s, qf[c][0].s, s, 0, 0, 0);
                s = __builtin_amdgcn_mfma_f32_16x16x32_bf16(ka1.s, qf[c][1].s, s, 0, 0, 0);
                sacc[ks] = s;
            }

        // ---- online softmax (exp2 domain), q row = cl
        float tm = -1e30f;
#pragma unroll
        for (int ks = 0; ks < 4; ++ks)
#pragma unroll
            for (int i = 0; i < 4; ++i) tm = fmaxf(tm, sacc[ks][i]);
        tm = fmaxf(tm, __shfl_xor(tm, 16));
        tm = fmaxf(tm, __shfl_xor(tm, 32));

        const float mn = fmaxf(m, tm);
        const float sc = __builtin_amdgcn_exp2f(m - mn);
        m = mn;

        float rs = 0.f;
        uint2v P1[4];
#pragma unroll
        for (int ks = 0; ks < 4; ++ks) {
            float p[4];
            unsigned ub[4];
#pragma unroll
            for (int i = 0; i < 4; ++i) {
                p[i] = __builtin_amdgcn_exp2f(sacc[ks][i] - mn);
                rs += p[i];
                ub[i] = __float_as_uint(p[i]);
            }
            P1[ks] = (uint2v){ (ub[0] >> 16) | (ub[1] & 0xFFFF0000u),
                               (ub[2] >> 16) | (ub[3] & 0xFFFF0000u) };
        }
        rs += __shfl_xor(rs, 16);
        rs += __shfl_xor(rs, 32);
        l = l * sc + rs;

        float scv[4];
#pragma unroll
        for (int i = 0; i < 4; ++i) scv[i] = __shfl(sc, 4 * g + i);
#pragma unroll
        for (int s = 0; s < 4; ++s)
#pragma unroll
            for (int i = 0; i < 4; ++i) acc[s][i] *= scv[i];

        // ---- PV: A = P via in-register shfl relayout (R3-verified pattern)
#pragma unroll
        for (int c = 0; c < 2; ++c) {
            uint2v a0 = shfl_u2(P1[2 * c],     srcA);
            uint2v a1 = shfl_u2(P1[2 * c + 1], srcA);
            uint2v b0 = shfl_u2(P1[2 * c],     srcB);
            uint2v b1 = shfl_u2(P1[2 * c + 1], srcB);
            uint2v lo = g2 ? a1 : a0;
            uint2v hi = g2 ? b1 : b0;
            Frag pa;
            pa.u = (uint4v){ lo.x, lo.y, hi.x, hi.y };
#pragma unroll
            for (int s = 0; s < 4; ++s) {
                const int row = s * 16 + cl;
                const int vo  = row * 64 + swz8(row, 4 * c + g) * 8;
                Frag vb1, vb2;
                vb1.s = *reinterpret_cast<const short8v*>(&Vt1[bf][vo]);
                vb2.s = *reinterpret_cast<const short8v*>(&Vt2[bf][vo]);
                f32x4 a = acc[s];
                a = __builtin_amdgcn_mfma_f32_16x16x32_bf16(pa.s, vb1.s, a, 0, 0, 0);
                a = __builtin_amdgcn_mfma_f32_16x16x32_bf16(pa.s, vb2.s, a, 0, 0, 0);
                acc[s] = a;
            }
        }

        // stage tile it+1 into buf^1 — no barrier needed (disjoint buffer;
        // next iteration's top barrier orders these writes before reads)
        if (it + 1 < NT)
            write_tile(bf ^ 1);
    }

    // ---- epilogue: divide by l and store as packed bf16 planes
    const float inv = 1.f / l;
    float iv[4];
#pragma unroll
    for (int i = 0; i < 4; ++i) iv[i] = __shfl(inv, 4 * g + i);
#pragma unroll
    for (int s = 0; s < 4; ++s)
#pragma unroll
        for (int i = 0; i < 4; ++i) {
            const float val = acc[s][i] * iv[i];
            const size_t grow = rowBase + q0 + w * 16 + 4 * g + i;
            const int gc = hOff + s * 16 + cl;
            pack_store(pctx + grow * (size_t)(D_MODEL * 2), gc, val);
        }
}

// ---------------------------------------------------------------------------
extern "C" void kernel_launch(void* const* d_in, const int* in_sizes, int n_in,
                              void* d_out, int out_size, void* d_ws, size_t ws_size,
                              hipStream_t stream)
{
    const float* x    = (const float*)d_in[0];
    const float* Win  = (const float*)d_in[1];   // (3072, 1024)
    const float* bin  = (const float*)d_in[2];   // (3072,)
    const float* Wout = (const float*)d_in[3];   // (1024, 1024)
    const float* bout = (const float*)d_in[4];   // (1024,)
    float* out = (float*)d_out;

    float* R1 = (float*)d_ws;
    float* R2 = R1 + (size_t)ROWS * THREE_D;
    unsigned short* pW  = (unsigned short*)(R2 + (size_t)ROWS * THREE_D);
    unsigned short* pWo = pW + (size_t)THREE_D * D_MODEL * 2;
    float* tab = (float*)(pWo + (size_t)D_MODEL * D_MODEL * 2);

    unsigned short* px    = (unsigned short*)R1;   // dead once qkv written
    float*          qkv   = R1;
    unsigned short* pcomb = (unsigned short*)R2;
    unsigned short* pctx  = (unsigned short*)R2;   // overwrites pcomb (dead)

    float* qbuf = qkv;
    float* kbuf = qkv + (size_t)ROWS * D_MODEL;
    float* vbuf = kbuf + (size_t)ROWS * D_MODEL;

    const dim3 blk(256);

    rope_table<<<dim3(SEQ * 32 / 256), blk, 0, stream>>>(tab);

    // pack inputs/weights to bf16 planes (one-time, memory-bound)
    split_pack<<<dim3(ROWS * D_MODEL / 8 / 256), blk, 0, stream>>>(x, px);
    split_pack<<<dim3(THREE_D * D_MODEL / 8 / 256), blk, 0, stream>>>(Win, pW);
    split_pack<<<dim3(D_MODEL * D_MODEL / 8 / 256), blk, 0, stream>>>(Wout, pWo);

    // GEMM1 + fused rope: pcomb = pack(rope(x @ Win^T + bin))
    gemm_p_rope<<<dim3(24, 32), blk, 0, stream>>>(
        px, D_MODEL * 2, pW, D_MODEL * 2, bin, tab, pcomb, D_MODEL);

    // fused q/k/v second projection: qkv fp32 (overwrites px; px dead)
    gemm_p<<<dim3(24, 32), blk, 0, stream>>>(
        pcomb, THREE_D * 2, pW, D_MODEL * 2, bin, qkv, D_MODEL, D_MODEL,
        8, (size_t)(D_MODEL * 2), (size_t)D_MODEL * D_MODEL * 2, D_MODEL,
        (size_t)ROWS * D_MODEL);

    // attention -> pctx packed planes (overwrites pcomb; dead)
    attn_mfma<<<dim3(SEQ / 128, BATCH * N_HEADS), dim3(512), 0, stream>>>(
        qbuf, kbuf, vbuf, pctx);

    // GEMM3: out = ctx @ Wout^T + bout
    gemm_p<<<dim3(8, 32), blk, 0, stream>>>(
        pctx, D_MODEL * 2, pWo, D_MODEL * 2, bout, out, D_MODEL, D_MODEL,
        8, (size_t)0, (size_t)0, 0, (size_t)0);
}